// Round 3
// baseline (608.700 us; speedup 1.0000x reference)
//
#include <hip/hip_runtime.h>
#include <cmath>

namespace {

constexpr int N = 100000;
constexpr int E = 1600000;
constexpr int S = 32;           // hidden
constexpr int L = 5;            // layers
constexpr int NB = (N + 255) / 256;   // node-per-thread kernels
constexpr int NPW = 16;               // nodes per wave in layer kernel
constexpr int LB2 = (N + 63) / 64;    // 1563 blocks (4 waves/block, 16 nodes/wave)
constexpr int NXCD = 8;
constexpr float PI_F    = 3.14159265358979323846f;
constexpr float SQRT2_F = 1.41421356237309515f;

typedef __attribute__((ext_vector_type(8))) short short8;   // 8 x bf16
typedef __attribute__((ext_vector_type(4))) float f32x4;

// fast silu: v_rcp_f32 instead of IEEE division (saves ~10 VALU instrs/call)
__device__ __forceinline__ float silu_f(float x) {
    return x * __builtin_amdgcn_rcpf(1.0f + __expf(-x));
}

// float -> bf16 bits, round-to-nearest-even
__device__ __forceinline__ unsigned short f2bf(float f) {
    unsigned int u = __float_as_uint(f);
    u = (u + 0x7FFFu + ((u >> 16) & 1u)) >> 16;
    return (unsigned short)u;
}

__device__ __forceinline__ int rl(int v, int i) {
    return __builtin_amdgcn_readlane(v, i);
}

// 32-bit byte-offset gather of a 16B xb fragment: base + col*64 + quad*16
__device__ __forceinline__ short8 ld_xb(const unsigned short* base, int col, int quad) {
    unsigned off = ((unsigned)col << 6) | ((unsigned)quad << 4);
    return *reinterpret_cast<const short8*>(reinterpret_cast<const char*>(base) + off);
}

// 32-bit byte-offset read of an rbf half-row: base + slot*32 + quad*16
__device__ __forceinline__ short8 ld_rbf(const unsigned short* base, int slot, int quad) {
    unsigned off = ((unsigned)slot << 5) | ((unsigned)quad << 4);
    return *reinterpret_cast<const short8*>(reinterpret_cast<const char*>(base) + off);
}

// advance (i,t) to the next tile of this wave's 16-node batch (uniform)
__device__ __forceinline__ void adv(int& i, int& t, int vd) {
    ++t;
    while (i < 16) {
        int dgi = rl(vd, i);
        int nt = (dgi + 15) >> 4;
        if (t < nt) break;
        t = 0; ++i;
    }
}

// CSR slot for (i,t) at lane row ml; clamped into the node's own range
__device__ __forceinline__ int slotOf(int i, int t, int vs, int vd, int ml) {
    if (i >= 16) return 0;
    int s0 = rl(vs, i);
    int dg = rl(vd, i);
    int smax = s0 + ((dg > 0) ? dg : 1) - 1;
    int s = s0 + t * 16 + ml;
    return min(s, smax);
}

// ---------------------------------------------------------------- degree count, XCD-privatized
// blockIdx&7 ~ XCD id (round-robin dispatch). Each deg8 slice is touched by one
// XCD only -> counter lines stay in that XCD's L2, no cross-die atomic ping-pong.
// Correctness does NOT depend on the mapping: any partition gives bijective ranks.
__global__ __launch_bounds__(256) void deg_kernel(
    const int* __restrict__ ei, int* __restrict__ deg8, int* __restrict__ ke)
{
    int e = blockIdx.x * 256 + threadIdx.x;
    if (e >= E) return;
    int p = blockIdx.x & (NXCD - 1);
    int lr = atomicAdd(&deg8[p * N + ei[e]], 1);
    ke[e] = (p << 24) | lr;   // partition + local rank, coalesced store
}

// ---------------------------------------------------------------- combine partitions
// deg[n] = sum_p deg8[p][n]; deg8[p][n] <- exclusive prefix over p (partition base)
__global__ __launch_bounds__(256) void combine_kernel(
    int* __restrict__ deg8, int* __restrict__ deg)
{
    int n = blockIdx.x * 256 + threadIdx.x;
    if (n >= N) return;
    int s = 0;
    #pragma unroll
    for (int p = 0; p < NXCD; ++p) {
        int c = deg8[p * N + n];
        deg8[p * N + n] = s;
        s += c;
    }
    deg[n] = s;
}

// ---------------------------------------------------------------- scan (3-kernel hierarchical)
__global__ __launch_bounds__(256) void scanA(
    const int* __restrict__ deg, int* __restrict__ bsum)
{
    __shared__ int sd[256];
    int t = threadIdx.x;
    int n = blockIdx.x * 256 + t;
    sd[t] = (n < N) ? deg[n] : 0;
    __syncthreads();
    #pragma unroll
    for (int s = 128; s > 0; s >>= 1) {
        if (t < s) sd[t] += sd[t + s];
        __syncthreads();
    }
    if (t == 0) bsum[blockIdx.x] = sd[0];
}

__global__ __launch_bounds__(512) void scanB(int* __restrict__ bsum)
{
    __shared__ int sd[512];
    int t = threadIdx.x;
    sd[t] = (t < NB) ? bsum[t] : 0;
    __syncthreads();
    #pragma unroll
    for (int off = 1; off < 512; off <<= 1) {
        int v = (t >= off) ? sd[t - off] : 0;
        __syncthreads();
        sd[t] += v;
        __syncthreads();
    }
    if (t < NB) bsum[t] = (t == 0) ? 0 : sd[t - 1];   // exclusive
}

__global__ __launch_bounds__(256) void scanC(
    const int* __restrict__ deg, const int* __restrict__ bsum,
    int* __restrict__ start)
{
    __shared__ int sd[256];
    int t = threadIdx.x;
    int n = blockIdx.x * 256 + t;
    int v = (n < N) ? deg[n] : 0;
    sd[t] = v;
    __syncthreads();
    #pragma unroll
    for (int off = 1; off < 256; off <<= 1) {
        int w = (t >= off) ? sd[t - off] : 0;
        __syncthreads();
        sd[t] += w;
        __syncthreads();
    }
    if (n < N) start[n] = bsum[blockIdx.x] + sd[t] - v;  // exclusive
}

// ---------------------------------------------------------------- CSR fill: minimal 8B scatter
__global__ __launch_bounds__(256) void fill_kernel(
    const int* __restrict__ ei, const float* __restrict__ pos,
    const int* __restrict__ start, const int* __restrict__ ke,
    const int* __restrict__ deg8, unsigned long long* __restrict__ cd)
{
    int e = blockIdx.x * 256 + threadIdx.x;
    if (e >= E) return;
    int r = ei[e];
    int c = ei[E + e];
    float2 pr = reinterpret_cast<const float2*>(pos)[r];
    float2 pc = reinterpret_cast<const float2*>(pos)[c];
    float dx = pr.x - pc.x, dy = pr.y - pc.y;
    float d = sqrtf(dx * dx + dy * dy);   // pos-mean cancels
    int pk = ke[e];
    int p = pk >> 24;
    int lr = pk & 0xFFFFFF;
    int s = start[r] + deg8[p * N + r] + lr;
    cd[s] = (unsigned long long)(unsigned int)c |
            ((unsigned long long)__float_as_uint(d) << 32);
}

// ---------------------------------------------------------------- CSR expand: fully streaming
__global__ __launch_bounds__(256) void expand_kernel(
    const unsigned long long* __restrict__ cd,
    int* __restrict__ csr_col, unsigned short* __restrict__ rbf_buf)
{
    int s = blockIdx.x * 256 + threadIdx.x;
    if (s >= E) return;
    unsigned long long t = cd[s];
    int c = (int)(unsigned int)(t & 0xffffffffull);
    float d = __uint_as_float((unsigned int)(t >> 32));
    csr_col[s] = c;

    float s1 = __sinf(PI_F * d);
    float c1 = __cosf(PI_F * d);
    float inv = SQRT2_F / (d + 1e-8f);
    float tc = 2.0f * c1;
    float sk = s1, skm = 0.0f;
    unsigned int pk[8];
    #pragma unroll
    for (int i = 0; i < 8; ++i) {
        float r0 = sk * inv;
        float s2 = tc * sk - skm; skm = sk; sk = s2;
        float r1 = sk * inv;
        float s3 = tc * sk - skm; skm = sk; sk = s3;
        pk[i] = (unsigned int)f2bf(r0) | ((unsigned int)f2bf(r1) << 16);
    }
    uint4* out = reinterpret_cast<uint4*>(rbf_buf + (size_t)s * 16);
    out[0] = make_uint4(pk[0], pk[1], pk[2], pk[3]);
    out[1] = make_uint4(pk[4], pk[5], pk[6], pk[7]);
}

// ---------------------------------------------------------------- bf16 weight prep (transposed [n][k])
__global__ __launch_bounds__(256) void prep_wt_kernel(
    const float* __restrict__ We1, const float* __restrict__ We2,
    const float* __restrict__ Wu1, const float* __restrict__ Wu2,
    short* __restrict__ wt1, short* __restrict__ wt2,
    short* __restrict__ wtu1, short* __restrict__ wtu2)
{
    int idx = blockIdx.x * 256 + threadIdx.x;
    if (idx < 5 * 32 * 96) {
        int l = idx / (32 * 96), r = idx % (32 * 96), n = r / 96, k = r % 96;
        float v = (k < 80) ? We1[((size_t)l * 80 + k) * 32 + n] : 0.0f;
        wt1[idx] = (short)f2bf(v);
    }
    if (idx < 5 * 32 * 32) {
        int l = idx / 1024, r = idx % 1024, n = r / 32, k = r % 32;
        wt2[idx]  = (short)f2bf(We2[((size_t)l * 32 + k) * 32 + n]);
        wtu2[idx] = (short)f2bf(Wu2[((size_t)l * 32 + k) * 32 + n]);
    }
    if (idx < 5 * 32 * 64) {
        int l = idx / 2048, r = idx % 2048, n = r / 64, k = r % 64;
        wtu1[idx] = (short)f2bf(Wu1[((size_t)l * 64 + k) * 32 + n]);
    }
}

// ---------------------------------------------------------------- node embed (writes fp32 x + bf16 xb)
__global__ __launch_bounds__(256) void node_embed_kernel(
    const float* __restrict__ u, const float* __restrict__ v,
    const float* __restrict__ bnorm, const float* __restrict__ yf,
    const float* __restrict__ Wn1, const float* __restrict__ bn1,
    const float* __restrict__ Wn2, const float* __restrict__ bn2,
    float* __restrict__ x, unsigned short* __restrict__ xb)
{
    int n = blockIdx.x * 256 + threadIdx.x;
    if (n >= N) return;

    float f[10];
    float4 uu = reinterpret_cast<const float4*>(u)[n];
    f[0] = uu.x; f[1] = uu.y; f[2] = uu.z; f[3] = uu.w;
    float4 v0 = reinterpret_cast<const float4*>(v)[2 * n];
    float4 v1 = reinterpret_cast<const float4*>(v)[2 * n + 1];
    f[4] = sqrtf(v0.x * v0.x + v0.y * v0.y);
    f[5] = sqrtf(v0.z * v0.z + v0.w * v0.w);
    f[6] = sqrtf(v1.x * v1.x + v1.y * v1.y);
    f[7] = sqrtf(v1.z * v1.z + v1.w * v1.w);
    float2 bb = reinterpret_cast<const float2*>(bnorm)[n];
    f[8] = sqrtf(bb.x * bb.x + bb.y * bb.y);
    float2 yy = reinterpret_cast<const float2*>(yf)[n];
    f[9] = sqrtf(yy.x * yy.x + yy.y * yy.y);

    float h[64];
    #pragma unroll
    for (int j = 0; j < 64; ++j) h[j] = bn1[j];
    #pragma unroll
    for (int i = 0; i < 10; ++i) {
        float t = f[i];
        #pragma unroll
        for (int j = 0; j < 64; ++j) h[j] = fmaf(t, Wn1[i * 64 + j], h[j]);
    }
    #pragma unroll
    for (int j = 0; j < 64; ++j) h[j] = silu_f(h[j]);

    float o[32];
    #pragma unroll
    for (int j = 0; j < 32; ++j) o[j] = bn2[j];
    #pragma unroll
    for (int i = 0; i < 64; ++i) {
        float t = h[i];
        #pragma unroll
        for (int j = 0; j < 32; ++j) o[j] = fmaf(t, Wn2[i * 32 + j], o[j]);
    }
    float4* xo = reinterpret_cast<float4*>(x + (size_t)n * 32);
    #pragma unroll
    for (int i = 0; i < 8; ++i)
        xo[i] = make_float4(o[4 * i], o[4 * i + 1], o[4 * i + 2], o[4 * i + 3]);

    unsigned int* xbu = reinterpret_cast<unsigned int*>(xb) + (size_t)n * 16;
    #pragma unroll
    for (int i = 0; i < 16; ++i)
        xbu[i] = (unsigned int)f2bf(o[2 * i]) | ((unsigned int)f2bf(o[2 * i + 1]) << 16);
}

// ---------------------------------------------------------------- fused layer v3.1
// v3 + fast-silu (rcp) + 32-bit gather addressing.
__global__ __launch_bounds__(256, 4) void layer_kernel(
    const int* __restrict__ deg, const int* __restrict__ start,
    const int* __restrict__ csr_col, const unsigned short* __restrict__ rbf_buf,
    const float* __restrict__ x_in, const unsigned short* __restrict__ xb_in,
    float* __restrict__ x_out, unsigned short* __restrict__ xb_out,
    const short* __restrict__ wt1, const float* __restrict__ b1,
    const short* __restrict__ wt2, const float* __restrict__ b2,
    const short* __restrict__ wtu1, const float* __restrict__ bu1,
    const short* __restrict__ wtu2, const float* __restrict__ bu2)
{
    __shared__ unsigned short lsh[4][16 * 34];   // sh  (bf16), stride 34
    __shared__ unsigned short agb[4][16 * 34];   // ag  (bf16)
    __shared__ unsigned short hub[4][16 * 34];   // hu  (bf16)
    __shared__ float lx[4][16 * 33];             // x   (fp32), stride 33
    __shared__ float lrp[4][16 * 33];            // rowpart b1 + x@W1[0:32,:] (fp32)
    __shared__ float ldg[4][16];
    __shared__ float livd[4][16];

    int t = threadIdx.x;
    int w = t >> 6;
    int lane = t & 63;
    int quad = lane >> 4;
    int ml = lane & 15;
    int wid = blockIdx.x * 4 + w;
    int nbase = __builtin_amdgcn_readfirstlane(wid * NPW);
    if (nbase >= N) return;   // N % 16 == 0, so valid waves own full batches

    // ---- batch metadata: lane ml holds node ml's start/deg
    int vs = start[nbase + ml];
    int vd = deg[nbase + ml];

    // ---- edge-phase B fragments (wt1 [32][96])
    const short8* wp = reinterpret_cast<const short8*>(wt1);
    short8 B00 = wp[(ml     ) * 12 + 0 * 4 + quad];
    short8 B01 = wp[(ml     ) * 12 + 1 * 4 + quad];
    short8 B02 = wp[(ml     ) * 12 + 2 * 4 + quad];
    short8 B10 = wp[(ml + 16) * 12 + 0 * 4 + quad];
    short8 B11 = wp[(ml + 16) * 12 + 1 * 4 + quad];
    short8 B12 = wp[(ml + 16) * 12 + 2 * 4 + quad];

    // node-phase / rowpart x A-fragment (A[m=node ml][k=quad*8+j])
    short8 Ax = ld_xb(xb_in, nbase + ml, quad);

    float b1j0 = b1[ml];
    float b1j1 = b1[ml + 16];

    // ---- zero sh, preload x into LDS, stash deg floats
    unsigned short* lshp = lsh[w];
    for (int k = lane; k < 16 * 34; k += 64) lshp[k] = 0;
    {
        const float* xs = x_in + (size_t)nbase * 32;
        float* lxp = lx[w];
        #pragma unroll
        for (int k = 0; k < 8; ++k) {
            int idx = lane * 8 + k;
            lxp[(idx >> 5) * 33 + (idx & 31)] = xs[idx];
        }
    }
    if (lane < 16) {
        ldg[w][lane] = (float)vd;
        livd[w][lane] = 1.0f / fmaxf((float)vd, 1.0f);
    }

    // ---- hoisted row-node partial: rp[m][j] = b1[j] + x[m] @ W1[0:32, j]
    float* rpp = lrp[w];
    {
        f32x4 rp0 = {b1j0, b1j0, b1j0, b1j0};
        f32x4 rp1 = {b1j1, b1j1, b1j1, b1j1};
        rp0 = __builtin_amdgcn_mfma_f32_16x16x32_bf16(Ax, B00, rp0, 0, 0, 0);
        rp1 = __builtin_amdgcn_mfma_f32_16x16x32_bf16(Ax, B10, rp1, 0, 0, 0);
        int row = quad * 4;
        #pragma unroll
        for (int r = 0; r < 4; ++r) {
            rpp[(row + r) * 33 + ml]      = rp0[r];
            rpp[(row + r) * 33 + ml + 16] = rp1[r];
        }
    }
    __builtin_amdgcn_wave_barrier();

    // ---- software-pipelined edge loop
    const short8 Z8 = {0, 0, 0, 0, 0, 0, 0, 0};
    int i0 = 0, t0 = -1; adv(i0, t0, vd);
    int i1 = i0, t1 = t0; adv(i1, t1, vd);
    int i2 = i1, t2 = t1; adv(i2, t2, vd);

    int slot0 = slotOf(i0, t0, vs, vd, ml);
    int slot1 = slotOf(i1, t1, vs, vd, ml);
    int colCur  = csr_col[slot0];
    int colNext = csr_col[slot1];
    short8 A1c = ld_xb(xb_in, colCur, quad);
    short8 A2c = Z8;
    if (quad < 2) A2c = ld_rbf(rbf_buf, slot0, quad);

    float colp0 = 0.0f, colp1 = 0.0f;
    while (i0 < 16) {
        // stage 2: col two ahead
        int slot2 = slotOf(i2, t2, vs, vd, ml);
        int colNN = csr_col[slot2];
        // stage 1: fragments one ahead
        short8 A1n = ld_xb(xb_in, colNext, quad);
        short8 A2n = Z8;
        if (quad < 2) A2n = ld_rbf(rbf_buf, slot1, quad);

        // stage 0: compute current tile (acc seeded with hoisted rowpart + b1)
        float rpa = rpp[i0 * 33 + ml];
        float rpb = rpp[i0 * 33 + ml + 16];
        f32x4 acc0 = {rpa, rpa, rpa, rpa};
        f32x4 acc1 = {rpb, rpb, rpb, rpb};
        acc0 = __builtin_amdgcn_mfma_f32_16x16x32_bf16(A1c, B01, acc0, 0, 0, 0);
        acc0 = __builtin_amdgcn_mfma_f32_16x16x32_bf16(A2c, B02, acc0, 0, 0, 0);
        acc1 = __builtin_amdgcn_mfma_f32_16x16x32_bf16(A1c, B11, acc1, 0, 0, 0);
        acc1 = __builtin_amdgcn_mfma_f32_16x16x32_bf16(A2c, B12, acc1, 0, 0, 0);

        int dg0 = rl(vd, i0);
        int rowbase = t0 * 16 + quad * 4;
        #pragma unroll
        for (int r = 0; r < 4; ++r) {
            bool vld = (rowbase + r) < dg0;
            colp0 += vld ? silu_f(acc0[r]) : 0.0f;
            colp1 += vld ? silu_f(acc1[r]) : 0.0f;
        }
        if (t0 == ((dg0 + 15) >> 4) - 1) {   // last tile of node i0 (uniform)
            colp0 += __shfl_xor(colp0, 16, 64);
            colp0 += __shfl_xor(colp0, 32, 64);
            colp1 += __shfl_xor(colp1, 16, 64);
            colp1 += __shfl_xor(colp1, 32, 64);
            if (quad == 0) {
                lshp[i0 * 34 + ml]      = f2bf(colp0);
                lshp[i0 * 34 + ml + 16] = f2bf(colp1);
            }
            colp0 = 0.0f; colp1 = 0.0f;
        }

        // rotate pipeline
        A1c = A1n; A2c = A2n;
        colNext = colNN; slot1 = slot2;
        i0 = i1; t0 = t1; i1 = i2; t1 = t2;
        adv(i2, t2, vd);
    }
    __builtin_amdgcn_wave_barrier();

    // ---- node phase: 16-node batch, 8 MFMAs
    const short8* w2p = reinterpret_cast<const short8*>(wt2);
    short8 Bw2_0 = w2p[(ml     ) * 4 + quad];
    short8 Bw2_1 = w2p[(ml + 16) * 4 + quad];
    const short8* u1p = reinterpret_cast<const short8*>(wtu1);
    short8 Bu1_00 = u1p[(ml     ) * 8 + quad];       // k 0..31 (x)
    short8 Bu1_10 = u1p[(ml     ) * 8 + 4 + quad];   // k 32..63 (ag)
    short8 Bu1_01 = u1p[(ml + 16) * 8 + quad];
    short8 Bu1_11 = u1p[(ml + 16) * 8 + 4 + quad];
    const short8* u2p = reinterpret_cast<const short8*>(wtu2);
    short8 Bu2_0 = u2p[(ml     ) * 4 + quad];
    short8 Bu2_1 = u2p[(ml + 16) * 4 + quad];

    // sh @ W2
    short8 Ash = *reinterpret_cast<const short8*>(lshp + ml * 34 + quad * 8);
    f32x4 c0 = {0.0f, 0.0f, 0.0f, 0.0f};
    f32x4 c1 = {0.0f, 0.0f, 0.0f, 0.0f};
    c0 = __builtin_amdgcn_mfma_f32_16x16x32_bf16(Ash, Bw2_0, c0, 0, 0, 0);
    c1 = __builtin_amdgcn_mfma_f32_16x16x32_bf16(Ash, Bw2_1, c1, 0, 0, 0);
    float b2c0 = b2[ml], b2c1 = b2[ml + 16];
    unsigned short* agp = agb[w];
    int row = quad * 4;
    #pragma unroll
    for (int r = 0; r < 4; ++r) {
        float fd = ldg[w][row + r];
        float iv = livd[w][row + r];
        agp[(row + r) * 34 + ml]      = f2bf((c0[r] + fd * b2c0) * iv);
        agp[(row + r) * 34 + ml + 16] = f2bf((c1[r] + fd * b2c1) * iv);
    }
    __builtin_amdgcn_wave_barrier();

    // [x ; ag] @ Wu1
    short8 Aag = *reinterpret_cast<const short8*>(agp + ml * 34 + quad * 8);
    f32x4 d0 = {0.0f, 0.0f, 0.0f, 0.0f};
    f32x4 d1 = {0.0f, 0.0f, 0.0f, 0.0f};
    d0 = __builtin_amdgcn_mfma_f32_16x16x32_bf16(Ax,  Bu1_00, d0, 0, 0, 0);
    d0 = __builtin_amdgcn_mfma_f32_16x16x32_bf16(Aag, Bu1_10, d0, 0, 0, 0);
    d1 = __builtin_amdgcn_mfma_f32_16x16x32_bf16(Ax,  Bu1_01, d1, 0, 0, 0);
    d1 = __builtin_amdgcn_mfma_f32_16x16x32_bf16(Aag, Bu1_11, d1, 0, 0, 0);
    float bu1c0 = bu1[ml], bu1c1 = bu1[ml + 16];
    unsigned short* hup = hub[w];
    #pragma unroll
    for (int r = 0; r < 4; ++r) {
        hup[(row + r) * 34 + ml]      = f2bf(silu_f(d0[r] + bu1c0));
        hup[(row + r) * 34 + ml + 16] = f2bf(silu_f(d1[r] + bu1c1));
    }
    __builtin_amdgcn_wave_barrier();

    // hu @ Wu2 ; residual + store
    short8 Ahu = *reinterpret_cast<const short8*>(hup + ml * 34 + quad * 8);
    f32x4 e0 = {0.0f, 0.0f, 0.0f, 0.0f};
    f32x4 e1 = {0.0f, 0.0f, 0.0f, 0.0f};
    e0 = __builtin_amdgcn_mfma_f32_16x16x32_bf16(Ahu, Bu2_0, e0, 0, 0, 0);
    e1 = __builtin_amdgcn_mfma_f32_16x16x32_bf16(Ahu, Bu2_1, e1, 0, 0, 0);
    float bu2c0 = bu2[ml], bu2c1 = bu2[ml + 16];
    #pragma unroll
    for (int r = 0; r < 4; ++r) {
        int nn = nbase + row + r;
        float o0 = e0[r] + bu2c0 + lx[w][(row + r) * 33 + ml];
        float o1 = e1[r] + bu2c1 + lx[w][(row + r) * 33 + ml + 16];
        x_out[(size_t)nn * 32 + ml]      = o0;
        x_out[(size_t)nn * 32 + ml + 16] = o1;
        xb_out[(size_t)nn * 32 + ml]      = f2bf(o0);
        xb_out[(size_t)nn * 32 + ml + 16] = f2bf(o1);
    }
}

// ---------------------------------------------------------------- LN + heads
__global__ __launch_bounds__(256) void final_kernel(
    const float* __restrict__ x, const float* __restrict__ u,
    const float* __restrict__ v,
    const float* __restrict__ ln_g, const float* __restrict__ ln_b,
    const float* __restrict__ Wr1, const float* __restrict__ br1,
    const float* __restrict__ Wr2, const float* __restrict__ br2,
    const float* __restrict__ Ws1, const float* __restrict__ bs1,
    const float* __restrict__ Ws2, const float* __restrict__ bs2,
    float* __restrict__ out)
{
    int n = blockIdx.x * 256 + threadIdx.x;
    if (n >= N) return;

    float a[32];
    const float4* x4 = reinterpret_cast<const float4*>(x + (size_t)n * 32);
    #pragma unroll
    for (int i = 0; i < 8; ++i) {
        float4 t = x4[i];
        a[4 * i] = t.x; a[4 * i + 1] = t.y; a[4 * i + 2] = t.z; a[4 * i + 3] = t.w;
    }
    float mu = 0.0f;
    #pragma unroll
    for (int i = 0; i < 32; ++i) mu += a[i];
    mu *= (1.0f / 32.0f);
    float var = 0.0f;
    #pragma unroll
    for (int i = 0; i < 32; ++i) { float dlt = a[i] - mu; var += dlt * dlt; }
    var *= (1.0f / 32.0f);
    float rs = rsqrtf(var + 1e-5f);
    #pragma unroll
    for (int i = 0; i < 32; ++i) a[i] = (a[i] - mu) * rs * ln_g[i] + ln_b[i];

    float o0 = br2[0], o1 = br2[1], o2 = bs2[0];
    #pragma unroll 1
    for (int j = 0; j < 96; ++j) {
        float hr = br1[j];
        float hs = bs1[j];
        #pragma unroll
        for (int i = 0; i < 32; ++i) {
            hr = fmaf(a[i], Wr1[i * 96 + j], hr);
            hs = fmaf(a[i], Ws1[i * 96 + j], hs);
        }
        hr = silu_f(hr);
        hs = silu_f(hs);
        o0 = fmaf(hr, Wr2[2 * j], o0);
        o1 = fmaf(hr, Wr2[2 * j + 1], o1);
        o2 = fmaf(hs, Ws2[j], o2);
    }
    out[n] = u[n * 4 + 3] + o2;
    out[N + 2 * n]     = o0 + v[n * 8 + 6];
    out[N + 2 * n + 1] = o1 + v[n * 8 + 7];
}

} // anonymous namespace

extern "C" void kernel_launch(void* const* d_in, const int* in_sizes, int n_in,
                              void* d_out, int out_size, void* d_ws, size_t ws_size,
                              hipStream_t stream)
{
    const float* u    = (const float*)d_in[0];
    const float* v    = (const float*)d_in[1];
    const float* bno  = (const float*)d_in[2];
    const float* yf   = (const float*)d_in[4];
    const float* pos  = (const float*)d_in[5];
    const int*   ei   = (const int*)d_in[6];
    const float* Wn1  = (const float*)d_in[7];
    const float* bn1  = (const float*)d_in[8];
    const float* Wn2  = (const float*)d_in[9];
    const float* bn2  = (const float*)d_in[10];
    const float* We1  = (const float*)d_in[11];
    const float* be1  = (const float*)d_in[12];
    const float* We2  = (const float*)d_in[13];
    const float* be2  = (const float*)d_in[14];
    const float* Wu1  = (const float*)d_in[15];
    const float* bu1  = (const float*)d_in[16];
    const float* Wu2  = (const float*)d_in[17];
    const float* bu2  = (const float*)d_in[18];
    const float* ln_g = (const float*)d_in[19];
    const float* ln_b = (const float*)d_in[20];
    const float* Wr1  = (const float*)d_in[21];
    const float* br1  = (const float*)d_in[22];
    const float* Wr2  = (const float*)d_in[23];
    const float* br2  = (const float*)d_in[24];
    const float* Ws1  = (const float*)d_in[25];
    const float* bs1  = (const float*)d_in[26];
    const float* Ws2  = (const float*)d_in[27];
    const float* bs2  = (const float*)d_in[28];
    float* out = (float*)d_out;

    // workspace layout (16B-aligned sections)
    int*   deg      = (int*)d_ws;                            // N
    int*   start    = deg + N;                               // N
    int*   bsum     = start + N;                             // 512
    int*   csr_col  = bsum + 512;                            // E ints
    unsigned short* rbf = (unsigned short*)(csr_col + E);    // E*16 bf16 (51.2 MB)
    float* x0       = (float*)(rbf + (size_t)E * 16);        // N*32 f32
    float* x1       = x0 + (size_t)N * S;                    // N*32 f32
    unsigned short* xb0 = (unsigned short*)(x1 + (size_t)N * S);   // N*32 bf16
    unsigned short* xb1 = xb0 + (size_t)N * S;               // N*32 bf16
    short* wt1      = (short*)(xb1 + (size_t)N * S);         // 5*32*96
    short* wt2      = wt1 + 5 * 32 * 96;                     // 5*32*32
    short* wtu1     = wt2 + 5 * 32 * 32;                     // 5*32*64
    short* wtu2     = wtu1 + 5 * 32 * 64;                    // 5*32*32
    int*   deg8     = (int*)(wtu2 + 5 * 32 * 32);            // 8*N (XCD-private counters)

    // transient aliases (dead before node_embed writes x0/xb0):
    //   cd: E*8B packed {col,dist}  == x0..x1 region (E*8 == N*32*4 exactly)
    //   ke: E*4B per-edge rank      == xb0  region   (E*4 == N*32*2 exactly)
    unsigned long long* cd = (unsigned long long*)x0;
    int* ke = (int*)xb0;

    const int egrid = (E + 255) / 256;

    hipMemsetAsync(deg8, 0, (size_t)NXCD * N * sizeof(int), stream);
    deg_kernel<<<egrid, 256, 0, stream>>>(ei, deg8, ke);
    combine_kernel<<<NB, 256, 0, stream>>>(deg8, deg);
    scanA<<<NB, 256, 0, stream>>>(deg, bsum);
    scanB<<<1, 512, 0, stream>>>(bsum);
    scanC<<<NB, 256, 0, stream>>>(deg, bsum, start);
    fill_kernel<<<egrid, 256, 0, stream>>>(ei, pos, start, ke, deg8, cd);
    expand_kernel<<<egrid, 256, 0, stream>>>(cd, csr_col, rbf);
    prep_wt_kernel<<<60, 256, 0, stream>>>(We1, We2, Wu1, Wu2, wt1, wt2, wtu1, wtu2);

    node_embed_kernel<<<NB, 256, 0, stream>>>(u, v, bno, yf, Wn1, bn1, Wn2, bn2,
                                              x0, xb0);

    float* xin = x0;  float* xout = x1;
    unsigned short* xbin = xb0;  unsigned short* xbout = xb1;
    for (int l = 0; l < L; ++l) {
        layer_kernel<<<LB2, 256, 0, stream>>>(
            deg, start, csr_col, rbf, xin, xbin, xout, xbout,
            wt1 + (size_t)l * 32 * 96,  be1 + (size_t)l * 32,
            wt2 + (size_t)l * 32 * 32,  be2 + (size_t)l * 32,
            wtu1 + (size_t)l * 32 * 64, bu1 + (size_t)l * 32,
            wtu2 + (size_t)l * 32 * 32, bu2 + (size_t)l * 32);
        float* tf = xin; xin = xout; xout = tf;
        unsigned short* tb = xbin; xbin = xbout; xbout = tb;
    }

    final_kernel<<<NB, 256, 0, stream>>>(xin, u, v, ln_g, ln_b,
                                         Wr1, br1, Wr2, br2,
                                         Ws1, bs1, Ws2, bs2, out);
}

// Round 4
// 606.954 us; speedup vs baseline: 1.0029x; 1.0029x over previous
//
#include <hip/hip_runtime.h>
#include <cmath>

namespace {

constexpr int N = 100000;
constexpr int E = 1600000;
constexpr int S = 32;           // hidden
constexpr int L = 5;            // layers
constexpr int NB = (N + 255) / 256;   // node-per-thread kernels
constexpr int NPW = 16;               // nodes per wave in layer kernel
constexpr int LB2 = (N + 63) / 64;    // 1563 blocks (4 waves/block, 16 nodes/wave)
constexpr int NXCD = 8;
constexpr float PI_F    = 3.14159265358979323846f;
constexpr float SQRT2_F = 1.41421356237309515f;

typedef __attribute__((ext_vector_type(8))) short short8;   // 8 x bf16
typedef __attribute__((ext_vector_type(4))) float f32x4;

// fast silu: v_rcp_f32 instead of IEEE division (saves ~10 VALU instrs/call)
__device__ __forceinline__ float silu_f(float x) {
    return x * __builtin_amdgcn_rcpf(1.0f + __expf(-x));
}

// float -> bf16 bits, round-to-nearest-even
__device__ __forceinline__ unsigned short f2bf(float f) {
    unsigned int u = __float_as_uint(f);
    u = (u + 0x7FFFu + ((u >> 16) & 1u)) >> 16;
    return (unsigned short)u;
}

__device__ __forceinline__ int rl(int v, int i) {
    return __builtin_amdgcn_readlane(v, i);
}

// physical XCD id of this wave (gfx940+: HW_REG_XCC_ID; HW-verified m09)
__device__ __forceinline__ int xcc_id() {
    int id;
    asm("s_getreg_b32 %0, hwreg(HW_REG_XCC_ID)" : "=s"(id));
    return id & (NXCD - 1);
}

// XCD-local returning atomic add: sc0 (return old) WITHOUT sc1 -> the RMW is
// performed in this XCD's L2 (coherent across all CUs of the XCD only).
// Safe here because the target slice is indexed by the wave's own XCC_ID.
__device__ __forceinline__ int atomic_add_xcd(int* p, int v) {
    int old;
    asm volatile("global_atomic_add %0, %1, %2, off sc0\n\t"
                 "s_waitcnt vmcnt(0)"
                 : "=&v"(old) : "v"(p), "v"(v) : "memory");
    return old;
}

// 32-bit byte-offset gather of a 16B xb fragment: base + col*64 + quad*16
__device__ __forceinline__ short8 ld_xb(const unsigned short* base, int col, int quad) {
    unsigned off = ((unsigned)col << 6) | ((unsigned)quad << 4);
    return *reinterpret_cast<const short8*>(reinterpret_cast<const char*>(base) + off);
}

// 32-bit byte-offset read of an rbf half-row: base + slot*32 + quad*16
__device__ __forceinline__ short8 ld_rbf(const unsigned short* base, int slot, int quad) {
    unsigned off = ((unsigned)slot << 5) | ((unsigned)quad << 4);
    return *reinterpret_cast<const short8*>(reinterpret_cast<const char*>(base) + off);
}

// advance (i,t) to the next tile of this wave's 16-node batch (uniform)
__device__ __forceinline__ void adv(int& i, int& t, int vd) {
    ++t;
    while (i < 16) {
        int dgi = rl(vd, i);
        int nt = (dgi + 15) >> 4;
        if (t < nt) break;
        t = 0; ++i;
    }
}

// CSR slot for (i,t) at lane row ml; clamped into the node's own range
__device__ __forceinline__ int slotOf(int i, int t, int vs, int vd, int ml) {
    if (i >= 16) return 0;
    int s0 = rl(vs, i);
    int dg = rl(vd, i);
    int smax = s0 + ((dg > 0) ? dg : 1) - 1;
    int s = s0 + t * 16 + ml;
    return min(s, smax);
}

// ---------------------------------------------------------------- degree count, XCD-local atomics
// Partition p = the wave's PHYSICAL XCD id -> slice p is only ever touched from
// XCD p, so an XCD-local (no-sc1) atomic is correct by construction, resolves in
// the local L2, and never pays the device-coherence write-through.
__global__ __launch_bounds__(256) void deg_kernel(
    const int* __restrict__ ei, int* __restrict__ deg8, int* __restrict__ ke)
{
    int e = blockIdx.x * 256 + threadIdx.x;
    if (e >= E) return;
    int p = xcc_id();
    int lr = atomic_add_xcd(&deg8[p * N + ei[e]], 1);
    ke[e] = (p << 24) | lr;   // partition + local rank, coalesced store
}

// ---------------------------------------------------------------- combine partitions
// deg[n] = sum_p deg8[p][n]; deg8[p][n] <- exclusive prefix over p (partition base)
__global__ __launch_bounds__(256) void combine_kernel(
    int* __restrict__ deg8, int* __restrict__ deg)
{
    int n = blockIdx.x * 256 + threadIdx.x;
    if (n >= N) return;
    int s = 0;
    #pragma unroll
    for (int p = 0; p < NXCD; ++p) {
        int c = deg8[p * N + n];
        deg8[p * N + n] = s;
        s += c;
    }
    deg[n] = s;
}

// ---------------------------------------------------------------- scan (3-kernel hierarchical)
__global__ __launch_bounds__(256) void scanA(
    const int* __restrict__ deg, int* __restrict__ bsum)
{
    __shared__ int sd[256];
    int t = threadIdx.x;
    int n = blockIdx.x * 256 + t;
    sd[t] = (n < N) ? deg[n] : 0;
    __syncthreads();
    #pragma unroll
    for (int s = 128; s > 0; s >>= 1) {
        if (t < s) sd[t] += sd[t + s];
        __syncthreads();
    }
    if (t == 0) bsum[blockIdx.x] = sd[0];
}

__global__ __launch_bounds__(512) void scanB(int* __restrict__ bsum)
{
    __shared__ int sd[512];
    int t = threadIdx.x;
    sd[t] = (t < NB) ? bsum[t] : 0;
    __syncthreads();
    #pragma unroll
    for (int off = 1; off < 512; off <<= 1) {
        int v = (t >= off) ? sd[t - off] : 0;
        __syncthreads();
        sd[t] += v;
        __syncthreads();
    }
    if (t < NB) bsum[t] = (t == 0) ? 0 : sd[t - 1];   // exclusive
}

__global__ __launch_bounds__(256) void scanC(
    const int* __restrict__ deg, const int* __restrict__ bsum,
    int* __restrict__ start)
{
    __shared__ int sd[256];
    int t = threadIdx.x;
    int n = blockIdx.x * 256 + t;
    int v = (n < N) ? deg[n] : 0;
    sd[t] = v;
    __syncthreads();
    #pragma unroll
    for (int off = 1; off < 256; off <<= 1) {
        int w = (t >= off) ? sd[t - off] : 0;
        __syncthreads();
        sd[t] += w;
        __syncthreads();
    }
    if (n < N) start[n] = bsum[blockIdx.x] + sd[t] - v;  // exclusive
}

// ---------------------------------------------------------------- CSR fill: minimal 8B scatter
__global__ __launch_bounds__(256) void fill_kernel(
    const int* __restrict__ ei, const float* __restrict__ pos,
    const int* __restrict__ start, const int* __restrict__ ke,
    const int* __restrict__ deg8, unsigned long long* __restrict__ cd)
{
    int e = blockIdx.x * 256 + threadIdx.x;
    if (e >= E) return;
    int r = ei[e];
    int c = ei[E + e];
    float2 pr = reinterpret_cast<const float2*>(pos)[r];
    float2 pc = reinterpret_cast<const float2*>(pos)[c];
    float dx = pr.x - pc.x, dy = pr.y - pc.y;
    float d = sqrtf(dx * dx + dy * dy);   // pos-mean cancels
    int pk = ke[e];
    int p = pk >> 24;
    int lr = pk & 0xFFFFFF;
    int s = start[r] + deg8[p * N + r] + lr;
    cd[s] = (unsigned long long)(unsigned int)c |
            ((unsigned long long)__float_as_uint(d) << 32);
}

// ---------------------------------------------------------------- CSR expand: fully streaming
__global__ __launch_bounds__(256) void expand_kernel(
    const unsigned long long* __restrict__ cd,
    int* __restrict__ csr_col, unsigned short* __restrict__ rbf_buf)
{
    int s = blockIdx.x * 256 + threadIdx.x;
    if (s >= E) return;
    unsigned long long t = cd[s];
    int c = (int)(unsigned int)(t & 0xffffffffull);
    float d = __uint_as_float((unsigned int)(t >> 32));
    csr_col[s] = c;

    float s1 = __sinf(PI_F * d);
    float c1 = __cosf(PI_F * d);
    float inv = SQRT2_F / (d + 1e-8f);
    float tc = 2.0f * c1;
    float sk = s1, skm = 0.0f;
    unsigned int pk[8];
    #pragma unroll
    for (int i = 0; i < 8; ++i) {
        float r0 = sk * inv;
        float s2 = tc * sk - skm; skm = sk; sk = s2;
        float r1 = sk * inv;
        float s3 = tc * sk - skm; skm = sk; sk = s3;
        pk[i] = (unsigned int)f2bf(r0) | ((unsigned int)f2bf(r1) << 16);
    }
    uint4* out = reinterpret_cast<uint4*>(rbf_buf + (size_t)s * 16);
    out[0] = make_uint4(pk[0], pk[1], pk[2], pk[3]);
    out[1] = make_uint4(pk[4], pk[5], pk[6], pk[7]);
}

// ---------------------------------------------------------------- bf16 weight prep (transposed [n][k])
__global__ __launch_bounds__(256) void prep_wt_kernel(
    const float* __restrict__ We1, const float* __restrict__ We2,
    const float* __restrict__ Wu1, const float* __restrict__ Wu2,
    short* __restrict__ wt1, short* __restrict__ wt2,
    short* __restrict__ wtu1, short* __restrict__ wtu2)
{
    int idx = blockIdx.x * 256 + threadIdx.x;
    if (idx < 5 * 32 * 96) {
        int l = idx / (32 * 96), r = idx % (32 * 96), n = r / 96, k = r % 96;
        float v = (k < 80) ? We1[((size_t)l * 80 + k) * 32 + n] : 0.0f;
        wt1[idx] = (short)f2bf(v);
    }
    if (idx < 5 * 32 * 32) {
        int l = idx / 1024, r = idx % 1024, n = r / 32, k = r % 32;
        wt2[idx]  = (short)f2bf(We2[((size_t)l * 32 + k) * 32 + n]);
        wtu2[idx] = (short)f2bf(Wu2[((size_t)l * 32 + k) * 32 + n]);
    }
    if (idx < 5 * 32 * 64) {
        int l = idx / 2048, r = idx % 2048, n = r / 64, k = r % 64;
        wtu1[idx] = (short)f2bf(Wu1[((size_t)l * 64 + k) * 32 + n]);
    }
}

// ---------------------------------------------------------------- node embed (writes fp32 x + bf16 xb)
__global__ __launch_bounds__(256) void node_embed_kernel(
    const float* __restrict__ u, const float* __restrict__ v,
    const float* __restrict__ bnorm, const float* __restrict__ yf,
    const float* __restrict__ Wn1, const float* __restrict__ bn1,
    const float* __restrict__ Wn2, const float* __restrict__ bn2,
    float* __restrict__ x, unsigned short* __restrict__ xb)
{
    int n = blockIdx.x * 256 + threadIdx.x;
    if (n >= N) return;

    float f[10];
    float4 uu = reinterpret_cast<const float4*>(u)[n];
    f[0] = uu.x; f[1] = uu.y; f[2] = uu.z; f[3] = uu.w;
    float4 v0 = reinterpret_cast<const float4*>(v)[2 * n];
    float4 v1 = reinterpret_cast<const float4*>(v)[2 * n + 1];
    f[4] = sqrtf(v0.x * v0.x + v0.y * v0.y);
    f[5] = sqrtf(v0.z * v0.z + v0.w * v0.w);
    f[6] = sqrtf(v1.x * v1.x + v1.y * v1.y);
    f[7] = sqrtf(v1.z * v1.z + v1.w * v1.w);
    float2 bb = reinterpret_cast<const float2*>(bnorm)[n];
    f[8] = sqrtf(bb.x * bb.x + bb.y * bb.y);
    float2 yy = reinterpret_cast<const float2*>(yf)[n];
    f[9] = sqrtf(yy.x * yy.x + yy.y * yy.y);

    float h[64];
    #pragma unroll
    for (int j = 0; j < 64; ++j) h[j] = bn1[j];
    #pragma unroll
    for (int i = 0; i < 10; ++i) {
        float t = f[i];
        #pragma unroll
        for (int j = 0; j < 64; ++j) h[j] = fmaf(t, Wn1[i * 64 + j], h[j]);
    }
    #pragma unroll
    for (int j = 0; j < 64; ++j) h[j] = silu_f(h[j]);

    float o[32];
    #pragma unroll
    for (int j = 0; j < 32; ++j) o[j] = bn2[j];
    #pragma unroll
    for (int i = 0; i < 64; ++i) {
        float t = h[i];
        #pragma unroll
        for (int j = 0; j < 32; ++j) o[j] = fmaf(t, Wn2[i * 32 + j], o[j]);
    }
    float4* xo = reinterpret_cast<float4*>(x + (size_t)n * 32);
    #pragma unroll
    for (int i = 0; i < 8; ++i)
        xo[i] = make_float4(o[4 * i], o[4 * i + 1], o[4 * i + 2], o[4 * i + 3]);

    unsigned int* xbu = reinterpret_cast<unsigned int*>(xb) + (size_t)n * 16;
    #pragma unroll
    for (int i = 0; i < 16; ++i)
        xbu[i] = (unsigned int)f2bf(o[2 * i]) | ((unsigned int)f2bf(o[2 * i + 1]) << 16);
}

// ---------------------------------------------------------------- fused layer v3.1
// v3 + fast-silu (rcp) + 32-bit gather addressing.
__global__ __launch_bounds__(256, 4) void layer_kernel(
    const int* __restrict__ deg, const int* __restrict__ start,
    const int* __restrict__ csr_col, const unsigned short* __restrict__ rbf_buf,
    const float* __restrict__ x_in, const unsigned short* __restrict__ xb_in,
    float* __restrict__ x_out, unsigned short* __restrict__ xb_out,
    const short* __restrict__ wt1, const float* __restrict__ b1,
    const short* __restrict__ wt2, const float* __restrict__ b2,
    const short* __restrict__ wtu1, const float* __restrict__ bu1,
    const short* __restrict__ wtu2, const float* __restrict__ bu2)
{
    __shared__ unsigned short lsh[4][16 * 34];   // sh  (bf16), stride 34
    __shared__ unsigned short agb[4][16 * 34];   // ag  (bf16)
    __shared__ unsigned short hub[4][16 * 34];   // hu  (bf16)
    __shared__ float lx[4][16 * 33];             // x   (fp32), stride 33
    __shared__ float lrp[4][16 * 33];            // rowpart b1 + x@W1[0:32,:] (fp32)
    __shared__ float ldg[4][16];
    __shared__ float livd[4][16];

    int t = threadIdx.x;
    int w = t >> 6;
    int lane = t & 63;
    int quad = lane >> 4;
    int ml = lane & 15;
    int wid = blockIdx.x * 4 + w;
    int nbase = __builtin_amdgcn_readfirstlane(wid * NPW);
    if (nbase >= N) return;   // N % 16 == 0, so valid waves own full batches

    // ---- batch metadata: lane ml holds node ml's start/deg
    int vs = start[nbase + ml];
    int vd = deg[nbase + ml];

    // ---- edge-phase B fragments (wt1 [32][96])
    const short8* wp = reinterpret_cast<const short8*>(wt1);
    short8 B00 = wp[(ml     ) * 12 + 0 * 4 + quad];
    short8 B01 = wp[(ml     ) * 12 + 1 * 4 + quad];
    short8 B02 = wp[(ml     ) * 12 + 2 * 4 + quad];
    short8 B10 = wp[(ml + 16) * 12 + 0 * 4 + quad];
    short8 B11 = wp[(ml + 16) * 12 + 1 * 4 + quad];
    short8 B12 = wp[(ml + 16) * 12 + 2 * 4 + quad];

    // node-phase / rowpart x A-fragment (A[m=node ml][k=quad*8+j])
    short8 Ax = ld_xb(xb_in, nbase + ml, quad);

    float b1j0 = b1[ml];
    float b1j1 = b1[ml + 16];

    // ---- zero sh, preload x into LDS, stash deg floats
    unsigned short* lshp = lsh[w];
    for (int k = lane; k < 16 * 34; k += 64) lshp[k] = 0;
    {
        const float* xs = x_in + (size_t)nbase * 32;
        float* lxp = lx[w];
        #pragma unroll
        for (int k = 0; k < 8; ++k) {
            int idx = lane * 8 + k;
            lxp[(idx >> 5) * 33 + (idx & 31)] = xs[idx];
        }
    }
    if (lane < 16) {
        ldg[w][lane] = (float)vd;
        livd[w][lane] = 1.0f / fmaxf((float)vd, 1.0f);
    }

    // ---- hoisted row-node partial: rp[m][j] = b1[j] + x[m] @ W1[0:32, j]
    float* rpp = lrp[w];
    {
        f32x4 rp0 = {b1j0, b1j0, b1j0, b1j0};
        f32x4 rp1 = {b1j1, b1j1, b1j1, b1j1};
        rp0 = __builtin_amdgcn_mfma_f32_16x16x32_bf16(Ax, B00, rp0, 0, 0, 0);
        rp1 = __builtin_amdgcn_mfma_f32_16x16x32_bf16(Ax, B10, rp1, 0, 0, 0);
        int row = quad * 4;
        #pragma unroll
        for (int r = 0; r < 4; ++r) {
            rpp[(row + r) * 33 + ml]      = rp0[r];
            rpp[(row + r) * 33 + ml + 16] = rp1[r];
        }
    }
    __builtin_amdgcn_wave_barrier();

    // ---- software-pipelined edge loop
    const short8 Z8 = {0, 0, 0, 0, 0, 0, 0, 0};
    int i0 = 0, t0 = -1; adv(i0, t0, vd);
    int i1 = i0, t1 = t0; adv(i1, t1, vd);
    int i2 = i1, t2 = t1; adv(i2, t2, vd);

    int slot0 = slotOf(i0, t0, vs, vd, ml);
    int slot1 = slotOf(i1, t1, vs, vd, ml);
    int colCur  = csr_col[slot0];
    int colNext = csr_col[slot1];
    short8 A1c = ld_xb(xb_in, colCur, quad);
    short8 A2c = Z8;
    if (quad < 2) A2c = ld_rbf(rbf_buf, slot0, quad);

    float colp0 = 0.0f, colp1 = 0.0f;
    while (i0 < 16) {
        // stage 2: col two ahead
        int slot2 = slotOf(i2, t2, vs, vd, ml);
        int colNN = csr_col[slot2];
        // stage 1: fragments one ahead
        short8 A1n = ld_xb(xb_in, colNext, quad);
        short8 A2n = Z8;
        if (quad < 2) A2n = ld_rbf(rbf_buf, slot1, quad);

        // stage 0: compute current tile (acc seeded with hoisted rowpart + b1)
        float rpa = rpp[i0 * 33 + ml];
        float rpb = rpp[i0 * 33 + ml + 16];
        f32x4 acc0 = {rpa, rpa, rpa, rpa};
        f32x4 acc1 = {rpb, rpb, rpb, rpb};
        acc0 = __builtin_amdgcn_mfma_f32_16x16x32_bf16(A1c, B01, acc0, 0, 0, 0);
        acc0 = __builtin_amdgcn_mfma_f32_16x16x32_bf16(A2c, B02, acc0, 0, 0, 0);
        acc1 = __builtin_amdgcn_mfma_f32_16x16x32_bf16(A1c, B11, acc1, 0, 0, 0);
        acc1 = __builtin_amdgcn_mfma_f32_16x16x32_bf16(A2c, B12, acc1, 0, 0, 0);

        int dg0 = rl(vd, i0);
        int rowbase = t0 * 16 + quad * 4;
        #pragma unroll
        for (int r = 0; r < 4; ++r) {
            bool vld = (rowbase + r) < dg0;
            colp0 += vld ? silu_f(acc0[r]) : 0.0f;
            colp1 += vld ? silu_f(acc1[r]) : 0.0f;
        }
        if (t0 == ((dg0 + 15) >> 4) - 1) {   // last tile of node i0 (uniform)
            colp0 += __shfl_xor(colp0, 16, 64);
            colp0 += __shfl_xor(colp0, 32, 64);
            colp1 += __shfl_xor(colp1, 16, 64);
            colp1 += __shfl_xor(colp1, 32, 64);
            if (quad == 0) {
                lshp[i0 * 34 + ml]      = f2bf(colp0);
                lshp[i0 * 34 + ml + 16] = f2bf(colp1);
            }
            colp0 = 0.0f; colp1 = 0.0f;
        }

        // rotate pipeline
        A1c = A1n; A2c = A2n;
        colNext = colNN; slot1 = slot2;
        i0 = i1; t0 = t1; i1 = i2; t1 = t2;
        adv(i2, t2, vd);
    }
    __builtin_amdgcn_wave_barrier();

    // ---- node phase: 16-node batch, 8 MFMAs
    const short8* w2p = reinterpret_cast<const short8*>(wt2);
    short8 Bw2_0 = w2p[(ml     ) * 4 + quad];
    short8 Bw2_1 = w2p[(ml + 16) * 4 + quad];
    const short8* u1p = reinterpret_cast<const short8*>(wtu1);
    short8 Bu1_00 = u1p[(ml     ) * 8 + quad];       // k 0..31 (x)
    short8 Bu1_10 = u1p[(ml     ) * 8 + 4 + quad];   // k 32..63 (ag)
    short8 Bu1_01 = u1p[(ml + 16) * 8 + quad];
    short8 Bu1_11 = u1p[(ml + 16) * 8 + 4 + quad];
    const short8* u2p = reinterpret_cast<const short8*>(wtu2);
    short8 Bu2_0 = u2p[(ml     ) * 4 + quad];
    short8 Bu2_1 = u2p[(ml + 16) * 4 + quad];

    // sh @ W2
    short8 Ash = *reinterpret_cast<const short8*>(lshp + ml * 34 + quad * 8);
    f32x4 c0 = {0.0f, 0.0f, 0.0f, 0.0f};
    f32x4 c1 = {0.0f, 0.0f, 0.0f, 0.0f};
    c0 = __builtin_amdgcn_mfma_f32_16x16x32_bf16(Ash, Bw2_0, c0, 0, 0, 0);
    c1 = __builtin_amdgcn_mfma_f32_16x16x32_bf16(Ash, Bw2_1, c1, 0, 0, 0);
    float b2c0 = b2[ml], b2c1 = b2[ml + 16];
    unsigned short* agp = agb[w];
    int row = quad * 4;
    #pragma unroll
    for (int r = 0; r < 4; ++r) {
        float fd = ldg[w][row + r];
        float iv = livd[w][row + r];
        agp[(row + r) * 34 + ml]      = f2bf((c0[r] + fd * b2c0) * iv);
        agp[(row + r) * 34 + ml + 16] = f2bf((c1[r] + fd * b2c1) * iv);
    }
    __builtin_amdgcn_wave_barrier();

    // [x ; ag] @ Wu1
    short8 Aag = *reinterpret_cast<const short8*>(agp + ml * 34 + quad * 8);
    f32x4 d0 = {0.0f, 0.0f, 0.0f, 0.0f};
    f32x4 d1 = {0.0f, 0.0f, 0.0f, 0.0f};
    d0 = __builtin_amdgcn_mfma_f32_16x16x32_bf16(Ax,  Bu1_00, d0, 0, 0, 0);
    d0 = __builtin_amdgcn_mfma_f32_16x16x32_bf16(Aag, Bu1_10, d0, 0, 0, 0);
    d1 = __builtin_amdgcn_mfma_f32_16x16x32_bf16(Ax,  Bu1_01, d1, 0, 0, 0);
    d1 = __builtin_amdgcn_mfma_f32_16x16x32_bf16(Aag, Bu1_11, d1, 0, 0, 0);
    float bu1c0 = bu1[ml], bu1c1 = bu1[ml + 16];
    unsigned short* hup = hub[w];
    #pragma unroll
    for (int r = 0; r < 4; ++r) {
        hup[(row + r) * 34 + ml]      = f2bf(silu_f(d0[r] + bu1c0));
        hup[(row + r) * 34 + ml + 16] = f2bf(silu_f(d1[r] + bu1c1));
    }
    __builtin_amdgcn_wave_barrier();

    // hu @ Wu2 ; residual + store
    short8 Ahu = *reinterpret_cast<const short8*>(hup + ml * 34 + quad * 8);
    f32x4 e0 = {0.0f, 0.0f, 0.0f, 0.0f};
    f32x4 e1 = {0.0f, 0.0f, 0.0f, 0.0f};
    e0 = __builtin_amdgcn_mfma_f32_16x16x32_bf16(Ahu, Bu2_0, e0, 0, 0, 0);
    e1 = __builtin_amdgcn_mfma_f32_16x16x32_bf16(Ahu, Bu2_1, e1, 0, 0, 0);
    float bu2c0 = bu2[ml], bu2c1 = bu2[ml + 16];
    #pragma unroll
    for (int r = 0; r < 4; ++r) {
        int nn = nbase + row + r;
        float o0 = e0[r] + bu2c0 + lx[w][(row + r) * 33 + ml];
        float o1 = e1[r] + bu2c1 + lx[w][(row + r) * 33 + ml + 16];
        x_out[(size_t)nn * 32 + ml]      = o0;
        x_out[(size_t)nn * 32 + ml + 16] = o1;
        xb_out[(size_t)nn * 32 + ml]      = f2bf(o0);
        xb_out[(size_t)nn * 32 + ml + 16] = f2bf(o1);
    }
}

// ---------------------------------------------------------------- LN + heads
__global__ __launch_bounds__(256) void final_kernel(
    const float* __restrict__ x, const float* __restrict__ u,
    const float* __restrict__ v,
    const float* __restrict__ ln_g, const float* __restrict__ ln_b,
    const float* __restrict__ Wr1, const float* __restrict__ br1,
    const float* __restrict__ Wr2, const float* __restrict__ br2,
    const float* __restrict__ Ws1, const float* __restrict__ bs1,
    const float* __restrict__ Ws2, const float* __restrict__ bs2,
    float* __restrict__ out)
{
    int n = blockIdx.x * 256 + threadIdx.x;
    if (n >= N) return;

    float a[32];
    const float4* x4 = reinterpret_cast<const float4*>(x + (size_t)n * 32);
    #pragma unroll
    for (int i = 0; i < 8; ++i) {
        float4 t = x4[i];
        a[4 * i] = t.x; a[4 * i + 1] = t.y; a[4 * i + 2] = t.z; a[4 * i + 3] = t.w;
    }
    float mu = 0.0f;
    #pragma unroll
    for (int i = 0; i < 32; ++i) mu += a[i];
    mu *= (1.0f / 32.0f);
    float var = 0.0f;
    #pragma unroll
    for (int i = 0; i < 32; ++i) { float dlt = a[i] - mu; var += dlt * dlt; }
    var *= (1.0f / 32.0f);
    float rs = rsqrtf(var + 1e-5f);
    #pragma unroll
    for (int i = 0; i < 32; ++i) a[i] = (a[i] - mu) * rs * ln_g[i] + ln_b[i];

    float o0 = br2[0], o1 = br2[1], o2 = bs2[0];
    #pragma unroll 1
    for (int j = 0; j < 96; ++j) {
        float hr = br1[j];
        float hs = bs1[j];
        #pragma unroll
        for (int i = 0; i < 32; ++i) {
            hr = fmaf(a[i], Wr1[i * 96 + j], hr);
            hs = fmaf(a[i], Ws1[i * 96 + j], hs);
        }
        hr = silu_f(hr);
        hs = silu_f(hs);
        o0 = fmaf(hr, Wr2[2 * j], o0);
        o1 = fmaf(hr, Wr2[2 * j + 1], o1);
        o2 = fmaf(hs, Ws2[j], o2);
    }
    out[n] = u[n * 4 + 3] + o2;
    out[N + 2 * n]     = o0 + v[n * 8 + 6];
    out[N + 2 * n + 1] = o1 + v[n * 8 + 7];
}

} // anonymous namespace

extern "C" void kernel_launch(void* const* d_in, const int* in_sizes, int n_in,
                              void* d_out, int out_size, void* d_ws, size_t ws_size,
                              hipStream_t stream)
{
    const float* u    = (const float*)d_in[0];
    const float* v    = (const float*)d_in[1];
    const float* bno  = (const float*)d_in[2];
    const float* yf   = (const float*)d_in[4];
    const float* pos  = (const float*)d_in[5];
    const int*   ei   = (const int*)d_in[6];
    const float* Wn1  = (const float*)d_in[7];
    const float* bn1  = (const float*)d_in[8];
    const float* Wn2  = (const float*)d_in[9];
    const float* bn2  = (const float*)d_in[10];
    const float* We1  = (const float*)d_in[11];
    const float* be1  = (const float*)d_in[12];
    const float* We2  = (const float*)d_in[13];
    const float* be2  = (const float*)d_in[14];
    const float* Wu1  = (const float*)d_in[15];
    const float* bu1  = (const float*)d_in[16];
    const float* Wu2  = (const float*)d_in[17];
    const float* bu2  = (const float*)d_in[18];
    const float* ln_g = (const float*)d_in[19];
    const float* ln_b = (const float*)d_in[20];
    const float* Wr1  = (const float*)d_in[21];
    const float* br1  = (const float*)d_in[22];
    const float* Wr2  = (const float*)d_in[23];
    const float* br2  = (const float*)d_in[24];
    const float* Ws1  = (const float*)d_in[25];
    const float* bs1  = (const float*)d_in[26];
    const float* Ws2  = (const float*)d_in[27];
    const float* bs2  = (const float*)d_in[28];
    float* out = (float*)d_out;

    // workspace layout (16B-aligned sections)
    int*   deg      = (int*)d_ws;                            // N
    int*   start    = deg + N;                               // N
    int*   bsum     = start + N;                             // 512
    int*   csr_col  = bsum + 512;                            // E ints
    unsigned short* rbf = (unsigned short*)(csr_col + E);    // E*16 bf16 (51.2 MB)
    float* x0       = (float*)(rbf + (size_t)E * 16);        // N*32 f32
    float* x1       = x0 + (size_t)N * S;                    // N*32 f32
    unsigned short* xb0 = (unsigned short*)(x1 + (size_t)N * S);   // N*32 bf16
    unsigned short* xb1 = xb0 + (size_t)N * S;               // N*32 bf16
    short* wt1      = (short*)(xb1 + (size_t)N * S);         // 5*32*96
    short* wt2      = wt1 + 5 * 32 * 96;                     // 5*32*32
    short* wtu1     = wt2 + 5 * 32 * 32;                     // 5*32*64
    short* wtu2     = wtu1 + 5 * 32 * 64;                    // 5*32*32
    int*   deg8     = (int*)(wtu2 + 5 * 32 * 32);            // 8*N (XCD-private counters)

    // transient aliases (dead before node_embed writes x0/xb0):
    //   cd: E*8B packed {col,dist}  == x0..x1 region (E*8 == N*32*4 exactly)
    //   ke: E*4B per-edge rank      == xb0  region   (E*4 == N*32*2 exactly)
    unsigned long long* cd = (unsigned long long*)x0;
    int* ke = (int*)xb0;

    const int egrid = (E + 255) / 256;

    hipMemsetAsync(deg8, 0, (size_t)NXCD * N * sizeof(int), stream);
    deg_kernel<<<egrid, 256, 0, stream>>>(ei, deg8, ke);
    combine_kernel<<<NB, 256, 0, stream>>>(deg8, deg);
    scanA<<<NB, 256, 0, stream>>>(deg, bsum);
    scanB<<<1, 512, 0, stream>>>(bsum);
    scanC<<<NB, 256, 0, stream>>>(deg, bsum, start);
    fill_kernel<<<egrid, 256, 0, stream>>>(ei, pos, start, ke, deg8, cd);
    expand_kernel<<<egrid, 256, 0, stream>>>(cd, csr_col, rbf);
    prep_wt_kernel<<<60, 256, 0, stream>>>(We1, We2, Wu1, Wu2, wt1, wt2, wtu1, wtu2);

    node_embed_kernel<<<NB, 256, 0, stream>>>(u, v, bno, yf, Wn1, bn1, Wn2, bn2,
                                              x0, xb0);

    float* xin = x0;  float* xout = x1;
    unsigned short* xbin = xb0;  unsigned short* xbout = xb1;
    for (int l = 0; l < L; ++l) {
        layer_kernel<<<LB2, 256, 0, stream>>>(
            deg, start, csr_col, rbf, xin, xbin, xout, xbout,
            wt1 + (size_t)l * 32 * 96,  be1 + (size_t)l * 32,
            wt2 + (size_t)l * 32 * 32,  be2 + (size_t)l * 32,
            wtu1 + (size_t)l * 32 * 64, bu1 + (size_t)l * 32,
            wtu2 + (size_t)l * 32 * 32, bu2 + (size_t)l * 32);
        float* tf = xin; xin = xout; xout = tf;
        unsigned short* tb = xbin; xbin = xbout; xbout = tb;
    }

    final_kernel<<<NB, 256, 0, stream>>>(xin, u, v, ln_g, ln_b,
                                         Wr1, br1, Wr2, br2,
                                         Ws1, bs1, Ws2, bs2, out);
}

// Round 6
// 572.563 us; speedup vs baseline: 1.0631x; 1.0601x over previous
//
#include <hip/hip_runtime.h>
#include <cmath>

namespace {

constexpr int N = 100000;
constexpr int E = 1600000;
constexpr int S = 32;           // hidden
constexpr int L = 5;            // layers
constexpr int NB = (N + 255) / 256;   // node-per-thread kernels
constexpr int NPW = 16;               // nodes per wave in layer kernel
constexpr int LB2 = (N + 63) / 64;    // 1563 blocks (4 waves/block, 16 nodes/wave)
constexpr int NBKT = 391;             // CSR buckets: row>>8, 256 rows each
constexpr int EPB  = E / 256;         // 6250 edges per histogram/scatter block
constexpr float PI_F    = 3.14159265358979323846f;
constexpr float SQRT2_F = 1.41421356237309515f;

typedef __attribute__((ext_vector_type(8))) short short8;   // 8 x bf16
typedef __attribute__((ext_vector_type(4))) float f32x4;

// fast silu: v_rcp_f32 instead of IEEE division (saves ~10 VALU instrs/call)
__device__ __forceinline__ float silu_f(float x) {
    return x * __builtin_amdgcn_rcpf(1.0f + __expf(-x));
}

// float -> bf16 bits, round-to-nearest-even
__device__ __forceinline__ unsigned short f2bf(float f) {
    unsigned int u = __float_as_uint(f);
    u = (u + 0x7FFFu + ((u >> 16) & 1u)) >> 16;
    return (unsigned short)u;
}

__device__ __forceinline__ int rl(int v, int i) {
    return __builtin_amdgcn_readlane(v, i);
}

// 32-bit byte-offset gather of a 16B xb fragment: base + col*64 + quad*16
__device__ __forceinline__ short8 ld_xb(const unsigned short* base, int col, int quad) {
    unsigned off = ((unsigned)col << 6) | ((unsigned)quad << 4);
    return *reinterpret_cast<const short8*>(reinterpret_cast<const char*>(base) + off);
}

// 32-bit byte-offset read of an rbf half-row: base + slot*32 + quad*16
__device__ __forceinline__ short8 ld_rbf(const unsigned short* base, int slot, int quad) {
    unsigned off = ((unsigned)slot << 5) | ((unsigned)quad << 4);
    return *reinterpret_cast<const short8*>(reinterpret_cast<const char*>(base) + off);
}

// advance (i,t) to the next tile of this wave's 16-node batch (uniform)
__device__ __forceinline__ void adv(int& i, int& t, int vd) {
    ++t;
    while (i < 16) {
        int dgi = rl(vd, i);
        int nt = (dgi + 15) >> 4;
        if (t < nt) break;
        t = 0; ++i;
    }
}

// CSR slot for (i,t) at lane row ml; clamped into the node's own range
__device__ __forceinline__ int slotOf(int i, int t, int vs, int vd, int ml) {
    if (i >= 16) return 0;
    int s0 = rl(vs, i);
    int dg = rl(vd, i);
    int smax = s0 + ((dg > 0) ? dg : 1) - 1;
    int s = s0 + t * 16 + ml;
    return min(s, smax);
}

// ---------------------------------------------------------------- passA: bucket histogram
// 256 blocks x 6250 edges. LDS atomics only (no fabric atomics).
// hist layout [bin][blk] for the per-bin prefix in p2.
__global__ __launch_bounds__(256) void passA_kernel(
    const int* __restrict__ ei, int* __restrict__ hist)
{
    __shared__ int h[NBKT];
    int t = threadIdx.x;
    int blk = blockIdx.x;
    for (int b = t; b < NBKT; b += 256) h[b] = 0;
    __syncthreads();
    int base = blk * EPB;
    for (int i = t; i < EPB; i += 256) {
        int r = ei[base + i];
        atomicAdd(&h[r >> 8], 1);
    }
    __syncthreads();
    for (int b = t; b < NBKT; b += 256) hist[b * 256 + blk] = h[b];
}

// ---------------------------------------------------------------- p1: bucket totals + exclusive prefix
__global__ __launch_bounds__(512) void p1_kernel(
    const int* __restrict__ hist, int* __restrict__ bstart)
{
    __shared__ int tot[NBKT + 1];
    int t = threadIdx.x;
    if (t < NBKT) {
        int s = 0;
        for (int b = 0; b < 256; ++b) s += hist[t * 256 + b];
        tot[t] = s;
    }
    __syncthreads();
    if (t == 0) {
        int a = 0;
        for (int i = 0; i < NBKT; ++i) { int c = tot[i]; tot[i] = a; a += c; }
        tot[NBKT] = a;   // == E
    }
    __syncthreads();
    if (t <= NBKT) bstart[t] = tot[t];
}

// ---------------------------------------------------------------- p2: per-(bin,blk) scatter bases
__global__ __launch_bounds__(256) void p2_kernel(
    const int* __restrict__ hist, const int* __restrict__ bstart,
    int* __restrict__ base)
{
    __shared__ int pre[256];
    int t = threadIdx.x;
    int bin = blockIdx.x;
    int h = hist[bin * 256 + t];
    pre[t] = h;
    __syncthreads();
    #pragma unroll
    for (int off = 1; off < 256; off <<= 1) {
        int v = (t >= off) ? pre[t - off] : 0;
        __syncthreads();
        pre[t] += v;
        __syncthreads();
    }
    base[bin * 256 + t] = bstart[bin] + pre[t] - h;   // exclusive over blocks
}

// ---------------------------------------------------------------- passB: scatter to bucket staging
// LDS cursors (preloaded with global bases) -> each edge claims a unique slot in
// its bucket's contiguous region. 16B records; per-block destination working set
// ~100KB -> write-combines in L2.
__global__ __launch_bounds__(256) void passB_kernel(
    const int* __restrict__ ei, const float* __restrict__ pos,
    const int* __restrict__ base, uint4* __restrict__ edgebuf)
{
    __shared__ int cur[NBKT];
    int t = threadIdx.x;
    int blk = blockIdx.x;
    for (int b = t; b < NBKT; b += 256) cur[b] = base[b * 256 + blk];
    __syncthreads();
    int ebase = blk * EPB;
    for (int i = t; i < EPB; i += 256) {
        int e = ebase + i;
        int r = ei[e];
        int c = ei[E + e];
        float2 pr = reinterpret_cast<const float2*>(pos)[r];
        float2 pc = reinterpret_cast<const float2*>(pos)[c];
        float dx = pr.x - pc.x, dy = pr.y - pc.y;
        float d = sqrtf(dx * dx + dy * dy);   // pos-mean cancels
        int slot = atomicAdd(&cur[r >> 8], 1);   // LDS atomic
        edgebuf[slot] = make_uint4((unsigned)c, __float_as_uint(d), (unsigned)r, 0u);
    }
}

// ---------------------------------------------------------------- passC: per-bucket deg/start/rank + fused rbf
// One block per bucket (256 rows). Two LDS-atomic sweeps over the bucket's region;
// final CSR slots + rbf rows written into the bucket's L2-resident window.
__global__ __launch_bounds__(256) void passC_kernel(
    const uint4* __restrict__ edgebuf, const int* __restrict__ bstart,
    int* __restrict__ deg, int* __restrict__ start,
    int* __restrict__ csr_col, unsigned short* __restrict__ rbf_buf)
{
    __shared__ int cnt[256];
    __shared__ int pre[256];
    __shared__ int cur[256];
    int t = threadIdx.x;
    int bkt = blockIdx.x;
    int s0 = bstart[bkt], s1 = bstart[bkt + 1];

    cnt[t] = 0;
    __syncthreads();
    for (int i = s0 + t; i < s1; i += 256) {
        unsigned r = edgebuf[i].z;
        atomicAdd(&cnt[r & 255], 1);
    }
    __syncthreads();
    int c0 = cnt[t];
    pre[t] = c0;
    __syncthreads();
    #pragma unroll
    for (int off = 1; off < 256; off <<= 1) {
        int v = (t >= off) ? pre[t - off] : 0;
        __syncthreads();
        pre[t] += v;
        __syncthreads();
    }
    int row = bkt * 256 + t;
    int st = s0 + pre[t] - c0;   // exclusive
    if (row < N) {
        deg[row] = c0;
        start[row] = st;
    }
    cur[t] = st;
    __syncthreads();

    for (int i = s0 + t; i < s1; i += 256) {
        uint4 e = edgebuf[i];
        int slot = atomicAdd(&cur[e.z & 255], 1);   // LDS atomic
        csr_col[slot] = (int)e.x;
        float d = __uint_as_float(e.y);

        float sn = __sinf(PI_F * d);
        float c1 = __cosf(PI_F * d);
        float inv = SQRT2_F / (d + 1e-8f);
        float tc = 2.0f * c1;
        float sk = sn, skm = 0.0f;
        unsigned int pk[8];
        #pragma unroll
        for (int k = 0; k < 8; ++k) {
            float r0 = sk * inv;
            float s2 = tc * sk - skm; skm = sk; sk = s2;
            float r1 = sk * inv;
            float s3 = tc * sk - skm; skm = sk; sk = s3;
            pk[k] = (unsigned int)f2bf(r0) | ((unsigned int)f2bf(r1) << 16);
        }
        uint4* out = reinterpret_cast<uint4*>(rbf_buf + (size_t)slot * 16);
        out[0] = make_uint4(pk[0], pk[1], pk[2], pk[3]);
        out[1] = make_uint4(pk[4], pk[5], pk[6], pk[7]);
    }
}

// ---------------------------------------------------------------- bf16 weight prep (transposed [n][k])
__global__ __launch_bounds__(256) void prep_wt_kernel(
    const float* __restrict__ We1, const float* __restrict__ We2,
    const float* __restrict__ Wu1, const float* __restrict__ Wu2,
    short* __restrict__ wt1, short* __restrict__ wt2,
    short* __restrict__ wtu1, short* __restrict__ wtu2)
{
    int idx = blockIdx.x * 256 + threadIdx.x;
    if (idx < 5 * 32 * 96) {
        int l = idx / (32 * 96), r = idx % (32 * 96), n = r / 96, k = r % 96;
        float v = (k < 80) ? We1[((size_t)l * 80 + k) * 32 + n] : 0.0f;
        wt1[idx] = (short)f2bf(v);
    }
    if (idx < 5 * 32 * 32) {
        int l = idx / 1024, r = idx % 1024, n = r / 32, k = r % 32;
        wt2[idx]  = (short)f2bf(We2[((size_t)l * 32 + k) * 32 + n]);
        wtu2[idx] = (short)f2bf(Wu2[((size_t)l * 32 + k) * 32 + n]);
    }
    if (idx < 5 * 32 * 64) {
        int l = idx / 2048, r = idx % 2048, n = r / 64, k = r % 64;
        wtu1[idx] = (short)f2bf(Wu1[((size_t)l * 64 + k) * 32 + n]);
    }
}

// ---------------------------------------------------------------- node embed (writes fp32 x + bf16 xb)
__global__ __launch_bounds__(256) void node_embed_kernel(
    const float* __restrict__ u, const float* __restrict__ v,
    const float* __restrict__ bnorm, const float* __restrict__ yf,
    const float* __restrict__ Wn1, const float* __restrict__ bn1,
    const float* __restrict__ Wn2, const float* __restrict__ bn2,
    float* __restrict__ x, unsigned short* __restrict__ xb)
{
    int n = blockIdx.x * 256 + threadIdx.x;
    if (n >= N) return;

    float f[10];
    float4 uu = reinterpret_cast<const float4*>(u)[n];
    f[0] = uu.x; f[1] = uu.y; f[2] = uu.z; f[3] = uu.w;
    float4 v0 = reinterpret_cast<const float4*>(v)[2 * n];
    float4 v1 = reinterpret_cast<const float4*>(v)[2 * n + 1];
    f[4] = sqrtf(v0.x * v0.x + v0.y * v0.y);
    f[5] = sqrtf(v0.z * v0.z + v0.w * v0.w);
    f[6] = sqrtf(v1.x * v1.x + v1.y * v1.y);
    f[7] = sqrtf(v1.z * v1.z + v1.w * v1.w);
    float2 bb = reinterpret_cast<const float2*>(bnorm)[n];
    f[8] = sqrtf(bb.x * bb.x + bb.y * bb.y);
    float2 yy = reinterpret_cast<const float2*>(yf)[n];
    f[9] = sqrtf(yy.x * yy.x + yy.y * yy.y);

    float h[64];
    #pragma unroll
    for (int j = 0; j < 64; ++j) h[j] = bn1[j];
    #pragma unroll
    for (int i = 0; i < 10; ++i) {
        float t = f[i];
        #pragma unroll
        for (int j = 0; j < 64; ++j) h[j] = fmaf(t, Wn1[i * 64 + j], h[j]);
    }
    #pragma unroll
    for (int j = 0; j < 64; ++j) h[j] = silu_f(h[j]);

    float o[32];
    #pragma unroll
    for (int j = 0; j < 32; ++j) o[j] = bn2[j];
    #pragma unroll
    for (int i = 0; i < 64; ++i) {
        float t = h[i];
        #pragma unroll
        for (int j = 0; j < 32; ++j) o[j] = fmaf(t, Wn2[i * 32 + j], o[j]);
    }
    float4* xo = reinterpret_cast<float4*>(x + (size_t)n * 32);
    #pragma unroll
    for (int i = 0; i < 8; ++i)
        xo[i] = make_float4(o[4 * i], o[4 * i + 1], o[4 * i + 2], o[4 * i + 3]);

    unsigned int* xbu = reinterpret_cast<unsigned int*>(xb) + (size_t)n * 16;
    #pragma unroll
    for (int i = 0; i < 16; ++i)
        xbu[i] = (unsigned int)f2bf(o[2 * i]) | ((unsigned int)f2bf(o[2 * i + 1]) << 16);
}

// ---------------------------------------------------------------- fused layer v3.1
// v3 + fast-silu (rcp) + 32-bit gather addressing.
__global__ __launch_bounds__(256, 4) void layer_kernel(
    const int* __restrict__ deg, const int* __restrict__ start,
    const int* __restrict__ csr_col, const unsigned short* __restrict__ rbf_buf,
    const float* __restrict__ x_in, const unsigned short* __restrict__ xb_in,
    float* __restrict__ x_out, unsigned short* __restrict__ xb_out,
    const short* __restrict__ wt1, const float* __restrict__ b1,
    const short* __restrict__ wt2, const float* __restrict__ b2,
    const short* __restrict__ wtu1, const float* __restrict__ bu1,
    const short* __restrict__ wtu2, const float* __restrict__ bu2)
{
    __shared__ unsigned short lsh[4][16 * 34];   // sh  (bf16), stride 34
    __shared__ unsigned short agb[4][16 * 34];   // ag  (bf16)
    __shared__ unsigned short hub[4][16 * 34];   // hu  (bf16)
    __shared__ float lx[4][16 * 33];             // x   (fp32), stride 33
    __shared__ float lrp[4][16 * 33];            // rowpart b1 + x@W1[0:32,:] (fp32)
    __shared__ float ldg[4][16];
    __shared__ float livd[4][16];

    int t = threadIdx.x;
    int w = t >> 6;
    int lane = t & 63;
    int quad = lane >> 4;
    int ml = lane & 15;
    int wid = blockIdx.x * 4 + w;
    int nbase = __builtin_amdgcn_readfirstlane(wid * NPW);
    if (nbase >= N) return;   // N % 16 == 0, so valid waves own full batches

    // ---- batch metadata: lane ml holds node ml's start/deg
    int vs = start[nbase + ml];
    int vd = deg[nbase + ml];

    // ---- edge-phase B fragments (wt1 [32][96])
    const short8* wp = reinterpret_cast<const short8*>(wt1);
    short8 B00 = wp[(ml     ) * 12 + 0 * 4 + quad];
    short8 B01 = wp[(ml     ) * 12 + 1 * 4 + quad];
    short8 B02 = wp[(ml     ) * 12 + 2 * 4 + quad];
    short8 B10 = wp[(ml + 16) * 12 + 0 * 4 + quad];
    short8 B11 = wp[(ml + 16) * 12 + 1 * 4 + quad];
    short8 B12 = wp[(ml + 16) * 12 + 2 * 4 + quad];

    // node-phase / rowpart x A-fragment (A[m=node ml][k=quad*8+j])
    short8 Ax = ld_xb(xb_in, nbase + ml, quad);

    float b1j0 = b1[ml];
    float b1j1 = b1[ml + 16];

    // ---- zero sh, preload x into LDS, stash deg floats
    unsigned short* lshp = lsh[w];
    for (int k = lane; k < 16 * 34; k += 64) lshp[k] = 0;
    {
        const float* xs = x_in + (size_t)nbase * 32;
        float* lxp = lx[w];
        #pragma unroll
        for (int k = 0; k < 8; ++k) {
            int idx = lane * 8 + k;
            lxp[(idx >> 5) * 33 + (idx & 31)] = xs[idx];
        }
    }
    if (lane < 16) {
        ldg[w][lane] = (float)vd;
        livd[w][lane] = 1.0f / fmaxf((float)vd, 1.0f);
    }

    // ---- hoisted row-node partial: rp[m][j] = b1[j] + x[m] @ W1[0:32, j]
    float* rpp = lrp[w];
    {
        f32x4 rp0 = {b1j0, b1j0, b1j0, b1j0};
        f32x4 rp1 = {b1j1, b1j1, b1j1, b1j1};
        rp0 = __builtin_amdgcn_mfma_f32_16x16x32_bf16(Ax, B00, rp0, 0, 0, 0);
        rp1 = __builtin_amdgcn_mfma_f32_16x16x32_bf16(Ax, B10, rp1, 0, 0, 0);
        int row = quad * 4;
        #pragma unroll
        for (int r = 0; r < 4; ++r) {
            rpp[(row + r) * 33 + ml]      = rp0[r];
            rpp[(row + r) * 33 + ml + 16] = rp1[r];
        }
    }
    __builtin_amdgcn_wave_barrier();

    // ---- software-pipelined edge loop
    const short8 Z8 = {0, 0, 0, 0, 0, 0, 0, 0};
    int i0 = 0, t0 = -1; adv(i0, t0, vd);
    int i1 = i0, t1 = t0; adv(i1, t1, vd);
    int i2 = i1, t2 = t1; adv(i2, t2, vd);

    int slot0 = slotOf(i0, t0, vs, vd, ml);
    int slot1 = slotOf(i1, t1, vs, vd, ml);
    int colCur  = csr_col[slot0];
    int colNext = csr_col[slot1];
    short8 A1c = ld_xb(xb_in, colCur, quad);
    short8 A2c = Z8;
    if (quad < 2) A2c = ld_rbf(rbf_buf, slot0, quad);

    float colp0 = 0.0f, colp1 = 0.0f;
    while (i0 < 16) {
        // stage 2: col two ahead
        int slot2 = slotOf(i2, t2, vs, vd, ml);
        int colNN = csr_col[slot2];
        // stage 1: fragments one ahead
        short8 A1n = ld_xb(xb_in, colNext, quad);
        short8 A2n = Z8;
        if (quad < 2) A2n = ld_rbf(rbf_buf, slot1, quad);

        // stage 0: compute current tile (acc seeded with hoisted rowpart + b1)
        float rpa = rpp[i0 * 33 + ml];
        float rpb = rpp[i0 * 33 + ml + 16];
        f32x4 acc0 = {rpa, rpa, rpa, rpa};
        f32x4 acc1 = {rpb, rpb, rpb, rpb};
        acc0 = __builtin_amdgcn_mfma_f32_16x16x32_bf16(A1c, B01, acc0, 0, 0, 0);
        acc0 = __builtin_amdgcn_mfma_f32_16x16x32_bf16(A2c, B02, acc0, 0, 0, 0);
        acc1 = __builtin_amdgcn_mfma_f32_16x16x32_bf16(A1c, B11, acc1, 0, 0, 0);
        acc1 = __builtin_amdgcn_mfma_f32_16x16x32_bf16(A2c, B12, acc1, 0, 0, 0);

        int dg0 = rl(vd, i0);
        int rowbase = t0 * 16 + quad * 4;
        #pragma unroll
        for (int r = 0; r < 4; ++r) {
            bool vld = (rowbase + r) < dg0;
            colp0 += vld ? silu_f(acc0[r]) : 0.0f;
            colp1 += vld ? silu_f(acc1[r]) : 0.0f;
        }
        if (t0 == ((dg0 + 15) >> 4) - 1) {   // last tile of node i0 (uniform)
            colp0 += __shfl_xor(colp0, 16, 64);
            colp0 += __shfl_xor(colp0, 32, 64);
            colp1 += __shfl_xor(colp1, 16, 64);
            colp1 += __shfl_xor(colp1, 32, 64);
            if (quad == 0) {
                lshp[i0 * 34 + ml]      = f2bf(colp0);
                lshp[i0 * 34 + ml + 16] = f2bf(colp1);
            }
            colp0 = 0.0f; colp1 = 0.0f;
        }

        // rotate pipeline
        A1c = A1n; A2c = A2n;
        colNext = colNN; slot1 = slot2;
        i0 = i1; t0 = t1; i1 = i2; t1 = t2;
        adv(i2, t2, vd);
    }
    __builtin_amdgcn_wave_barrier();

    // ---- node phase: 16-node batch, 8 MFMAs
    const short8* w2p = reinterpret_cast<const short8*>(wt2);
    short8 Bw2_0 = w2p[(ml     ) * 4 + quad];
    short8 Bw2_1 = w2p[(ml + 16) * 4 + quad];
    const short8* u1p = reinterpret_cast<const short8*>(wtu1);
    short8 Bu1_00 = u1p[(ml     ) * 8 + quad];       // k 0..31 (x)
    short8 Bu1_10 = u1p[(ml     ) * 8 + 4 + quad];   // k 32..63 (ag)
    short8 Bu1_01 = u1p[(ml + 16) * 8 + quad];
    short8 Bu1_11 = u1p[(ml + 16) * 8 + 4 + quad];
    const short8* u2p = reinterpret_cast<const short8*>(wtu2);
    short8 Bu2_0 = u2p[(ml     ) * 4 + quad];
    short8 Bu2_1 = u2p[(ml + 16) * 4 + quad];

    // sh @ W2
    short8 Ash = *reinterpret_cast<const short8*>(lshp + ml * 34 + quad * 8);
    f32x4 c0 = {0.0f, 0.0f, 0.0f, 0.0f};
    f32x4 c1 = {0.0f, 0.0f, 0.0f, 0.0f};
    c0 = __builtin_amdgcn_mfma_f32_16x16x32_bf16(Ash, Bw2_0, c0, 0, 0, 0);
    c1 = __builtin_amdgcn_mfma_f32_16x16x32_bf16(Ash, Bw2_1, c1, 0, 0, 0);
    float b2c0 = b2[ml], b2c1 = b2[ml + 16];
    unsigned short* agp = agb[w];
    int row = quad * 4;
    #pragma unroll
    for (int r = 0; r < 4; ++r) {
        float fd = ldg[w][row + r];
        float iv = livd[w][row + r];
        agp[(row + r) * 34 + ml]      = f2bf((c0[r] + fd * b2c0) * iv);
        agp[(row + r) * 34 + ml + 16] = f2bf((c1[r] + fd * b2c1) * iv);
    }
    __builtin_amdgcn_wave_barrier();

    // [x ; ag] @ Wu1
    short8 Aag = *reinterpret_cast<const short8*>(agp + ml * 34 + quad * 8);
    f32x4 d0 = {0.0f, 0.0f, 0.0f, 0.0f};
    f32x4 d1 = {0.0f, 0.0f, 0.0f, 0.0f};
    d0 = __builtin_amdgcn_mfma_f32_16x16x32_bf16(Ax,  Bu1_00, d0, 0, 0, 0);
    d0 = __builtin_amdgcn_mfma_f32_16x16x32_bf16(Aag, Bu1_10, d0, 0, 0, 0);
    d1 = __builtin_amdgcn_mfma_f32_16x16x32_bf16(Ax,  Bu1_01, d1, 0, 0, 0);
    d1 = __builtin_amdgcn_mfma_f32_16x16x32_bf16(Aag, Bu1_11, d1, 0, 0, 0);
    float bu1c0 = bu1[ml], bu1c1 = bu1[ml + 16];
    unsigned short* hup = hub[w];
    #pragma unroll
    for (int r = 0; r < 4; ++r) {
        hup[(row + r) * 34 + ml]      = f2bf(silu_f(d0[r] + bu1c0));
        hup[(row + r) * 34 + ml + 16] = f2bf(silu_f(d1[r] + bu1c1));
    }
    __builtin_amdgcn_wave_barrier();

    // hu @ Wu2 ; residual + store
    short8 Ahu = *reinterpret_cast<const short8*>(hup + ml * 34 + quad * 8);
    f32x4 e0 = {0.0f, 0.0f, 0.0f, 0.0f};
    f32x4 e1 = {0.0f, 0.0f, 0.0f, 0.0f};
    e0 = __builtin_amdgcn_mfma_f32_16x16x32_bf16(Ahu, Bu2_0, e0, 0, 0, 0);
    e1 = __builtin_amdgcn_mfma_f32_16x16x32_bf16(Ahu, Bu2_1, e1, 0, 0, 0);
    float bu2c0 = bu2[ml], bu2c1 = bu2[ml + 16];
    #pragma unroll
    for (int r = 0; r < 4; ++r) {
        int nn = nbase + row + r;
        float o0 = e0[r] + bu2c0 + lx[w][(row + r) * 33 + ml];
        float o1 = e1[r] + bu2c1 + lx[w][(row + r) * 33 + ml + 16];
        x_out[(size_t)nn * 32 + ml]      = o0;
        x_out[(size_t)nn * 32 + ml + 16] = o1;
        xb_out[(size_t)nn * 32 + ml]      = f2bf(o0);
        xb_out[(size_t)nn * 32 + ml + 16] = f2bf(o1);
    }
}

// ---------------------------------------------------------------- LN + heads
__global__ __launch_bounds__(256) void final_kernel(
    const float* __restrict__ x, const float* __restrict__ u,
    const float* __restrict__ v,
    const float* __restrict__ ln_g, const float* __restrict__ ln_b,
    const float* __restrict__ Wr1, const float* __restrict__ br1,
    const float* __restrict__ Wr2, const float* __restrict__ br2,
    const float* __restrict__ Ws1, const float* __restrict__ bs1,
    const float* __restrict__ Ws2, const float* __restrict__ bs2,
    float* __restrict__ out)
{
    int n = blockIdx.x * 256 + threadIdx.x;
    if (n >= N) return;

    float a[32];
    const float4* x4 = reinterpret_cast<const float4*>(x + (size_t)n * 32);
    #pragma unroll
    for (int i = 0; i < 8; ++i) {
        float4 t = x4[i];
        a[4 * i] = t.x; a[4 * i + 1] = t.y; a[4 * i + 2] = t.z; a[4 * i + 3] = t.w;
    }
    float mu = 0.0f;
    #pragma unroll
    for (int i = 0; i < 32; ++i) mu += a[i];
    mu *= (1.0f / 32.0f);
    float var = 0.0f;
    #pragma unroll
    for (int i = 0; i < 32; ++i) { float dlt = a[i] - mu; var += dlt * dlt; }
    var *= (1.0f / 32.0f);
    float rs = rsqrtf(var + 1e-5f);
    #pragma unroll
    for (int i = 0; i < 32; ++i) a[i] = (a[i] - mu) * rs * ln_g[i] + ln_b[i];

    float o0 = br2[0], o1 = br2[1], o2 = bs2[0];
    #pragma unroll 1
    for (int j = 0; j < 96; ++j) {
        float hr = br1[j];
        float hs = bs1[j];
        #pragma unroll
        for (int i = 0; i < 32; ++i) {
            hr = fmaf(a[i], Wr1[i * 96 + j], hr);
            hs = fmaf(a[i], Ws1[i * 96 + j], hs);
        }
        hr = silu_f(hr);
        hs = silu_f(hs);
        o0 = fmaf(hr, Wr2[2 * j], o0);
        o1 = fmaf(hr, Wr2[2 * j + 1], o1);
        o2 = fmaf(hs, Ws2[j], o2);
    }
    out[n] = u[n * 4 + 3] + o2;
    out[N + 2 * n]     = o0 + v[n * 8 + 6];
    out[N + 2 * n + 1] = o1 + v[n * 8 + 7];
}

} // anonymous namespace

extern "C" void kernel_launch(void* const* d_in, const int* in_sizes, int n_in,
                              void* d_out, int out_size, void* d_ws, size_t ws_size,
                              hipStream_t stream)
{
    const float* u    = (const float*)d_in[0];
    const float* v    = (const float*)d_in[1];
    const float* bno  = (const float*)d_in[2];
    const float* yf   = (const float*)d_in[4];
    const float* pos  = (const float*)d_in[5];
    const int*   ei   = (const int*)d_in[6];
    const float* Wn1  = (const float*)d_in[7];
    const float* bn1  = (const float*)d_in[8];
    const float* Wn2  = (const float*)d_in[9];
    const float* bn2  = (const float*)d_in[10];
    const float* We1  = (const float*)d_in[11];
    const float* be1  = (const float*)d_in[12];
    const float* We2  = (const float*)d_in[13];
    const float* be2  = (const float*)d_in[14];
    const float* Wu1  = (const float*)d_in[15];
    const float* bu1  = (const float*)d_in[16];
    const float* Wu2  = (const float*)d_in[17];
    const float* bu2  = (const float*)d_in[18];
    const float* ln_g = (const float*)d_in[19];
    const float* ln_b = (const float*)d_in[20];
    const float* Wr1  = (const float*)d_in[21];
    const float* br1  = (const float*)d_in[22];
    const float* Wr2  = (const float*)d_in[23];
    const float* br2  = (const float*)d_in[24];
    const float* Ws1  = (const float*)d_in[25];
    const float* bs1  = (const float*)d_in[26];
    const float* Ws2  = (const float*)d_in[27];
    const float* bs2  = (const float*)d_in[28];
    float* out = (float*)d_out;

    // workspace layout (16B-aligned sections)
    int*   deg      = (int*)d_ws;                            // N
    int*   start    = deg + N;                               // N
    int*   bstart   = start + N;                             // NBKT+1
    int*   csr_col  = bstart + 512;                          // E ints
    unsigned short* rbf = (unsigned short*)(csr_col + E);    // E*16 bf16 (51.2 MB)
    float* x0       = (float*)(rbf + (size_t)E * 16);        // N*32 f32
    float* x1       = x0 + (size_t)N * S;                    // N*32 f32
    unsigned short* xb0 = (unsigned short*)(x1 + (size_t)N * S);   // N*32 bf16
    unsigned short* xb1 = xb0 + (size_t)N * S;               // N*32 bf16
    short* wt1      = (short*)(xb1 + (size_t)N * S);         // 5*32*96
    short* wt2      = wt1 + 5 * 32 * 96;                     // 5*32*32
    short* wtu1     = wt2 + 5 * 32 * 32;                     // 5*32*64
    short* wtu2     = wtu1 + 5 * 32 * 64;                    // 5*32*32
    int*   hist     = (int*)(wtu2 + 5 * 32 * 32);            // NBKT*256
    int*   basem    = hist + NBKT * 256;                     // NBKT*256

    // transient alias (dead before node_embed writes x0 / layer writes x1):
    //   edgebuf: E*16B bucket-ordered {col, dist, row} == x0..xb0 (E*16 == N*32*4*2)
    uint4* edgebuf = (uint4*)x0;

    passA_kernel<<<256, 256, 0, stream>>>(ei, hist);
    p1_kernel<<<1, 512, 0, stream>>>(hist, bstart);
    p2_kernel<<<NBKT, 256, 0, stream>>>(hist, bstart, basem);
    passB_kernel<<<256, 256, 0, stream>>>(ei, pos, basem, edgebuf);
    passC_kernel<<<NBKT, 256, 0, stream>>>(edgebuf, bstart, deg, start, csr_col, rbf);
    prep_wt_kernel<<<60, 256, 0, stream>>>(We1, We2, Wu1, Wu2, wt1, wt2, wtu1, wtu2);

    node_embed_kernel<<<NB, 256, 0, stream>>>(u, v, bno, yf, Wn1, bn1, Wn2, bn2,
                                              x0, xb0);

    float* xin = x0;  float* xout = x1;
    unsigned short* xbin = xb0;  unsigned short* xbout = xb1;
    for (int l = 0; l < L; ++l) {
        layer_kernel<<<LB2, 256, 0, stream>>>(
            deg, start, csr_col, rbf, xin, xbin, xout, xbout,
            wt1 + (size_t)l * 32 * 96,  be1 + (size_t)l * 32,
            wt2 + (size_t)l * 32 * 32,  be2 + (size_t)l * 32,
            wtu1 + (size_t)l * 32 * 64, bu1 + (size_t)l * 32,
            wtu2 + (size_t)l * 32 * 32, bu2 + (size_t)l * 32);
        float* tf = xin; xin = xout; xout = tf;
        unsigned short* tb = xbin; xbin = xbout; xbout = tb;
    }

    final_kernel<<<NB, 256, 0, stream>>>(xin, u, v, ln_g, ln_b,
                                         Wr1, br1, Wr2, br2,
                                         Ws1, bs1, Ws2, bs2, out);
}

// Round 7
// 526.338 us; speedup vs baseline: 1.1565x; 1.0878x over previous
//
#include <hip/hip_runtime.h>
#include <cmath>

namespace {

constexpr int N = 100000;
constexpr int E = 1600000;
constexpr int S = 32;           // hidden
constexpr int L = 5;            // layers
constexpr int NB = (N + 255) / 256;   // node-per-thread kernels
constexpr int NPW = 16;               // nodes per wave in layer kernel
constexpr int LB2 = (N + 63) / 64;    // 1563 blocks (4 waves/block, 16 nodes/wave)
constexpr int NBKT = 391;             // CSR buckets: row>>8, 256 rows each
constexpr int EPB  = E / 256;         // 6250 edges per histogram/scatter block
constexpr float PI_F    = 3.14159265358979323846f;
constexpr float SQRT2_F = 1.41421356237309515f;

typedef __attribute__((ext_vector_type(8))) short short8;   // 8 x bf16
typedef __attribute__((ext_vector_type(4))) float f32x4;

// fast silu: v_rcp_f32 instead of IEEE division (saves ~10 VALU instrs/call)
__device__ __forceinline__ float silu_f(float x) {
    return x * __builtin_amdgcn_rcpf(1.0f + __expf(-x));
}

// float -> bf16 bits, round-to-nearest-even
__device__ __forceinline__ unsigned short f2bf(float f) {
    unsigned int u = __float_as_uint(f);
    u = (u + 0x7FFFu + ((u >> 16) & 1u)) >> 16;
    return (unsigned short)u;
}

__device__ __forceinline__ int rl(int v, int i) {
    return __builtin_amdgcn_readlane(v, i);
}

// 32-bit byte-offset gather of a 16B xb fragment: base + col*64 + quad*16
__device__ __forceinline__ short8 ld_xb(const unsigned short* base, int col, int quad) {
    unsigned off = ((unsigned)col << 6) | ((unsigned)quad << 4);
    return *reinterpret_cast<const short8*>(reinterpret_cast<const char*>(base) + off);
}

// 32-bit byte-offset read of an rbf half-row: base + slot*32 + quad*16
__device__ __forceinline__ short8 ld_rbf(const unsigned short* base, int slot, int quad) {
    unsigned off = ((unsigned)slot << 5) | ((unsigned)quad << 4);
    return *reinterpret_cast<const short8*>(reinterpret_cast<const char*>(base) + off);
}

// advance (i,t) to the next tile of this wave's 16-node batch (uniform)
__device__ __forceinline__ void adv(int& i, int& t, int vd) {
    ++t;
    while (i < 16) {
        int dgi = rl(vd, i);
        int nt = (dgi + 15) >> 4;
        if (t < nt) break;
        t = 0; ++i;
    }
}

// CSR slot for (i,t) at lane row ml; clamped into the node's own range
__device__ __forceinline__ int slotOf(int i, int t, int vs, int vd, int ml) {
    if (i >= 16) return 0;
    int s0 = rl(vs, i);
    int dg = rl(vd, i);
    int smax = s0 + ((dg > 0) ? dg : 1) - 1;
    int s = s0 + t * 16 + ml;
    return min(s, smax);
}

// ---------------------------------------------------------------- passA: bucket histogram
__global__ __launch_bounds__(256) void passA_kernel(
    const int* __restrict__ ei, int* __restrict__ hist)
{
    __shared__ int h[NBKT];
    int t = threadIdx.x;
    int blk = blockIdx.x;
    for (int b = t; b < NBKT; b += 256) h[b] = 0;
    __syncthreads();
    int base = blk * EPB;
    for (int i = t; i < EPB; i += 256) {
        int r = ei[base + i];
        atomicAdd(&h[r >> 8], 1);
    }
    __syncthreads();
    for (int b = t; b < NBKT; b += 256) hist[b * 256 + blk] = h[b];
}

// ---------------------------------------------------------------- p1: bucket totals + exclusive prefix
__global__ __launch_bounds__(512) void p1_kernel(
    const int* __restrict__ hist, int* __restrict__ bstart)
{
    __shared__ int tot[NBKT + 1];
    int t = threadIdx.x;
    if (t < NBKT) {
        int s = 0;
        for (int b = 0; b < 256; ++b) s += hist[t * 256 + b];
        tot[t] = s;
    }
    __syncthreads();
    if (t == 0) {
        int a = 0;
        for (int i = 0; i < NBKT; ++i) { int c = tot[i]; tot[i] = a; a += c; }
        tot[NBKT] = a;   // == E
    }
    __syncthreads();
    if (t <= NBKT) bstart[t] = tot[t];
}

// ---------------------------------------------------------------- p2: per-(bin,blk) scatter bases
__global__ __launch_bounds__(256) void p2_kernel(
    const int* __restrict__ hist, const int* __restrict__ bstart,
    int* __restrict__ base)
{
    __shared__ int pre[256];
    int t = threadIdx.x;
    int bin = blockIdx.x;
    int h = hist[bin * 256 + t];
    pre[t] = h;
    __syncthreads();
    #pragma unroll
    for (int off = 1; off < 256; off <<= 1) {
        int v = (t >= off) ? pre[t - off] : 0;
        __syncthreads();
        pre[t] += v;
        __syncthreads();
    }
    base[bin * 256 + t] = bstart[bin] + pre[t] - h;   // exclusive over blocks
}

// ---------------------------------------------------------------- passB: scatter to bucket staging
__global__ __launch_bounds__(256) void passB_kernel(
    const int* __restrict__ ei, const float* __restrict__ pos,
    const int* __restrict__ base, uint4* __restrict__ edgebuf)
{
    __shared__ int cur[NBKT];
    int t = threadIdx.x;
    int blk = blockIdx.x;
    for (int b = t; b < NBKT; b += 256) cur[b] = base[b * 256 + blk];
    __syncthreads();
    int ebase = blk * EPB;
    for (int i = t; i < EPB; i += 256) {
        int e = ebase + i;
        int r = ei[e];
        int c = ei[E + e];
        float2 pr = reinterpret_cast<const float2*>(pos)[r];
        float2 pc = reinterpret_cast<const float2*>(pos)[c];
        float dx = pr.x - pc.x, dy = pr.y - pc.y;
        float d = sqrtf(dx * dx + dy * dy);   // pos-mean cancels
        int slot = atomicAdd(&cur[r >> 8], 1);   // LDS atomic
        edgebuf[slot] = make_uint4((unsigned)c, __float_as_uint(d), (unsigned)r, 0u);
    }
}

// ---------------------------------------------------------------- passC: per-bucket deg/start/rank + fused rbf
__global__ __launch_bounds__(256) void passC_kernel(
    const uint4* __restrict__ edgebuf, const int* __restrict__ bstart,
    int* __restrict__ deg, int* __restrict__ start,
    int* __restrict__ csr_col, unsigned short* __restrict__ rbf_buf)
{
    __shared__ int cnt[256];
    __shared__ int pre[256];
    __shared__ int cur[256];
    int t = threadIdx.x;
    int bkt = blockIdx.x;
    int s0 = bstart[bkt], s1 = bstart[bkt + 1];

    cnt[t] = 0;
    __syncthreads();
    for (int i = s0 + t; i < s1; i += 256) {
        unsigned r = edgebuf[i].z;
        atomicAdd(&cnt[r & 255], 1);
    }
    __syncthreads();
    int c0 = cnt[t];
    pre[t] = c0;
    __syncthreads();
    #pragma unroll
    for (int off = 1; off < 256; off <<= 1) {
        int v = (t >= off) ? pre[t - off] : 0;
        __syncthreads();
        pre[t] += v;
        __syncthreads();
    }
    int row = bkt * 256 + t;
    int st = s0 + pre[t] - c0;   // exclusive
    if (row < N) {
        deg[row] = c0;
        start[row] = st;
    }
    cur[t] = st;
    __syncthreads();

    for (int i = s0 + t; i < s1; i += 256) {
        uint4 e = edgebuf[i];
        int slot = atomicAdd(&cur[e.z & 255], 1);   // LDS atomic
        csr_col[slot] = (int)e.x;
        float d = __uint_as_float(e.y);

        float sn = __sinf(PI_F * d);
        float c1 = __cosf(PI_F * d);
        float inv = SQRT2_F / (d + 1e-8f);
        float tc = 2.0f * c1;
        float sk = sn, skm = 0.0f;
        unsigned int pk[8];
        #pragma unroll
        for (int k = 0; k < 8; ++k) {
            float r0 = sk * inv;
            float s2 = tc * sk - skm; skm = sk; sk = s2;
            float r1 = sk * inv;
            float s3 = tc * sk - skm; skm = sk; sk = s3;
            pk[k] = (unsigned int)f2bf(r0) | ((unsigned int)f2bf(r1) << 16);
        }
        uint4* out = reinterpret_cast<uint4*>(rbf_buf + (size_t)slot * 16);
        out[0] = make_uint4(pk[0], pk[1], pk[2], pk[3]);
        out[1] = make_uint4(pk[4], pk[5], pk[6], pk[7]);
    }
}

// ---------------------------------------------------------------- bf16 weight prep (transposed [n][k])
__global__ __launch_bounds__(256) void prep_wt_kernel(
    const float* __restrict__ We1, const float* __restrict__ We2,
    const float* __restrict__ Wu1, const float* __restrict__ Wu2,
    const float* __restrict__ Wr1, const float* __restrict__ Ws1,
    short* __restrict__ wt1, short* __restrict__ wt2,
    short* __restrict__ wtu1, short* __restrict__ wtu2,
    short* __restrict__ wtr1, short* __restrict__ wts1)
{
    int idx = blockIdx.x * 256 + threadIdx.x;
    if (idx < 5 * 32 * 96) {
        int l = idx / (32 * 96), r = idx % (32 * 96), n = r / 96, k = r % 96;
        float v = (k < 80) ? We1[((size_t)l * 80 + k) * 32 + n] : 0.0f;
        wt1[idx] = (short)f2bf(v);
    }
    if (idx < 5 * 32 * 32) {
        int l = idx / 1024, r = idx % 1024, n = r / 32, k = r % 32;
        wt2[idx]  = (short)f2bf(We2[((size_t)l * 32 + k) * 32 + n]);
        wtu2[idx] = (short)f2bf(Wu2[((size_t)l * 32 + k) * 32 + n]);
    }
    if (idx < 5 * 32 * 64) {
        int l = idx / 2048, r = idx % 2048, n = r / 64, k = r % 64;
        wtu1[idx] = (short)f2bf(Wu1[((size_t)l * 64 + k) * 32 + n]);
    }
    if (idx < 96 * 32) {
        int n = idx / 32, k = idx % 32;   // head weights [n=96][k=32]
        wtr1[idx] = (short)f2bf(Wr1[k * 96 + n]);
        wts1[idx] = (short)f2bf(Ws1[k * 96 + n]);
    }
}

// ---------------------------------------------------------------- node embed (writes fp32 x + bf16 xb)
__global__ __launch_bounds__(256) void node_embed_kernel(
    const float* __restrict__ u, const float* __restrict__ v,
    const float* __restrict__ bnorm, const float* __restrict__ yf,
    const float* __restrict__ Wn1, const float* __restrict__ bn1,
    const float* __restrict__ Wn2, const float* __restrict__ bn2,
    float* __restrict__ x, unsigned short* __restrict__ xb)
{
    int n = blockIdx.x * 256 + threadIdx.x;
    if (n >= N) return;

    float f[10];
    float4 uu = reinterpret_cast<const float4*>(u)[n];
    f[0] = uu.x; f[1] = uu.y; f[2] = uu.z; f[3] = uu.w;
    float4 v0 = reinterpret_cast<const float4*>(v)[2 * n];
    float4 v1 = reinterpret_cast<const float4*>(v)[2 * n + 1];
    f[4] = sqrtf(v0.x * v0.x + v0.y * v0.y);
    f[5] = sqrtf(v0.z * v0.z + v0.w * v0.w);
    f[6] = sqrtf(v1.x * v1.x + v1.y * v1.y);
    f[7] = sqrtf(v1.z * v1.z + v1.w * v1.w);
    float2 bb = reinterpret_cast<const float2*>(bnorm)[n];
    f[8] = sqrtf(bb.x * bb.x + bb.y * bb.y);
    float2 yy = reinterpret_cast<const float2*>(yf)[n];
    f[9] = sqrtf(yy.x * yy.x + yy.y * yy.y);

    float h[64];
    #pragma unroll
    for (int j = 0; j < 64; ++j) h[j] = bn1[j];
    #pragma unroll
    for (int i = 0; i < 10; ++i) {
        float t = f[i];
        #pragma unroll
        for (int j = 0; j < 64; ++j) h[j] = fmaf(t, Wn1[i * 64 + j], h[j]);
    }
    #pragma unroll
    for (int j = 0; j < 64; ++j) h[j] = silu_f(h[j]);

    float o[32];
    #pragma unroll
    for (int j = 0; j < 32; ++j) o[j] = bn2[j];
    #pragma unroll
    for (int i = 0; i < 64; ++i) {
        float t = h[i];
        #pragma unroll
        for (int j = 0; j < 32; ++j) o[j] = fmaf(t, Wn2[i * 32 + j], o[j]);
    }
    float4* xo = reinterpret_cast<float4*>(x + (size_t)n * 32);
    #pragma unroll
    for (int i = 0; i < 8; ++i)
        xo[i] = make_float4(o[4 * i], o[4 * i + 1], o[4 * i + 2], o[4 * i + 3]);

    unsigned int* xbu = reinterpret_cast<unsigned int*>(xb) + (size_t)n * 16;
    #pragma unroll
    for (int i = 0; i < 16; ++i)
        xbu[i] = (unsigned int)f2bf(o[2 * i]) | ((unsigned int)f2bf(o[2 * i + 1]) << 16);
}

// ---------------------------------------------------------------- fused layer v3.1
__global__ __launch_bounds__(256, 4) void layer_kernel(
    const int* __restrict__ deg, const int* __restrict__ start,
    const int* __restrict__ csr_col, const unsigned short* __restrict__ rbf_buf,
    const float* __restrict__ x_in, const unsigned short* __restrict__ xb_in,
    float* __restrict__ x_out, unsigned short* __restrict__ xb_out,
    const short* __restrict__ wt1, const float* __restrict__ b1,
    const short* __restrict__ wt2, const float* __restrict__ b2,
    const short* __restrict__ wtu1, const float* __restrict__ bu1,
    const short* __restrict__ wtu2, const float* __restrict__ bu2)
{
    __shared__ unsigned short lsh[4][16 * 34];   // sh  (bf16), stride 34
    __shared__ unsigned short agb[4][16 * 34];   // ag  (bf16)
    __shared__ unsigned short hub[4][16 * 34];   // hu  (bf16)
    __shared__ float lx[4][16 * 33];             // x   (fp32), stride 33
    __shared__ float lrp[4][16 * 33];            // rowpart b1 + x@W1[0:32,:] (fp32)
    __shared__ float ldg[4][16];
    __shared__ float livd[4][16];

    int t = threadIdx.x;
    int w = t >> 6;
    int lane = t & 63;
    int quad = lane >> 4;
    int ml = lane & 15;
    int wid = blockIdx.x * 4 + w;
    int nbase = __builtin_amdgcn_readfirstlane(wid * NPW);
    if (nbase >= N) return;   // N % 16 == 0, so valid waves own full batches

    // ---- batch metadata: lane ml holds node ml's start/deg
    int vs = start[nbase + ml];
    int vd = deg[nbase + ml];

    // ---- edge-phase B fragments (wt1 [32][96])
    const short8* wp = reinterpret_cast<const short8*>(wt1);
    short8 B00 = wp[(ml     ) * 12 + 0 * 4 + quad];
    short8 B01 = wp[(ml     ) * 12 + 1 * 4 + quad];
    short8 B02 = wp[(ml     ) * 12 + 2 * 4 + quad];
    short8 B10 = wp[(ml + 16) * 12 + 0 * 4 + quad];
    short8 B11 = wp[(ml + 16) * 12 + 1 * 4 + quad];
    short8 B12 = wp[(ml + 16) * 12 + 2 * 4 + quad];

    // node-phase / rowpart x A-fragment (A[m=node ml][k=quad*8+j])
    short8 Ax = ld_xb(xb_in, nbase + ml, quad);

    float b1j0 = b1[ml];
    float b1j1 = b1[ml + 16];

    // ---- zero sh, preload x into LDS, stash deg floats
    unsigned short* lshp = lsh[w];
    for (int k = lane; k < 16 * 34; k += 64) lshp[k] = 0;
    {
        const float* xs = x_in + (size_t)nbase * 32;
        float* lxp = lx[w];
        #pragma unroll
        for (int k = 0; k < 8; ++k) {
            int idx = lane * 8 + k;
            lxp[(idx >> 5) * 33 + (idx & 31)] = xs[idx];
        }
    }
    if (lane < 16) {
        ldg[w][lane] = (float)vd;
        livd[w][lane] = 1.0f / fmaxf((float)vd, 1.0f);
    }

    // ---- hoisted row-node partial: rp[m][j] = b1[j] + x[m] @ W1[0:32, j]
    float* rpp = lrp[w];
    {
        f32x4 rp0 = {b1j0, b1j0, b1j0, b1j0};
        f32x4 rp1 = {b1j1, b1j1, b1j1, b1j1};
        rp0 = __builtin_amdgcn_mfma_f32_16x16x32_bf16(Ax, B00, rp0, 0, 0, 0);
        rp1 = __builtin_amdgcn_mfma_f32_16x16x32_bf16(Ax, B10, rp1, 0, 0, 0);
        int row = quad * 4;
        #pragma unroll
        for (int r = 0; r < 4; ++r) {
            rpp[(row + r) * 33 + ml]      = rp0[r];
            rpp[(row + r) * 33 + ml + 16] = rp1[r];
        }
    }
    __builtin_amdgcn_wave_barrier();

    // ---- software-pipelined edge loop
    const short8 Z8 = {0, 0, 0, 0, 0, 0, 0, 0};
    int i0 = 0, t0 = -1; adv(i0, t0, vd);
    int i1 = i0, t1 = t0; adv(i1, t1, vd);
    int i2 = i1, t2 = t1; adv(i2, t2, vd);

    int slot0 = slotOf(i0, t0, vs, vd, ml);
    int slot1 = slotOf(i1, t1, vs, vd, ml);
    int colCur  = csr_col[slot0];
    int colNext = csr_col[slot1];
    short8 A1c = ld_xb(xb_in, colCur, quad);
    short8 A2c = Z8;
    if (quad < 2) A2c = ld_rbf(rbf_buf, slot0, quad);

    float colp0 = 0.0f, colp1 = 0.0f;
    while (i0 < 16) {
        // stage 2: col two ahead
        int slot2 = slotOf(i2, t2, vs, vd, ml);
        int colNN = csr_col[slot2];
        // stage 1: fragments one ahead
        short8 A1n = ld_xb(xb_in, colNext, quad);
        short8 A2n = Z8;
        if (quad < 2) A2n = ld_rbf(rbf_buf, slot1, quad);

        // stage 0: compute current tile (acc seeded with hoisted rowpart + b1)
        float rpa = rpp[i0 * 33 + ml];
        float rpb = rpp[i0 * 33 + ml + 16];
        f32x4 acc0 = {rpa, rpa, rpa, rpa};
        f32x4 acc1 = {rpb, rpb, rpb, rpb};
        acc0 = __builtin_amdgcn_mfma_f32_16x16x32_bf16(A1c, B01, acc0, 0, 0, 0);
        acc0 = __builtin_amdgcn_mfma_f32_16x16x32_bf16(A2c, B02, acc0, 0, 0, 0);
        acc1 = __builtin_amdgcn_mfma_f32_16x16x32_bf16(A1c, B11, acc1, 0, 0, 0);
        acc1 = __builtin_amdgcn_mfma_f32_16x16x32_bf16(A2c, B12, acc1, 0, 0, 0);

        int dg0 = rl(vd, i0);
        int rowbase = t0 * 16 + quad * 4;
        #pragma unroll
        for (int r = 0; r < 4; ++r) {
            bool vld = (rowbase + r) < dg0;
            colp0 += vld ? silu_f(acc0[r]) : 0.0f;
            colp1 += vld ? silu_f(acc1[r]) : 0.0f;
        }
        if (t0 == ((dg0 + 15) >> 4) - 1) {   // last tile of node i0 (uniform)
            colp0 += __shfl_xor(colp0, 16, 64);
            colp0 += __shfl_xor(colp0, 32, 64);
            colp1 += __shfl_xor(colp1, 16, 64);
            colp1 += __shfl_xor(colp1, 32, 64);
            if (quad == 0) {
                lshp[i0 * 34 + ml]      = f2bf(colp0);
                lshp[i0 * 34 + ml + 16] = f2bf(colp1);
            }
            colp0 = 0.0f; colp1 = 0.0f;
        }

        // rotate pipeline
        A1c = A1n; A2c = A2n;
        colNext = colNN; slot1 = slot2;
        i0 = i1; t0 = t1; i1 = i2; t1 = t2;
        adv(i2, t2, vd);
    }
    __builtin_amdgcn_wave_barrier();

    // ---- node phase: 16-node batch, 8 MFMAs
    const short8* w2p = reinterpret_cast<const short8*>(wt2);
    short8 Bw2_0 = w2p[(ml     ) * 4 + quad];
    short8 Bw2_1 = w2p[(ml + 16) * 4 + quad];
    const short8* u1p = reinterpret_cast<const short8*>(wtu1);
    short8 Bu1_00 = u1p[(ml     ) * 8 + quad];       // k 0..31 (x)
    short8 Bu1_10 = u1p[(ml     ) * 8 + 4 + quad];   // k 32..63 (ag)
    short8 Bu1_01 = u1p[(ml + 16) * 8 + quad];
    short8 Bu1_11 = u1p[(ml + 16) * 8 + 4 + quad];
    const short8* u2p = reinterpret_cast<const short8*>(wtu2);
    short8 Bu2_0 = u2p[(ml     ) * 4 + quad];
    short8 Bu2_1 = u2p[(ml + 16) * 4 + quad];

    // sh @ W2
    short8 Ash = *reinterpret_cast<const short8*>(lshp + ml * 34 + quad * 8);
    f32x4 c0 = {0.0f, 0.0f, 0.0f, 0.0f};
    f32x4 c1 = {0.0f, 0.0f, 0.0f, 0.0f};
    c0 = __builtin_amdgcn_mfma_f32_16x16x32_bf16(Ash, Bw2_0, c0, 0, 0, 0);
    c1 = __builtin_amdgcn_mfma_f32_16x16x32_bf16(Ash, Bw2_1, c1, 0, 0, 0);
    float b2c0 = b2[ml], b2c1 = b2[ml + 16];
    unsigned short* agp = agb[w];
    int row = quad * 4;
    #pragma unroll
    for (int r = 0; r < 4; ++r) {
        float fd = ldg[w][row + r];
        float iv = livd[w][row + r];
        agp[(row + r) * 34 + ml]      = f2bf((c0[r] + fd * b2c0) * iv);
        agp[(row + r) * 34 + ml + 16] = f2bf((c1[r] + fd * b2c1) * iv);
    }
    __builtin_amdgcn_wave_barrier();

    // [x ; ag] @ Wu1
    short8 Aag = *reinterpret_cast<const short8*>(agp + ml * 34 + quad * 8);
    f32x4 d0 = {0.0f, 0.0f, 0.0f, 0.0f};
    f32x4 d1 = {0.0f, 0.0f, 0.0f, 0.0f};
    d0 = __builtin_amdgcn_mfma_f32_16x16x32_bf16(Ax,  Bu1_00, d0, 0, 0, 0);
    d0 = __builtin_amdgcn_mfma_f32_16x16x32_bf16(Aag, Bu1_10, d0, 0, 0, 0);
    d1 = __builtin_amdgcn_mfma_f32_16x16x32_bf16(Ax,  Bu1_01, d1, 0, 0, 0);
    d1 = __builtin_amdgcn_mfma_f32_16x16x32_bf16(Aag, Bu1_11, d1, 0, 0, 0);
    float bu1c0 = bu1[ml], bu1c1 = bu1[ml + 16];
    unsigned short* hup = hub[w];
    #pragma unroll
    for (int r = 0; r < 4; ++r) {
        hup[(row + r) * 34 + ml]      = f2bf(silu_f(d0[r] + bu1c0));
        hup[(row + r) * 34 + ml + 16] = f2bf(silu_f(d1[r] + bu1c1));
    }
    __builtin_amdgcn_wave_barrier();

    // hu @ Wu2 ; residual + store
    short8 Ahu = *reinterpret_cast<const short8*>(hup + ml * 34 + quad * 8);
    f32x4 e0 = {0.0f, 0.0f, 0.0f, 0.0f};
    f32x4 e1 = {0.0f, 0.0f, 0.0f, 0.0f};
    e0 = __builtin_amdgcn_mfma_f32_16x16x32_bf16(Ahu, Bu2_0, e0, 0, 0, 0);
    e1 = __builtin_amdgcn_mfma_f32_16x16x32_bf16(Ahu, Bu2_1, e1, 0, 0, 0);
    float bu2c0 = bu2[ml], bu2c1 = bu2[ml + 16];
    #pragma unroll
    for (int r = 0; r < 4; ++r) {
        int nn = nbase + row + r;
        float o0 = e0[r] + bu2c0 + lx[w][(row + r) * 33 + ml];
        float o1 = e1[r] + bu2c1 + lx[w][(row + r) * 33 + ml + 16];
        x_out[(size_t)nn * 32 + ml]      = o0;
        x_out[(size_t)nn * 32 + ml + 16] = o1;
        xb_out[(size_t)nn * 32 + ml]      = f2bf(o0);
        xb_out[(size_t)nn * 32 + ml + 16] = f2bf(o1);
    }
}

// ---------------------------------------------------------------- LN + heads, MFMA version
// One wave = 16 nodes (same fragment layout as layer node-phase). LN via 2
// shfl_xor reductions; heads as [16,32]@[32,96] = 6 MFMAs each; second layer
// (96 -> {2,1}) as per-lane partials reduced over ml with 4 shfl_xor.
__global__ __launch_bounds__(256) void final_kernel(
    const float* __restrict__ x, const float* __restrict__ u,
    const float* __restrict__ v,
    const float* __restrict__ ln_g, const float* __restrict__ ln_b,
    const short* __restrict__ wtr1, const float* __restrict__ br1,
    const float* __restrict__ Wr2, const float* __restrict__ br2,
    const short* __restrict__ wts1, const float* __restrict__ bs1,
    const float* __restrict__ Ws2, const float* __restrict__ bs2,
    float* __restrict__ out)
{
    int t = threadIdx.x;
    int w = t >> 6;
    int lane = t & 63;
    int quad = lane >> 4;
    int ml = lane & 15;
    int wid = blockIdx.x * 4 + w;
    int nbase = __builtin_amdgcn_readfirstlane(wid * NPW);
    if (nbase >= N) return;

    // lane (quad,ml) holds x[nbase+ml][quad*8 .. quad*8+7]
    const float4* xs = reinterpret_cast<const float4*>(
        x + (size_t)(nbase + ml) * 32 + quad * 8);
    float4 xa = xs[0], xb4 = xs[1];
    float f[8] = {xa.x, xa.y, xa.z, xa.w, xb4.x, xb4.y, xb4.z, xb4.w};

    // LN statistics for node ml: reduce over k (across the 4 quads)
    float s = 0.0f, ss = 0.0f;
    #pragma unroll
    for (int i = 0; i < 8; ++i) { s += f[i]; ss += f[i] * f[i]; }
    s  += __shfl_xor(s, 16, 64);  s  += __shfl_xor(s, 32, 64);
    ss += __shfl_xor(ss, 16, 64); ss += __shfl_xor(ss, 32, 64);
    float mu = s * (1.0f / 32.0f);
    float var = ss * (1.0f / 32.0f) - mu * mu;
    float rs = rsqrtf(var + 1e-5f);

    // LN affine + bf16 A fragment (A[m=ml][k=quad*8+j])
    const float4* gp = reinterpret_cast<const float4*>(ln_g + quad * 8);
    const float4* bp = reinterpret_cast<const float4*>(ln_b + quad * 8);
    float4 g0 = gp[0], g1 = gp[1], bb0 = bp[0], bb1 = bp[1];
    float gg[8] = {g0.x, g0.y, g0.z, g0.w, g1.x, g1.y, g1.z, g1.w};
    float bb[8] = {bb0.x, bb0.y, bb0.z, bb0.w, bb1.x, bb1.y, bb1.z, bb1.w};
    short8 A;
    #pragma unroll
    for (int i = 0; i < 8; ++i)
        A[i] = (short)f2bf((f[i] - mu) * rs * gg[i] + bb[i]);

    // head layer 1: 6 MFMAs per head (output tiles n = ml + 16*h)
    const short8* r1p = reinterpret_cast<const short8*>(wtr1);
    const short8* s1p = reinterpret_cast<const short8*>(wts1);
    const f32x4 Zf = {0.0f, 0.0f, 0.0f, 0.0f};
    f32x4 hr[6], hs[6];
    #pragma unroll
    for (int h = 0; h < 6; ++h) {
        hr[h] = __builtin_amdgcn_mfma_f32_16x16x32_bf16(A, r1p[(ml + 16 * h) * 4 + quad], Zf, 0, 0, 0);
        hs[h] = __builtin_amdgcn_mfma_f32_16x16x32_bf16(A, s1p[(ml + 16 * h) * 4 + quad], Zf, 0, 0, 0);
    }

    // per-lane second-layer weights for features j = ml + 16*h
    float wr2a[6], wr2b[6], ws2v[6], br1v[6], bs1v[6];
    #pragma unroll
    for (int h = 0; h < 6; ++h) {
        int j = ml + 16 * h;
        float2 wr = reinterpret_cast<const float2*>(Wr2)[j];
        wr2a[h] = wr.x; wr2b[h] = wr.y;
        ws2v[h] = Ws2[j];
        br1v[h] = br1[j];
        bs1v[h] = bs1[j];
    }

    // silu + second layer; lane holds D rows m = quad*4+r, col n = ml+16h.
    // Reduce over n (= over ml lanes) with 4 xor shuffles within the quad group.
    float o0[4], o1[4], o2[4];
    #pragma unroll
    for (int r = 0; r < 4; ++r) {
        float p0 = 0.0f, p1 = 0.0f, p2 = 0.0f;
        #pragma unroll
        for (int h = 0; h < 6; ++h) {
            float a1 = silu_f(hr[h][r] + br1v[h]);
            float a2 = silu_f(hs[h][r] + bs1v[h]);
            p0 = fmaf(a1, wr2a[h], p0);
            p1 = fmaf(a1, wr2b[h], p1);
            p2 = fmaf(a2, ws2v[h], p2);
        }
        p0 += __shfl_xor(p0, 1, 64); p0 += __shfl_xor(p0, 2, 64);
        p0 += __shfl_xor(p0, 4, 64); p0 += __shfl_xor(p0, 8, 64);
        p1 += __shfl_xor(p1, 1, 64); p1 += __shfl_xor(p1, 2, 64);
        p1 += __shfl_xor(p1, 4, 64); p1 += __shfl_xor(p1, 8, 64);
        p2 += __shfl_xor(p2, 1, 64); p2 += __shfl_xor(p2, 2, 64);
        p2 += __shfl_xor(p2, 4, 64); p2 += __shfl_xor(p2, 8, 64);
        o0[r] = p0; o1[r] = p1; o2[r] = p2;
    }

    if (ml == 0) {
        float b20 = br2[0], b21 = br2[1], b22 = bs2[0];
        #pragma unroll
        for (int r = 0; r < 4; ++r) {
            int n = nbase + quad * 4 + r;
            out[n] = u[n * 4 + 3] + o2[r] + b22;
            out[N + 2 * n]     = o0[r] + b20 + v[n * 8 + 6];
            out[N + 2 * n + 1] = o1[r] + b21 + v[n * 8 + 7];
        }
    }
}

} // anonymous namespace

extern "C" void kernel_launch(void* const* d_in, const int* in_sizes, int n_in,
                              void* d_out, int out_size, void* d_ws, size_t ws_size,
                              hipStream_t stream)
{
    const float* u    = (const float*)d_in[0];
    const float* v    = (const float*)d_in[1];
    const float* bno  = (const float*)d_in[2];
    const float* yf   = (const float*)d_in[4];
    const float* pos  = (const float*)d_in[5];
    const int*   ei   = (const int*)d_in[6];
    const float* Wn1  = (const float*)d_in[7];
    const float* bn1  = (const float*)d_in[8];
    const float* Wn2  = (const float*)d_in[9];
    const float* bn2  = (const float*)d_in[10];
    const float* We1  = (const float*)d_in[11];
    const float* be1  = (const float*)d_in[12];
    const float* We2  = (const float*)d_in[13];
    const float* be2  = (const float*)d_in[14];
    const float* Wu1  = (const float*)d_in[15];
    const float* bu1  = (const float*)d_in[16];
    const float* Wu2  = (const float*)d_in[17];
    const float* bu2  = (const float*)d_in[18];
    const float* ln_g = (const float*)d_in[19];
    const float* ln_b = (const float*)d_in[20];
    const float* Wr1  = (const float*)d_in[21];
    const float* br1  = (const float*)d_in[22];
    const float* Wr2  = (const float*)d_in[23];
    const float* br2  = (const float*)d_in[24];
    const float* Ws1  = (const float*)d_in[25];
    const float* bs1  = (const float*)d_in[26];
    const float* Ws2  = (const float*)d_in[27];
    const float* bs2  = (const float*)d_in[28];
    float* out = (float*)d_out;

    // workspace layout (16B-aligned sections)
    int*   deg      = (int*)d_ws;                            // N
    int*   start    = deg + N;                               // N
    int*   bstart   = start + N;                             // NBKT+1
    int*   csr_col  = bstart + 512;                          // E ints
    unsigned short* rbf = (unsigned short*)(csr_col + E);    // E*16 bf16 (51.2 MB)
    float* x0       = (float*)(rbf + (size_t)E * 16);        // N*32 f32
    float* x1       = x0 + (size_t)N * S;                    // N*32 f32
    unsigned short* xb0 = (unsigned short*)(x1 + (size_t)N * S);   // N*32 bf16
    unsigned short* xb1 = xb0 + (size_t)N * S;               // N*32 bf16
    short* wt1      = (short*)(xb1 + (size_t)N * S);         // 5*32*96
    short* wt2      = wt1 + 5 * 32 * 96;                     // 5*32*32
    short* wtu1     = wt2 + 5 * 32 * 32;                     // 5*32*64
    short* wtu2     = wtu1 + 5 * 32 * 64;                    // 5*32*32
    short* wtr1     = wtu2 + 5 * 32 * 32;                    // 96*32 (head r, [n][k])
    short* wts1     = wtr1 + 96 * 32;                        // 96*32 (head s, [n][k])
    int*   hist     = (int*)(wts1 + 96 * 32);                // NBKT*256
    int*   basem    = hist + NBKT * 256;                     // NBKT*256

    // transient alias (dead before node_embed writes x0 / layer writes x1):
    //   edgebuf: E*16B bucket-ordered {col, dist, row} == x0..xb0 (E*16 == N*32*4*2)
    uint4* edgebuf = (uint4*)x0;

    passA_kernel<<<256, 256, 0, stream>>>(ei, hist);
    p1_kernel<<<1, 512, 0, stream>>>(hist, bstart);
    p2_kernel<<<NBKT, 256, 0, stream>>>(hist, bstart, basem);
    passB_kernel<<<256, 256, 0, stream>>>(ei, pos, basem, edgebuf);
    passC_kernel<<<NBKT, 256, 0, stream>>>(edgebuf, bstart, deg, start, csr_col, rbf);
    prep_wt_kernel<<<60, 256, 0, stream>>>(We1, We2, Wu1, Wu2, Wr1, Ws1,
                                           wt1, wt2, wtu1, wtu2, wtr1, wts1);

    node_embed_kernel<<<NB, 256, 0, stream>>>(u, v, bno, yf, Wn1, bn1, Wn2, bn2,
                                              x0, xb0);

    float* xin = x0;  float* xout = x1;
    unsigned short* xbin = xb0;  unsigned short* xbout = xb1;
    for (int l = 0; l < L; ++l) {
        layer_kernel<<<LB2, 256, 0, stream>>>(
            deg, start, csr_col, rbf, xin, xbin, xout, xbout,
            wt1 + (size_t)l * 32 * 96,  be1 + (size_t)l * 32,
            wt2 + (size_t)l * 32 * 32,  be2 + (size_t)l * 32,
            wtu1 + (size_t)l * 32 * 64, bu1 + (size_t)l * 32,
            wtu2 + (size_t)l * 32 * 32, bu2 + (size_t)l * 32);
        float* tf = xin; xin = xout; xout = tf;
        unsigned short* tb = xbin; xbin = xbout; xbout = tb;
    }

    final_kernel<<<LB2, 256, 0, stream>>>(xin, u, v, ln_g, ln_b,
                                          wtr1, br1, Wr2, br2,
                                          wts1, bs1, Ws2, bs2, out);
}

// Round 8
// 511.412 us; speedup vs baseline: 1.1902x; 1.0292x over previous
//
#include <hip/hip_runtime.h>
#include <cmath>

namespace {

constexpr int N = 100000;
constexpr int E = 1600000;
constexpr int S = 32;           // hidden
constexpr int L = 5;            // layers
constexpr int NB = (N + 255) / 256;   // node-per-thread kernels
constexpr int NPW = 16;               // nodes per wave in layer kernel
constexpr int LB2 = (N + 63) / 64;    // 1563 blocks (4 waves/block, 16 nodes/wave)
constexpr int NBKT = 391;             // CSR buckets: row>>8, 256 rows each
constexpr int EPB  = E / 256;         // 6250 edges per histogram/scatter block
constexpr float PI_F    = 3.14159265358979323846f;
constexpr float SQRT2_F = 1.41421356237309515f;

typedef __attribute__((ext_vector_type(8))) short short8;   // 8 x bf16
typedef __attribute__((ext_vector_type(4))) float f32x4;

// fast silu: v_rcp_f32 instead of IEEE division (saves ~10 VALU instrs/call)
__device__ __forceinline__ float silu_f(float x) {
    return x * __builtin_amdgcn_rcpf(1.0f + __expf(-x));
}

// float -> bf16 bits, round-to-nearest-even
__device__ __forceinline__ unsigned short f2bf(float f) {
    unsigned int u = __float_as_uint(f);
    u = (u + 0x7FFFu + ((u >> 16) & 1u)) >> 16;
    return (unsigned short)u;
}

__device__ __forceinline__ int rl(int v, int i) {
    return __builtin_amdgcn_readlane(v, i);
}

// 32-bit byte-offset gather of a 16B xb fragment: base + col*64 + quad*16
__device__ __forceinline__ short8 ld_xb(const unsigned short* base, int col, int quad) {
    unsigned off = ((unsigned)col << 6) | ((unsigned)quad << 4);
    return *reinterpret_cast<const short8*>(reinterpret_cast<const char*>(base) + off);
}

// 32-bit byte-offset read of an rbf half-row: base + slot*32 + quad*16
__device__ __forceinline__ short8 ld_rbf(const unsigned short* base, int slot, int quad) {
    unsigned off = ((unsigned)slot << 5) | ((unsigned)quad << 4);
    return *reinterpret_cast<const short8*>(reinterpret_cast<const char*>(base) + off);
}

// advance (i,t) to the next tile of this wave's 16-node batch (uniform)
__device__ __forceinline__ void adv(int& i, int& t, int vd) {
    ++t;
    while (i < 16) {
        int dgi = rl(vd, i);
        int nt = (dgi + 15) >> 4;
        if (t < nt) break;
        t = 0; ++i;
    }
}

// CSR slot for (i,t) at lane row ml; clamped into the node's own range
__device__ __forceinline__ int slotOf(int i, int t, int vs, int vd, int ml) {
    if (i >= 16) return 0;
    int s0 = rl(vs, i);
    int dg = rl(vd, i);
    int smax = s0 + ((dg > 0) ? dg : 1) - 1;
    int s = s0 + t * 16 + ml;
    return min(s, smax);
}

// ---------------------------------------------------------------- passA: bucket histogram
__global__ __launch_bounds__(256) void passA_kernel(
    const int* __restrict__ ei, int* __restrict__ hist)
{
    __shared__ int h[NBKT];
    int t = threadIdx.x;
    int blk = blockIdx.x;
    for (int b = t; b < NBKT; b += 256) h[b] = 0;
    __syncthreads();
    int base = blk * EPB;
    for (int i = t; i < EPB; i += 256) {
        int r = ei[base + i];
        atomicAdd(&h[r >> 8], 1);
    }
    __syncthreads();
    for (int b = t; b < NBKT; b += 256) hist[b * 256 + blk] = h[b];
}

// ---------------------------------------------------------------- p1: bucket totals + exclusive prefix
__global__ __launch_bounds__(512) void p1_kernel(
    const int* __restrict__ hist, int* __restrict__ bstart)
{
    __shared__ int tot[NBKT + 1];
    int t = threadIdx.x;
    if (t < NBKT) {
        int s = 0;
        for (int b = 0; b < 256; ++b) s += hist[t * 256 + b];
        tot[t] = s;
    }
    __syncthreads();
    if (t == 0) {
        int a = 0;
        for (int i = 0; i < NBKT; ++i) { int c = tot[i]; tot[i] = a; a += c; }
        tot[NBKT] = a;   // == E
    }
    __syncthreads();
    if (t <= NBKT) bstart[t] = tot[t];
}

// ---------------------------------------------------------------- p2: per-(bin,blk) scatter bases
__global__ __launch_bounds__(256) void p2_kernel(
    const int* __restrict__ hist, const int* __restrict__ bstart,
    int* __restrict__ base)
{
    __shared__ int pre[256];
    int t = threadIdx.x;
    int bin = blockIdx.x;
    int h = hist[bin * 256 + t];
    pre[t] = h;
    __syncthreads();
    #pragma unroll
    for (int off = 1; off < 256; off <<= 1) {
        int v = (t >= off) ? pre[t - off] : 0;
        __syncthreads();
        pre[t] += v;
        __syncthreads();
    }
    base[bin * 256 + t] = bstart[bin] + pre[t] - h;   // exclusive over blocks
}

// ---------------------------------------------------------------- passB: scatter to bucket staging
__global__ __launch_bounds__(256) void passB_kernel(
    const int* __restrict__ ei, const float* __restrict__ pos,
    const int* __restrict__ base, uint4* __restrict__ edgebuf)
{
    __shared__ int cur[NBKT];
    int t = threadIdx.x;
    int blk = blockIdx.x;
    for (int b = t; b < NBKT; b += 256) cur[b] = base[b * 256 + blk];
    __syncthreads();
    int ebase = blk * EPB;
    for (int i = t; i < EPB; i += 256) {
        int e = ebase + i;
        int r = ei[e];
        int c = ei[E + e];
        float2 pr = reinterpret_cast<const float2*>(pos)[r];
        float2 pc = reinterpret_cast<const float2*>(pos)[c];
        float dx = pr.x - pc.x, dy = pr.y - pc.y;
        float d = sqrtf(dx * dx + dy * dy);   // pos-mean cancels
        int slot = atomicAdd(&cur[r >> 8], 1);   // LDS atomic
        edgebuf[slot] = make_uint4((unsigned)c, __float_as_uint(d), (unsigned)r, 0u);
    }
}

// ---------------------------------------------------------------- passC: per-bucket deg/start/rank + fused rbf
__global__ __launch_bounds__(256) void passC_kernel(
    const uint4* __restrict__ edgebuf, const int* __restrict__ bstart,
    int* __restrict__ deg, int* __restrict__ start,
    int* __restrict__ csr_col, unsigned short* __restrict__ rbf_buf)
{
    __shared__ int cnt[256];
    __shared__ int pre[256];
    __shared__ int cur[256];
    int t = threadIdx.x;
    int bkt = blockIdx.x;
    int s0 = bstart[bkt], s1 = bstart[bkt + 1];

    cnt[t] = 0;
    __syncthreads();
    for (int i = s0 + t; i < s1; i += 256) {
        unsigned r = edgebuf[i].z;
        atomicAdd(&cnt[r & 255], 1);
    }
    __syncthreads();
    int c0 = cnt[t];
    pre[t] = c0;
    __syncthreads();
    #pragma unroll
    for (int off = 1; off < 256; off <<= 1) {
        int v = (t >= off) ? pre[t - off] : 0;
        __syncthreads();
        pre[t] += v;
        __syncthreads();
    }
    int row = bkt * 256 + t;
    int st = s0 + pre[t] - c0;   // exclusive
    if (row < N) {
        deg[row] = c0;
        start[row] = st;
    }
    cur[t] = st;
    __syncthreads();

    for (int i = s0 + t; i < s1; i += 256) {
        uint4 e = edgebuf[i];
        int slot = atomicAdd(&cur[e.z & 255], 1);   // LDS atomic
        csr_col[slot] = (int)e.x;
        float d = __uint_as_float(e.y);

        float sn = __sinf(PI_F * d);
        float c1 = __cosf(PI_F * d);
        float inv = SQRT2_F / (d + 1e-8f);
        float tc = 2.0f * c1;
        float sk = sn, skm = 0.0f;
        unsigned int pk[8];
        #pragma unroll
        for (int k = 0; k < 8; ++k) {
            float r0 = sk * inv;
            float s2 = tc * sk - skm; skm = sk; sk = s2;
            float r1 = sk * inv;
            float s3 = tc * sk - skm; skm = sk; sk = s3;
            pk[k] = (unsigned int)f2bf(r0) | ((unsigned int)f2bf(r1) << 16);
        }
        uint4* out = reinterpret_cast<uint4*>(rbf_buf + (size_t)slot * 16);
        out[0] = make_uint4(pk[0], pk[1], pk[2], pk[3]);
        out[1] = make_uint4(pk[4], pk[5], pk[6], pk[7]);
    }
}

// ---------------------------------------------------------------- bf16 weight prep (transposed [n][k])
__global__ __launch_bounds__(256) void prep_wt_kernel(
    const float* __restrict__ We1, const float* __restrict__ We2,
    const float* __restrict__ Wu1, const float* __restrict__ Wu2,
    const float* __restrict__ Wr1, const float* __restrict__ Ws1,
    short* __restrict__ wt1, short* __restrict__ wt2,
    short* __restrict__ wtu1, short* __restrict__ wtu2,
    short* __restrict__ wtr1, short* __restrict__ wts1)
{
    int idx = blockIdx.x * 256 + threadIdx.x;
    if (idx < 5 * 32 * 96) {
        int l = idx / (32 * 96), r = idx % (32 * 96), n = r / 96, k = r % 96;
        float v = (k < 80) ? We1[((size_t)l * 80 + k) * 32 + n] : 0.0f;
        wt1[idx] = (short)f2bf(v);
    }
    if (idx < 5 * 32 * 32) {
        int l = idx / 1024, r = idx % 1024, n = r / 32, k = r % 32;
        wt2[idx]  = (short)f2bf(We2[((size_t)l * 32 + k) * 32 + n]);
        wtu2[idx] = (short)f2bf(Wu2[((size_t)l * 32 + k) * 32 + n]);
    }
    if (idx < 5 * 32 * 64) {
        int l = idx / 2048, r = idx % 2048, n = r / 64, k = r % 64;
        wtu1[idx] = (short)f2bf(Wu1[((size_t)l * 64 + k) * 32 + n]);
    }
    if (idx < 96 * 32) {
        int n = idx / 32, k = idx % 32;   // head weights [n=96][k=32]
        wtr1[idx] = (short)f2bf(Wr1[k * 96 + n]);
        wts1[idx] = (short)f2bf(Ws1[k * 96 + n]);
    }
}

// ---------------------------------------------------------------- node embed (writes fp32 x + bf16 xb)
__global__ __launch_bounds__(256) void node_embed_kernel(
    const float* __restrict__ u, const float* __restrict__ v,
    const float* __restrict__ bnorm, const float* __restrict__ yf,
    const float* __restrict__ Wn1, const float* __restrict__ bn1,
    const float* __restrict__ Wn2, const float* __restrict__ bn2,
    float* __restrict__ x, unsigned short* __restrict__ xb)
{
    int n = blockIdx.x * 256 + threadIdx.x;
    if (n >= N) return;

    float f[10];
    float4 uu = reinterpret_cast<const float4*>(u)[n];
    f[0] = uu.x; f[1] = uu.y; f[2] = uu.z; f[3] = uu.w;
    float4 v0 = reinterpret_cast<const float4*>(v)[2 * n];
    float4 v1 = reinterpret_cast<const float4*>(v)[2 * n + 1];
    f[4] = sqrtf(v0.x * v0.x + v0.y * v0.y);
    f[5] = sqrtf(v0.z * v0.z + v0.w * v0.w);
    f[6] = sqrtf(v1.x * v1.x + v1.y * v1.y);
    f[7] = sqrtf(v1.z * v1.z + v1.w * v1.w);
    float2 bb = reinterpret_cast<const float2*>(bnorm)[n];
    f[8] = sqrtf(bb.x * bb.x + bb.y * bb.y);
    float2 yy = reinterpret_cast<const float2*>(yf)[n];
    f[9] = sqrtf(yy.x * yy.x + yy.y * yy.y);

    float h[64];
    #pragma unroll
    for (int j = 0; j < 64; ++j) h[j] = bn1[j];
    #pragma unroll
    for (int i = 0; i < 10; ++i) {
        float t = f[i];
        #pragma unroll
        for (int j = 0; j < 64; ++j) h[j] = fmaf(t, Wn1[i * 64 + j], h[j]);
    }
    #pragma unroll
    for (int j = 0; j < 64; ++j) h[j] = silu_f(h[j]);

    float o[32];
    #pragma unroll
    for (int j = 0; j < 32; ++j) o[j] = bn2[j];
    #pragma unroll
    for (int i = 0; i < 64; ++i) {
        float t = h[i];
        #pragma unroll
        for (int j = 0; j < 32; ++j) o[j] = fmaf(t, Wn2[i * 32 + j], o[j]);
    }
    float4* xo = reinterpret_cast<float4*>(x + (size_t)n * 32);
    #pragma unroll
    for (int i = 0; i < 8; ++i)
        xo[i] = make_float4(o[4 * i], o[4 * i + 1], o[4 * i + 2], o[4 * i + 3]);

    unsigned int* xbu = reinterpret_cast<unsigned int*>(xb) + (size_t)n * 16;
    #pragma unroll
    for (int i = 0; i < 16; ++i)
        xbu[i] = (unsigned int)f2bf(o[2 * i]) | ((unsigned int)f2bf(o[2 * i + 1]) << 16);
}

// ---------------------------------------------------------------- fused layer v3.2
// v3.1 minus the lx LDS buffer (residual re-reads x_in from global at epilogue,
// coalesced + L2-hot). LDS 30720 -> 22016 B => 7 blocks/CU resident; whole grid
// co-resident => latency hiding for the edge-phase gathers.
__global__ __launch_bounds__(256, 7) void layer_kernel(
    const int* __restrict__ deg, const int* __restrict__ start,
    const int* __restrict__ csr_col, const unsigned short* __restrict__ rbf_buf,
    const float* __restrict__ x_in, const unsigned short* __restrict__ xb_in,
    float* __restrict__ x_out, unsigned short* __restrict__ xb_out,
    const short* __restrict__ wt1, const float* __restrict__ b1,
    const short* __restrict__ wt2, const float* __restrict__ b2,
    const short* __restrict__ wtu1, const float* __restrict__ bu1,
    const short* __restrict__ wtu2, const float* __restrict__ bu2)
{
    __shared__ unsigned short lsh[4][16 * 34];   // sh  (bf16), stride 34
    __shared__ unsigned short agb[4][16 * 34];   // ag  (bf16)
    __shared__ unsigned short hub[4][16 * 34];   // hu  (bf16)
    __shared__ float lrp[4][16 * 33];            // rowpart b1 + x@W1[0:32,:] (fp32)
    __shared__ float ldg[4][16];
    __shared__ float livd[4][16];

    int t = threadIdx.x;
    int w = t >> 6;
    int lane = t & 63;
    int quad = lane >> 4;
    int ml = lane & 15;
    int wid = blockIdx.x * 4 + w;
    int nbase = __builtin_amdgcn_readfirstlane(wid * NPW);
    if (nbase >= N) return;   // N % 16 == 0, so valid waves own full batches

    // ---- batch metadata: lane ml holds node ml's start/deg
    int vs = start[nbase + ml];
    int vd = deg[nbase + ml];

    // ---- edge-phase B fragments (wt1 [32][96])
    const short8* wp = reinterpret_cast<const short8*>(wt1);
    short8 B00 = wp[(ml     ) * 12 + 0 * 4 + quad];
    short8 B01 = wp[(ml     ) * 12 + 1 * 4 + quad];
    short8 B02 = wp[(ml     ) * 12 + 2 * 4 + quad];
    short8 B10 = wp[(ml + 16) * 12 + 0 * 4 + quad];
    short8 B11 = wp[(ml + 16) * 12 + 1 * 4 + quad];
    short8 B12 = wp[(ml + 16) * 12 + 2 * 4 + quad];

    // node-phase / rowpart x A-fragment (A[m=node ml][k=quad*8+j])
    short8 Ax = ld_xb(xb_in, nbase + ml, quad);

    float b1j0 = b1[ml];
    float b1j1 = b1[ml + 16];

    // ---- zero sh, stash deg floats
    unsigned short* lshp = lsh[w];
    for (int k = lane; k < 16 * 34; k += 64) lshp[k] = 0;
    if (lane < 16) {
        ldg[w][lane] = (float)vd;
        livd[w][lane] = 1.0f / fmaxf((float)vd, 1.0f);
    }

    // ---- hoisted row-node partial: rp[m][j] = b1[j] + x[m] @ W1[0:32, j]
    float* rpp = lrp[w];
    {
        f32x4 rp0 = {b1j0, b1j0, b1j0, b1j0};
        f32x4 rp1 = {b1j1, b1j1, b1j1, b1j1};
        rp0 = __builtin_amdgcn_mfma_f32_16x16x32_bf16(Ax, B00, rp0, 0, 0, 0);
        rp1 = __builtin_amdgcn_mfma_f32_16x16x32_bf16(Ax, B10, rp1, 0, 0, 0);
        int row = quad * 4;
        #pragma unroll
        for (int r = 0; r < 4; ++r) {
            rpp[(row + r) * 33 + ml]      = rp0[r];
            rpp[(row + r) * 33 + ml + 16] = rp1[r];
        }
    }
    __builtin_amdgcn_wave_barrier();

    // ---- software-pipelined edge loop
    const short8 Z8 = {0, 0, 0, 0, 0, 0, 0, 0};
    int i0 = 0, t0 = -1; adv(i0, t0, vd);
    int i1 = i0, t1 = t0; adv(i1, t1, vd);
    int i2 = i1, t2 = t1; adv(i2, t2, vd);

    int slot0 = slotOf(i0, t0, vs, vd, ml);
    int slot1 = slotOf(i1, t1, vs, vd, ml);
    int colCur  = csr_col[slot0];
    int colNext = csr_col[slot1];
    short8 A1c = ld_xb(xb_in, colCur, quad);
    short8 A2c = Z8;
    if (quad < 2) A2c = ld_rbf(rbf_buf, slot0, quad);

    float colp0 = 0.0f, colp1 = 0.0f;
    while (i0 < 16) {
        // stage 2: col two ahead
        int slot2 = slotOf(i2, t2, vs, vd, ml);
        int colNN = csr_col[slot2];
        // stage 1: fragments one ahead
        short8 A1n = ld_xb(xb_in, colNext, quad);
        short8 A2n = Z8;
        if (quad < 2) A2n = ld_rbf(rbf_buf, slot1, quad);

        // stage 0: compute current tile (acc seeded with hoisted rowpart + b1)
        float rpa = rpp[i0 * 33 + ml];
        float rpb = rpp[i0 * 33 + ml + 16];
        f32x4 acc0 = {rpa, rpa, rpa, rpa};
        f32x4 acc1 = {rpb, rpb, rpb, rpb};
        acc0 = __builtin_amdgcn_mfma_f32_16x16x32_bf16(A1c, B01, acc0, 0, 0, 0);
        acc0 = __builtin_amdgcn_mfma_f32_16x16x32_bf16(A2c, B02, acc0, 0, 0, 0);
        acc1 = __builtin_amdgcn_mfma_f32_16x16x32_bf16(A1c, B11, acc1, 0, 0, 0);
        acc1 = __builtin_amdgcn_mfma_f32_16x16x32_bf16(A2c, B12, acc1, 0, 0, 0);

        int dg0 = rl(vd, i0);
        int rowbase = t0 * 16 + quad * 4;
        #pragma unroll
        for (int r = 0; r < 4; ++r) {
            bool vld = (rowbase + r) < dg0;
            colp0 += vld ? silu_f(acc0[r]) : 0.0f;
            colp1 += vld ? silu_f(acc1[r]) : 0.0f;
        }
        if (t0 == ((dg0 + 15) >> 4) - 1) {   // last tile of node i0 (uniform)
            colp0 += __shfl_xor(colp0, 16, 64);
            colp0 += __shfl_xor(colp0, 32, 64);
            colp1 += __shfl_xor(colp1, 16, 64);
            colp1 += __shfl_xor(colp1, 32, 64);
            if (quad == 0) {
                lshp[i0 * 34 + ml]      = f2bf(colp0);
                lshp[i0 * 34 + ml + 16] = f2bf(colp1);
            }
            colp0 = 0.0f; colp1 = 0.0f;
        }

        // rotate pipeline
        A1c = A1n; A2c = A2n;
        colNext = colNN; slot1 = slot2;
        i0 = i1; t0 = t1; i1 = i2; t1 = t2;
        adv(i2, t2, vd);
    }
    __builtin_amdgcn_wave_barrier();

    // ---- node phase: 16-node batch, 8 MFMAs
    const short8* w2p = reinterpret_cast<const short8*>(wt2);
    short8 Bw2_0 = w2p[(ml     ) * 4 + quad];
    short8 Bw2_1 = w2p[(ml + 16) * 4 + quad];
    const short8* u1p = reinterpret_cast<const short8*>(wtu1);
    short8 Bu1_00 = u1p[(ml     ) * 8 + quad];       // k 0..31 (x)
    short8 Bu1_10 = u1p[(ml     ) * 8 + 4 + quad];   // k 32..63 (ag)
    short8 Bu1_01 = u1p[(ml + 16) * 8 + quad];
    short8 Bu1_11 = u1p[(ml + 16) * 8 + 4 + quad];
    const short8* u2p = reinterpret_cast<const short8*>(wtu2);
    short8 Bu2_0 = u2p[(ml     ) * 4 + quad];
    short8 Bu2_1 = u2p[(ml + 16) * 4 + quad];

    // sh @ W2
    short8 Ash = *reinterpret_cast<const short8*>(lshp + ml * 34 + quad * 8);
    f32x4 c0 = {0.0f, 0.0f, 0.0f, 0.0f};
    f32x4 c1 = {0.0f, 0.0f, 0.0f, 0.0f};
    c0 = __builtin_amdgcn_mfma_f32_16x16x32_bf16(Ash, Bw2_0, c0, 0, 0, 0);
    c1 = __builtin_amdgcn_mfma_f32_16x16x32_bf16(Ash, Bw2_1, c1, 0, 0, 0);
    float b2c0 = b2[ml], b2c1 = b2[ml + 16];
    unsigned short* agp = agb[w];
    int row = quad * 4;
    #pragma unroll
    for (int r = 0; r < 4; ++r) {
        float fd = ldg[w][row + r];
        float iv = livd[w][row + r];
        agp[(row + r) * 34 + ml]      = f2bf((c0[r] + fd * b2c0) * iv);
        agp[(row + r) * 34 + ml + 16] = f2bf((c1[r] + fd * b2c1) * iv);
    }
    __builtin_amdgcn_wave_barrier();

    // [x ; ag] @ Wu1
    short8 Aag = *reinterpret_cast<const short8*>(agp + ml * 34 + quad * 8);
    f32x4 d0 = {0.0f, 0.0f, 0.0f, 0.0f};
    f32x4 d1 = {0.0f, 0.0f, 0.0f, 0.0f};
    d0 = __builtin_amdgcn_mfma_f32_16x16x32_bf16(Ax,  Bu1_00, d0, 0, 0, 0);
    d0 = __builtin_amdgcn_mfma_f32_16x16x32_bf16(Aag, Bu1_10, d0, 0, 0, 0);
    d1 = __builtin_amdgcn_mfma_f32_16x16x32_bf16(Ax,  Bu1_01, d1, 0, 0, 0);
    d1 = __builtin_amdgcn_mfma_f32_16x16x32_bf16(Aag, Bu1_11, d1, 0, 0, 0);
    float bu1c0 = bu1[ml], bu1c1 = bu1[ml + 16];
    unsigned short* hup = hub[w];
    #pragma unroll
    for (int r = 0; r < 4; ++r) {
        hup[(row + r) * 34 + ml]      = f2bf(silu_f(d0[r] + bu1c0));
        hup[(row + r) * 34 + ml + 16] = f2bf(silu_f(d1[r] + bu1c1));
    }
    __builtin_amdgcn_wave_barrier();

    // hu @ Wu2 ; residual (x_in re-read, coalesced + L2-hot) + store
    short8 Ahu = *reinterpret_cast<const short8*>(hup + ml * 34 + quad * 8);
    float xr0[4], xr1[4];
    #pragma unroll
    for (int r = 0; r < 4; ++r) {
        int nn = nbase + row + r;
        xr0[r] = x_in[(size_t)nn * 32 + ml];
        xr1[r] = x_in[(size_t)nn * 32 + ml + 16];
    }
    f32x4 e0 = {0.0f, 0.0f, 0.0f, 0.0f};
    f32x4 e1 = {0.0f, 0.0f, 0.0f, 0.0f};
    e0 = __builtin_amdgcn_mfma_f32_16x16x32_bf16(Ahu, Bu2_0, e0, 0, 0, 0);
    e1 = __builtin_amdgcn_mfma_f32_16x16x32_bf16(Ahu, Bu2_1, e1, 0, 0, 0);
    float bu2c0 = bu2[ml], bu2c1 = bu2[ml + 16];
    #pragma unroll
    for (int r = 0; r < 4; ++r) {
        int nn = nbase + row + r;
        float o0 = e0[r] + bu2c0 + xr0[r];
        float o1 = e1[r] + bu2c1 + xr1[r];
        x_out[(size_t)nn * 32 + ml]      = o0;
        x_out[(size_t)nn * 32 + ml + 16] = o1;
        xb_out[(size_t)nn * 32 + ml]      = f2bf(o0);
        xb_out[(size_t)nn * 32 + ml + 16] = f2bf(o1);
    }
}

// ---------------------------------------------------------------- LN + heads, MFMA version
__global__ __launch_bounds__(256) void final_kernel(
    const float* __restrict__ x, const float* __restrict__ u,
    const float* __restrict__ v,
    const float* __restrict__ ln_g, const float* __restrict__ ln_b,
    const short* __restrict__ wtr1, const float* __restrict__ br1,
    const float* __restrict__ Wr2, const float* __restrict__ br2,
    const short* __restrict__ wts1, const float* __restrict__ bs1,
    const float* __restrict__ Ws2, const float* __restrict__ bs2,
    float* __restrict__ out)
{
    int t = threadIdx.x;
    int w = t >> 6;
    int lane = t & 63;
    int quad = lane >> 4;
    int ml = lane & 15;
    int wid = blockIdx.x * 4 + w;
    int nbase = __builtin_amdgcn_readfirstlane(wid * NPW);
    if (nbase >= N) return;

    // lane (quad,ml) holds x[nbase+ml][quad*8 .. quad*8+7]
    const float4* xs = reinterpret_cast<const float4*>(
        x + (size_t)(nbase + ml) * 32 + quad * 8);
    float4 xa = xs[0], xb4 = xs[1];
    float f[8] = {xa.x, xa.y, xa.z, xa.w, xb4.x, xb4.y, xb4.z, xb4.w};

    // LN statistics for node ml: reduce over k (across the 4 quads)
    float s = 0.0f, ss = 0.0f;
    #pragma unroll
    for (int i = 0; i < 8; ++i) { s += f[i]; ss += f[i] * f[i]; }
    s  += __shfl_xor(s, 16, 64);  s  += __shfl_xor(s, 32, 64);
    ss += __shfl_xor(ss, 16, 64); ss += __shfl_xor(ss, 32, 64);
    float mu = s * (1.0f / 32.0f);
    float var = ss * (1.0f / 32.0f) - mu * mu;
    float rs = rsqrtf(var + 1e-5f);

    // LN affine + bf16 A fragment (A[m=ml][k=quad*8+j])
    const float4* gp = reinterpret_cast<const float4*>(ln_g + quad * 8);
    const float4* bp = reinterpret_cast<const float4*>(ln_b + quad * 8);
    float4 g0 = gp[0], g1 = gp[1], bb0 = bp[0], bb1 = bp[1];
    float gg[8] = {g0.x, g0.y, g0.z, g0.w, g1.x, g1.y, g1.z, g1.w};
    float bb[8] = {bb0.x, bb0.y, bb0.z, bb0.w, bb1.x, bb1.y, bb1.z, bb1.w};
    short8 A;
    #pragma unroll
    for (int i = 0; i < 8; ++i)
        A[i] = (short)f2bf((f[i] - mu) * rs * gg[i] + bb[i]);

    // head layer 1: 6 MFMAs per head (output tiles n = ml + 16*h)
    const short8* r1p = reinterpret_cast<const short8*>(wtr1);
    const short8* s1p = reinterpret_cast<const short8*>(wts1);
    const f32x4 Zf = {0.0f, 0.0f, 0.0f, 0.0f};
    f32x4 hr[6], hs[6];
    #pragma unroll
    for (int h = 0; h < 6; ++h) {
        hr[h] = __builtin_amdgcn_mfma_f32_16x16x32_bf16(A, r1p[(ml + 16 * h) * 4 + quad], Zf, 0, 0, 0);
        hs[h] = __builtin_amdgcn_mfma_f32_16x16x32_bf16(A, s1p[(ml + 16 * h) * 4 + quad], Zf, 0, 0, 0);
    }

    // per-lane second-layer weights for features j = ml + 16*h
    float wr2a[6], wr2b[6], ws2v[6], br1v[6], bs1v[6];
    #pragma unroll
    for (int h = 0; h < 6; ++h) {
        int j = ml + 16 * h;
        float2 wr = reinterpret_cast<const float2*>(Wr2)[j];
        wr2a[h] = wr.x; wr2b[h] = wr.y;
        ws2v[h] = Ws2[j];
        br1v[h] = br1[j];
        bs1v[h] = bs1[j];
    }

    // silu + second layer; lane holds D rows m = quad*4+r, col n = ml+16h.
    float o0[4], o1[4], o2[4];
    #pragma unroll
    for (int r = 0; r < 4; ++r) {
        float p0 = 0.0f, p1 = 0.0f, p2 = 0.0f;
        #pragma unroll
        for (int h = 0; h < 6; ++h) {
            float a1 = silu_f(hr[h][r] + br1v[h]);
            float a2 = silu_f(hs[h][r] + bs1v[h]);
            p0 = fmaf(a1, wr2a[h], p0);
            p1 = fmaf(a1, wr2b[h], p1);
            p2 = fmaf(a2, ws2v[h], p2);
        }
        p0 += __shfl_xor(p0, 1, 64); p0 += __shfl_xor(p0, 2, 64);
        p0 += __shfl_xor(p0, 4, 64); p0 += __shfl_xor(p0, 8, 64);
        p1 += __shfl_xor(p1, 1, 64); p1 += __shfl_xor(p1, 2, 64);
        p1 += __shfl_xor(p1, 4, 64); p1 += __shfl_xor(p1, 8, 64);
        p2 += __shfl_xor(p2, 1, 64); p2 += __shfl_xor(p2, 2, 64);
        p2 += __shfl_xor(p2, 4, 64); p2 += __shfl_xor(p2, 8, 64);
        o0[r] = p0; o1[r] = p1; o2[r] = p2;
    }

    if (ml == 0) {
        float b20 = br2[0], b21 = br2[1], b22 = bs2[0];
        #pragma unroll
        for (int r = 0; r < 4; ++r) {
            int n = nbase + quad * 4 + r;
            out[n] = u[n * 4 + 3] + o2[r] + b22;
            out[N + 2 * n]     = o0[r] + b20 + v[n * 8 + 6];
            out[N + 2 * n + 1] = o1[r] + b21 + v[n * 8 + 7];
        }
    }
}

} // anonymous namespace

extern "C" void kernel_launch(void* const* d_in, const int* in_sizes, int n_in,
                              void* d_out, int out_size, void* d_ws, size_t ws_size,
                              hipStream_t stream)
{
    const float* u    = (const float*)d_in[0];
    const float* v    = (const float*)d_in[1];
    const float* bno  = (const float*)d_in[2];
    const float* yf   = (const float*)d_in[4];
    const float* pos  = (const float*)d_in[5];
    const int*   ei   = (const int*)d_in[6];
    const float* Wn1  = (const float*)d_in[7];
    const float* bn1  = (const float*)d_in[8];
    const float* Wn2  = (const float*)d_in[9];
    const float* bn2  = (const float*)d_in[10];
    const float* We1  = (const float*)d_in[11];
    const float* be1  = (const float*)d_in[12];
    const float* We2  = (const float*)d_in[13];
    const float* be2  = (const float*)d_in[14];
    const float* Wu1  = (const float*)d_in[15];
    const float* bu1  = (const float*)d_in[16];
    const float* Wu2  = (const float*)d_in[17];
    const float* bu2  = (const float*)d_in[18];
    const float* ln_g = (const float*)d_in[19];
    const float* ln_b = (const float*)d_in[20];
    const float* Wr1  = (const float*)d_in[21];
    const float* br1  = (const float*)d_in[22];
    const float* Wr2  = (const float*)d_in[23];
    const float* br2  = (const float*)d_in[24];
    const float* Ws1  = (const float*)d_in[25];
    const float* bs1  = (const float*)d_in[26];
    const float* Ws2  = (const float*)d_in[27];
    const float* bs2  = (const float*)d_in[28];
    float* out = (float*)d_out;

    // workspace layout (16B-aligned sections)
    int*   deg      = (int*)d_ws;                            // N
    int*   start    = deg + N;                               // N
    int*   bstart   = start + N;                             // NBKT+1
    int*   csr_col  = bstart + 512;                          // E ints
    unsigned short* rbf = (unsigned short*)(csr_col + E);    // E*16 bf16 (51.2 MB)
    float* x0       = (float*)(rbf + (size_t)E * 16);        // N*32 f32
    float* x1       = x0 + (size_t)N * S;                    // N*32 f32
    unsigned short* xb0 = (unsigned short*)(x1 + (size_t)N * S);   // N*32 bf16
    unsigned short* xb1 = xb0 + (size_t)N * S;               // N*32 bf16
    short* wt1      = (short*)(xb1 + (size_t)N * S);         // 5*32*96
    short* wt2      = wt1 + 5 * 32 * 96;                     // 5*32*32
    short* wtu1     = wt2 + 5 * 32 * 32;                     // 5*32*64
    short* wtu2     = wtu1 + 5 * 32 * 64;                    // 5*32*32
    short* wtr1     = wtu2 + 5 * 32 * 32;                    // 96*32 (head r, [n][k])
    short* wts1     = wtr1 + 96 * 32;                        // 96*32 (head s, [n][k])
    int*   hist     = (int*)(wts1 + 96 * 32);                // NBKT*256
    int*   basem    = hist + NBKT * 256;                     // NBKT*256

    // transient alias (dead before node_embed writes x0 / layer writes x1):
    //   edgebuf: E*16B bucket-ordered {col, dist, row} == x0..xb0 (E*16 == N*32*4*2)
    uint4* edgebuf = (uint4*)x0;

    passA_kernel<<<256, 256, 0, stream>>>(ei, hist);
    p1_kernel<<<1, 512, 0, stream>>>(hist, bstart);
    p2_kernel<<<NBKT, 256, 0, stream>>>(hist, bstart, basem);
    passB_kernel<<<256, 256, 0, stream>>>(ei, pos, basem, edgebuf);
    passC_kernel<<<NBKT, 256, 0, stream>>>(edgebuf, bstart, deg, start, csr_col, rbf);
    prep_wt_kernel<<<60, 256, 0, stream>>>(We1, We2, Wu1, Wu2, Wr1, Ws1,
                                           wt1, wt2, wtu1, wtu2, wtr1, wts1);

    node_embed_kernel<<<NB, 256, 0, stream>>>(u, v, bno, yf, Wn1, bn1, Wn2, bn2,
                                              x0, xb0);

    float* xin = x0;  float* xout = x1;
    unsigned short* xbin = xb0;  unsigned short* xbout = xb1;
    for (int l = 0; l < L; ++l) {
        layer_kernel<<<LB2, 256, 0, stream>>>(
            deg, start, csr_col, rbf, xin, xbin, xout, xbout,
            wt1 + (size_t)l * 32 * 96,  be1 + (size_t)l * 32,
            wt2 + (size_t)l * 32 * 32,  be2 + (size_t)l * 32,
            wtu1 + (size_t)l * 32 * 64, bu1 + (size_t)l * 32,
            wtu2 + (size_t)l * 32 * 32, bu2 + (size_t)l * 32);
        float* tf = xin; xin = xout; xout = tf;
        unsigned short* tb = xbin; xbin = xbout; xbout = tb;
    }

    final_kernel<<<LB2, 256, 0, stream>>>(xin, u, v, ln_g, ln_b,
                                          wtr1, br1, Wr2, br2,
                                          wts1, bs1, Ws2, bs2, out);
}

// Round 9
// 505.285 us; speedup vs baseline: 1.2047x; 1.0121x over previous
//
#include <hip/hip_runtime.h>
#include <cmath>

namespace {

constexpr int N = 100000;
constexpr int E = 1600000;
constexpr int S = 32;           // hidden
constexpr int L = 5;            // layers
constexpr int NB = (N + 255) / 256;   // node-per-thread kernels
constexpr int NPW = 16;               // nodes per wave in layer kernel
constexpr int LB2 = (N + 63) / 64;    // 1563 blocks (4 waves/block, 16 nodes/wave)
constexpr int NBKT = 391;             // CSR buckets: row>>8, 256 rows each
constexpr int EPB  = E / 256;         // 6250 edges per histogram/scatter block
constexpr float PI_F    = 3.14159265358979323846f;
constexpr float SQRT2_F = 1.41421356237309515f;

typedef __attribute__((ext_vector_type(8))) short short8;   // 8 x bf16
typedef __attribute__((ext_vector_type(4))) float f32x4;

// fast silu: v_rcp_f32 instead of IEEE division (saves ~10 VALU instrs/call)
__device__ __forceinline__ float silu_f(float x) {
    return x * __builtin_amdgcn_rcpf(1.0f + __expf(-x));
}

// float -> bf16 bits, round-to-nearest-even
__device__ __forceinline__ unsigned short f2bf(float f) {
    unsigned int u = __float_as_uint(f);
    u = (u + 0x7FFFu + ((u >> 16) & 1u)) >> 16;
    return (unsigned short)u;
}

__device__ __forceinline__ int rl(int v, int i) {
    return __builtin_amdgcn_readlane(v, i);
}

// 32-bit byte-offset gather of a 16B xb fragment: base + col*64 + quad*16
__device__ __forceinline__ short8 ld_xb(const unsigned short* base, int col, int quad) {
    unsigned off = ((unsigned)col << 6) | ((unsigned)quad << 4);
    return *reinterpret_cast<const short8*>(reinterpret_cast<const char*>(base) + off);
}

// 32-bit byte-offset read of an rbf half-row: base + slot*32 + quad*16
__device__ __forceinline__ short8 ld_rbf(const unsigned short* base, int slot, int quad) {
    unsigned off = ((unsigned)slot << 5) | ((unsigned)quad << 4);
    return *reinterpret_cast<const short8*>(reinterpret_cast<const char*>(base) + off);
}

// advance (i,t) to the next tile of this wave's 16-node batch (uniform)
__device__ __forceinline__ void adv(int& i, int& t, int vd) {
    ++t;
    while (i < 16) {
        int dgi = rl(vd, i);
        int nt = (dgi + 15) >> 4;
        if (t < nt) break;
        t = 0; ++i;
    }
}

// CSR slot for (i,t) at lane row ml; clamped into the node's own range
__device__ __forceinline__ int slotOf(int i, int t, int vs, int vd, int ml) {
    if (i >= 16) return 0;
    int s0 = rl(vs, i);
    int dg = rl(vd, i);
    int smax = s0 + ((dg > 0) ? dg : 1) - 1;
    int s = s0 + t * 16 + ml;
    return min(s, smax);
}

// ---------------------------------------------------------------- passA: bucket histogram
__global__ __launch_bounds__(256) void passA_kernel(
    const int* __restrict__ ei, int* __restrict__ hist)
{
    __shared__ int h[NBKT];
    int t = threadIdx.x;
    int blk = blockIdx.x;
    for (int b = t; b < NBKT; b += 256) h[b] = 0;
    __syncthreads();
    int base = blk * EPB;
    for (int i = t; i < EPB; i += 256) {
        int r = ei[base + i];
        atomicAdd(&h[r >> 8], 1);
    }
    __syncthreads();
    for (int b = t; b < NBKT; b += 256) hist[b * 256 + blk] = h[b];
}

// ---------------------------------------------------------------- p1: bucket totals + exclusive prefix
__global__ __launch_bounds__(512) void p1_kernel(
    const int* __restrict__ hist, int* __restrict__ bstart)
{
    __shared__ int tot[NBKT + 1];
    int t = threadIdx.x;
    if (t < NBKT) {
        int s = 0;
        for (int b = 0; b < 256; ++b) s += hist[t * 256 + b];
        tot[t] = s;
    }
    __syncthreads();
    if (t == 0) {
        int a = 0;
        for (int i = 0; i < NBKT; ++i) { int c = tot[i]; tot[i] = a; a += c; }
        tot[NBKT] = a;   // == E
    }
    __syncthreads();
    if (t <= NBKT) bstart[t] = tot[t];
}

// ---------------------------------------------------------------- p2: per-(bin,blk) scatter bases
__global__ __launch_bounds__(256) void p2_kernel(
    const int* __restrict__ hist, const int* __restrict__ bstart,
    int* __restrict__ base)
{
    __shared__ int pre[256];
    int t = threadIdx.x;
    int bin = blockIdx.x;
    int h = hist[bin * 256 + t];
    pre[t] = h;
    __syncthreads();
    #pragma unroll
    for (int off = 1; off < 256; off <<= 1) {
        int v = (t >= off) ? pre[t - off] : 0;
        __syncthreads();
        pre[t] += v;
        __syncthreads();
    }
    base[bin * 256 + t] = bstart[bin] + pre[t] - h;   // exclusive over blocks
}

// ---------------------------------------------------------------- passB: scatter to bucket staging
__global__ __launch_bounds__(256) void passB_kernel(
    const int* __restrict__ ei, const float* __restrict__ pos,
    const int* __restrict__ base, uint4* __restrict__ edgebuf)
{
    __shared__ int cur[NBKT];
    int t = threadIdx.x;
    int blk = blockIdx.x;
    for (int b = t; b < NBKT; b += 256) cur[b] = base[b * 256 + blk];
    __syncthreads();
    int ebase = blk * EPB;
    for (int i = t; i < EPB; i += 256) {
        int e = ebase + i;
        int r = ei[e];
        int c = ei[E + e];
        float2 pr = reinterpret_cast<const float2*>(pos)[r];
        float2 pc = reinterpret_cast<const float2*>(pos)[c];
        float dx = pr.x - pc.x, dy = pr.y - pc.y;
        float d = sqrtf(dx * dx + dy * dy);   // pos-mean cancels
        int slot = atomicAdd(&cur[r >> 8], 1);   // LDS atomic
        edgebuf[slot] = make_uint4((unsigned)c, __float_as_uint(d), (unsigned)r, 0u);
    }
}

// ---------------------------------------------------------------- passC: per-bucket deg/start/rank + fused rbf
__global__ __launch_bounds__(256) void passC_kernel(
    const uint4* __restrict__ edgebuf, const int* __restrict__ bstart,
    int* __restrict__ deg, int* __restrict__ start,
    int* __restrict__ csr_col, unsigned short* __restrict__ rbf_buf)
{
    __shared__ int cnt[256];
    __shared__ int pre[256];
    __shared__ int cur[256];
    int t = threadIdx.x;
    int bkt = blockIdx.x;
    int s0 = bstart[bkt], s1 = bstart[bkt + 1];

    cnt[t] = 0;
    __syncthreads();
    for (int i = s0 + t; i < s1; i += 256) {
        unsigned r = edgebuf[i].z;
        atomicAdd(&cnt[r & 255], 1);
    }
    __syncthreads();
    int c0 = cnt[t];
    pre[t] = c0;
    __syncthreads();
    #pragma unroll
    for (int off = 1; off < 256; off <<= 1) {
        int v = (t >= off) ? pre[t - off] : 0;
        __syncthreads();
        pre[t] += v;
        __syncthreads();
    }
    int row = bkt * 256 + t;
    int st = s0 + pre[t] - c0;   // exclusive
    if (row < N) {
        deg[row] = c0;
        start[row] = st;
    }
    cur[t] = st;
    __syncthreads();

    for (int i = s0 + t; i < s1; i += 256) {
        uint4 e = edgebuf[i];
        int slot = atomicAdd(&cur[e.z & 255], 1);   // LDS atomic
        csr_col[slot] = (int)e.x;
        float d = __uint_as_float(e.y);

        float sn = __sinf(PI_F * d);
        float c1 = __cosf(PI_F * d);
        float inv = SQRT2_F / (d + 1e-8f);
        float tc = 2.0f * c1;
        float sk = sn, skm = 0.0f;
        unsigned int pk[8];
        #pragma unroll
        for (int k = 0; k < 8; ++k) {
            float r0 = sk * inv;
            float s2 = tc * sk - skm; skm = sk; sk = s2;
            float r1 = sk * inv;
            float s3 = tc * sk - skm; skm = sk; sk = s3;
            pk[k] = (unsigned int)f2bf(r0) | ((unsigned int)f2bf(r1) << 16);
        }
        uint4* out = reinterpret_cast<uint4*>(rbf_buf + (size_t)slot * 16);
        out[0] = make_uint4(pk[0], pk[1], pk[2], pk[3]);
        out[1] = make_uint4(pk[4], pk[5], pk[6], pk[7]);
    }
}

// ---------------------------------------------------------------- bf16 weight prep (transposed [n][k])
__global__ __launch_bounds__(256) void prep_wt_kernel(
    const float* __restrict__ We1, const float* __restrict__ We2,
    const float* __restrict__ Wu1, const float* __restrict__ Wu2,
    const float* __restrict__ Wr1, const float* __restrict__ Ws1,
    short* __restrict__ wt1, short* __restrict__ wt2,
    short* __restrict__ wtu1, short* __restrict__ wtu2,
    short* __restrict__ wtr1, short* __restrict__ wts1)
{
    int idx = blockIdx.x * 256 + threadIdx.x;
    if (idx < 5 * 32 * 96) {
        int l = idx / (32 * 96), r = idx % (32 * 96), n = r / 96, k = r % 96;
        float v = (k < 80) ? We1[((size_t)l * 80 + k) * 32 + n] : 0.0f;
        wt1[idx] = (short)f2bf(v);
    }
    if (idx < 5 * 32 * 32) {
        int l = idx / 1024, r = idx % 1024, n = r / 32, k = r % 32;
        wt2[idx]  = (short)f2bf(We2[((size_t)l * 32 + k) * 32 + n]);
        wtu2[idx] = (short)f2bf(Wu2[((size_t)l * 32 + k) * 32 + n]);
    }
    if (idx < 5 * 32 * 64) {
        int l = idx / 2048, r = idx % 2048, n = r / 64, k = r % 64;
        wtu1[idx] = (short)f2bf(Wu1[((size_t)l * 64 + k) * 32 + n]);
    }
    if (idx < 96 * 32) {
        int n = idx / 32, k = idx % 32;   // head weights [n=96][k=32]
        wtr1[idx] = (short)f2bf(Wr1[k * 96 + n]);
        wts1[idx] = (short)f2bf(Ws1[k * 96 + n]);
    }
}

// ---------------------------------------------------------------- node embed (writes fp32 x + bf16 xb)
__global__ __launch_bounds__(256) void node_embed_kernel(
    const float* __restrict__ u, const float* __restrict__ v,
    const float* __restrict__ bnorm, const float* __restrict__ yf,
    const float* __restrict__ Wn1, const float* __restrict__ bn1,
    const float* __restrict__ Wn2, const float* __restrict__ bn2,
    float* __restrict__ x, unsigned short* __restrict__ xb)
{
    int n = blockIdx.x * 256 + threadIdx.x;
    if (n >= N) return;

    float f[10];
    float4 uu = reinterpret_cast<const float4*>(u)[n];
    f[0] = uu.x; f[1] = uu.y; f[2] = uu.z; f[3] = uu.w;
    float4 v0 = reinterpret_cast<const float4*>(v)[2 * n];
    float4 v1 = reinterpret_cast<const float4*>(v)[2 * n + 1];
    f[4] = sqrtf(v0.x * v0.x + v0.y * v0.y);
    f[5] = sqrtf(v0.z * v0.z + v0.w * v0.w);
    f[6] = sqrtf(v1.x * v1.x + v1.y * v1.y);
    f[7] = sqrtf(v1.z * v1.z + v1.w * v1.w);
    float2 bb = reinterpret_cast<const float2*>(bnorm)[n];
    f[8] = sqrtf(bb.x * bb.x + bb.y * bb.y);
    float2 yy = reinterpret_cast<const float2*>(yf)[n];
    f[9] = sqrtf(yy.x * yy.x + yy.y * yy.y);

    float h[64];
    #pragma unroll
    for (int j = 0; j < 64; ++j) h[j] = bn1[j];
    #pragma unroll
    for (int i = 0; i < 10; ++i) {
        float t = f[i];
        #pragma unroll
        for (int j = 0; j < 64; ++j) h[j] = fmaf(t, Wn1[i * 64 + j], h[j]);
    }
    #pragma unroll
    for (int j = 0; j < 64; ++j) h[j] = silu_f(h[j]);

    float o[32];
    #pragma unroll
    for (int j = 0; j < 32; ++j) o[j] = bn2[j];
    #pragma unroll
    for (int i = 0; i < 64; ++i) {
        float t = h[i];
        #pragma unroll
        for (int j = 0; j < 32; ++j) o[j] = fmaf(t, Wn2[i * 32 + j], o[j]);
    }
    float4* xo = reinterpret_cast<float4*>(x + (size_t)n * 32);
    #pragma unroll
    for (int i = 0; i < 8; ++i)
        xo[i] = make_float4(o[4 * i], o[4 * i + 1], o[4 * i + 2], o[4 * i + 3]);

    unsigned int* xbu = reinterpret_cast<unsigned int*>(xb) + (size_t)n * 16;
    #pragma unroll
    for (int i = 0; i < 16; ++i)
        xbu[i] = (unsigned int)f2bf(o[2 * i]) | ((unsigned int)f2bf(o[2 * i + 1]) << 16);
}

// ---------------------------------------------------------------- fused layer v4
// v3.2 with a 3-set / 2-tile-deep fragment pipeline (3x unrolled, compile-time
// set indices): each xb/rbf gather now has ~2 full tile-computes to land.
__global__ __launch_bounds__(256, 6) void layer_kernel(
    const int* __restrict__ deg, const int* __restrict__ start,
    const int* __restrict__ csr_col, const unsigned short* __restrict__ rbf_buf,
    const float* __restrict__ x_in, const unsigned short* __restrict__ xb_in,
    float* __restrict__ x_out, unsigned short* __restrict__ xb_out,
    const short* __restrict__ wt1, const float* __restrict__ b1,
    const short* __restrict__ wt2, const float* __restrict__ b2,
    const short* __restrict__ wtu1, const float* __restrict__ bu1,
    const short* __restrict__ wtu2, const float* __restrict__ bu2)
{
    __shared__ unsigned short lsh[4][16 * 34];   // sh  (bf16), stride 34
    __shared__ unsigned short agb[4][16 * 34];   // ag  (bf16)
    __shared__ unsigned short hub[4][16 * 34];   // hu  (bf16)
    __shared__ float lrp[4][16 * 33];            // rowpart b1 + x@W1[0:32,:] (fp32)
    __shared__ float ldg[4][16];
    __shared__ float livd[4][16];

    int t = threadIdx.x;
    int w = t >> 6;
    int lane = t & 63;
    int quad = lane >> 4;
    int ml = lane & 15;
    int wid = blockIdx.x * 4 + w;
    int nbase = __builtin_amdgcn_readfirstlane(wid * NPW);
    if (nbase >= N) return;   // N % 16 == 0, so valid waves own full batches

    // ---- batch metadata: lane ml holds node ml's start/deg
    int vs = start[nbase + ml];
    int vd = deg[nbase + ml];

    // ---- edge-phase B fragments (wt1 [32][96])
    const short8* wp = reinterpret_cast<const short8*>(wt1);
    short8 B00 = wp[(ml     ) * 12 + 0 * 4 + quad];
    short8 B01 = wp[(ml     ) * 12 + 1 * 4 + quad];
    short8 B02 = wp[(ml     ) * 12 + 2 * 4 + quad];
    short8 B10 = wp[(ml + 16) * 12 + 0 * 4 + quad];
    short8 B11 = wp[(ml + 16) * 12 + 1 * 4 + quad];
    short8 B12 = wp[(ml + 16) * 12 + 2 * 4 + quad];

    // node-phase / rowpart x A-fragment (A[m=node ml][k=quad*8+j])
    short8 Ax = ld_xb(xb_in, nbase + ml, quad);

    float b1j0 = b1[ml];
    float b1j1 = b1[ml + 16];

    // ---- zero sh, stash deg floats
    unsigned short* lshp = lsh[w];
    for (int k = lane; k < 16 * 34; k += 64) lshp[k] = 0;
    if (lane < 16) {
        ldg[w][lane] = (float)vd;
        livd[w][lane] = 1.0f / fmaxf((float)vd, 1.0f);
    }

    // ---- hoisted row-node partial: rp[m][j] = b1[j] + x[m] @ W1[0:32, j]
    float* rpp = lrp[w];
    {
        f32x4 rp0 = {b1j0, b1j0, b1j0, b1j0};
        f32x4 rp1 = {b1j1, b1j1, b1j1, b1j1};
        rp0 = __builtin_amdgcn_mfma_f32_16x16x32_bf16(Ax, B00, rp0, 0, 0, 0);
        rp1 = __builtin_amdgcn_mfma_f32_16x16x32_bf16(Ax, B10, rp1, 0, 0, 0);
        int row = quad * 4;
        #pragma unroll
        for (int r = 0; r < 4; ++r) {
            rpp[(row + r) * 33 + ml]      = rp0[r];
            rpp[(row + r) * 33 + ml + 16] = rp1[r];
        }
    }
    __builtin_amdgcn_wave_barrier();

    // ---- edge loop: 5-deep index queue (A..E), 3 fragment sets, 2-deep col queue
    const short8 Z8 = {0, 0, 0, 0, 0, 0, 0, 0};
    int iA = 0, tA = -1; adv(iA, tA, vd);
    int iB = iA, tB = tA; adv(iB, tB, vd);
    int iC = iB, tC = tB; adv(iC, tC, vd);
    int iD = iC, tD = tC; adv(iD, tD, vd);
    int iE = iD, tE = tD; adv(iE, tE, vd);

    int slot0 = slotOf(iA, tA, vs, vd, ml);
    int slot1 = slotOf(iB, tB, vs, vd, ml);
    int slot2 = slotOf(iC, tC, vs, vd, ml);
    int slotQ = slotOf(iD, tD, vs, vd, ml);
    int col0 = csr_col[slot0];
    int col1 = csr_col[slot1];
    int col2 = csr_col[slot2];
    int colQ = csr_col[slotQ];

    short8 F1_0 = ld_xb(xb_in, col0, quad);
    short8 F2_0 = (quad < 2) ? ld_rbf(rbf_buf, slot0, quad) : Z8;
    short8 F1_1 = ld_xb(xb_in, col1, quad);
    short8 F2_1 = (quad < 2) ? ld_rbf(rbf_buf, slot1, quad) : Z8;
    short8 F1_2 = ld_xb(xb_in, col2, quad);
    short8 F2_2 = (quad < 2) ? ld_rbf(rbf_buf, slot2, quad) : Z8;

    float colp0 = 0.0f, colp1 = 0.0f;

    // compute tile at queue head from fragment set (A1,A2)
    auto tile = [&](const short8& A1, const short8& A2) {
        float rpa = rpp[iA * 33 + ml];
        float rpb = rpp[iA * 33 + ml + 16];
        f32x4 acc0 = {rpa, rpa, rpa, rpa};
        f32x4 acc1 = {rpb, rpb, rpb, rpb};
        acc0 = __builtin_amdgcn_mfma_f32_16x16x32_bf16(A1, B01, acc0, 0, 0, 0);
        acc0 = __builtin_amdgcn_mfma_f32_16x16x32_bf16(A2, B02, acc0, 0, 0, 0);
        acc1 = __builtin_amdgcn_mfma_f32_16x16x32_bf16(A1, B11, acc1, 0, 0, 0);
        acc1 = __builtin_amdgcn_mfma_f32_16x16x32_bf16(A2, B12, acc1, 0, 0, 0);

        int dg0 = rl(vd, iA);
        int rowbase = tA * 16 + quad * 4;
        #pragma unroll
        for (int r = 0; r < 4; ++r) {
            bool vld = (rowbase + r) < dg0;
            colp0 += vld ? silu_f(acc0[r]) : 0.0f;
            colp1 += vld ? silu_f(acc1[r]) : 0.0f;
        }
        if (tA == ((dg0 + 15) >> 4) - 1) {   // last tile of node iA (uniform)
            colp0 += __shfl_xor(colp0, 16, 64);
            colp0 += __shfl_xor(colp0, 32, 64);
            colp1 += __shfl_xor(colp1, 16, 64);
            colp1 += __shfl_xor(colp1, 32, 64);
            if (quad == 0) {
                lshp[iA * 34 + ml]      = f2bf(colp0);
                lshp[iA * 34 + ml + 16] = f2bf(colp1);
            }
            colp0 = 0.0f; colp1 = 0.0f;
        }
    };
    auto shiftq = [&]() {
        iA = iB; tA = tB; iB = iC; tB = tC;
        iC = iD; tC = tD; iD = iE; tD = tE;
        adv(iE, tE, vd);
    };

    // STEP k (set s): prefetch col(k+4); compute tile k; refill set s with
    // frags(k+3) via colQ/slotQ (queued at step k-1); shift.
    #define EDGE_STEP(F1s, F2s)                                     \
    {                                                               \
        int slotE_ = slotOf(iE, tE, vs, vd, ml);                    \
        int colE_  = csr_col[slotE_];                               \
        tile(F1s, F2s);                                             \
        F1s = ld_xb(xb_in, colQ, quad);                             \
        F2s = (quad < 2) ? ld_rbf(rbf_buf, slotQ, quad) : Z8;       \
        shiftq();                                                   \
        colQ = colE_; slotQ = slotE_;                               \
    }

    while (iA < 16) {
        EDGE_STEP(F1_0, F2_0);
        if (iA >= 16) break;
        EDGE_STEP(F1_1, F2_1);
        if (iA >= 16) break;
        EDGE_STEP(F1_2, F2_2);
    }
    #undef EDGE_STEP
    __builtin_amdgcn_wave_barrier();

    // ---- node phase: 16-node batch, 8 MFMAs
    const short8* w2p = reinterpret_cast<const short8*>(wt2);
    short8 Bw2_0 = w2p[(ml     ) * 4 + quad];
    short8 Bw2_1 = w2p[(ml + 16) * 4 + quad];
    const short8* u1p = reinterpret_cast<const short8*>(wtu1);
    short8 Bu1_00 = u1p[(ml     ) * 8 + quad];       // k 0..31 (x)
    short8 Bu1_10 = u1p[(ml     ) * 8 + 4 + quad];   // k 32..63 (ag)
    short8 Bu1_01 = u1p[(ml + 16) * 8 + quad];
    short8 Bu1_11 = u1p[(ml + 16) * 8 + 4 + quad];
    const short8* u2p = reinterpret_cast<const short8*>(wtu2);
    short8 Bu2_0 = u2p[(ml     ) * 4 + quad];
    short8 Bu2_1 = u2p[(ml + 16) * 4 + quad];

    // sh @ W2
    short8 Ash = *reinterpret_cast<const short8*>(lshp + ml * 34 + quad * 8);
    f32x4 c0 = {0.0f, 0.0f, 0.0f, 0.0f};
    f32x4 c1 = {0.0f, 0.0f, 0.0f, 0.0f};
    c0 = __builtin_amdgcn_mfma_f32_16x16x32_bf16(Ash, Bw2_0, c0, 0, 0, 0);
    c1 = __builtin_amdgcn_mfma_f32_16x16x32_bf16(Ash, Bw2_1, c1, 0, 0, 0);
    float b2c0 = b2[ml], b2c1 = b2[ml + 16];
    unsigned short* agp = agb[w];
    int row = quad * 4;
    #pragma unroll
    for (int r = 0; r < 4; ++r) {
        float fd = ldg[w][row + r];
        float iv = livd[w][row + r];
        agp[(row + r) * 34 + ml]      = f2bf((c0[r] + fd * b2c0) * iv);
        agp[(row + r) * 34 + ml + 16] = f2bf((c1[r] + fd * b2c1) * iv);
    }
    __builtin_amdgcn_wave_barrier();

    // [x ; ag] @ Wu1
    short8 Aag = *reinterpret_cast<const short8*>(agp + ml * 34 + quad * 8);
    f32x4 d0 = {0.0f, 0.0f, 0.0f, 0.0f};
    f32x4 d1 = {0.0f, 0.0f, 0.0f, 0.0f};
    d0 = __builtin_amdgcn_mfma_f32_16x16x32_bf16(Ax,  Bu1_00, d0, 0, 0, 0);
    d0 = __builtin_amdgcn_mfma_f32_16x16x32_bf16(Aag, Bu1_10, d0, 0, 0, 0);
    d1 = __builtin_amdgcn_mfma_f32_16x16x32_bf16(Ax,  Bu1_01, d1, 0, 0, 0);
    d1 = __builtin_amdgcn_mfma_f32_16x16x32_bf16(Aag, Bu1_11, d1, 0, 0, 0);
    float bu1c0 = bu1[ml], bu1c1 = bu1[ml + 16];
    unsigned short* hup = hub[w];
    #pragma unroll
    for (int r = 0; r < 4; ++r) {
        hup[(row + r) * 34 + ml]      = f2bf(silu_f(d0[r] + bu1c0));
        hup[(row + r) * 34 + ml + 16] = f2bf(silu_f(d1[r] + bu1c1));
    }
    __builtin_amdgcn_wave_barrier();

    // hu @ Wu2 ; residual (x_in re-read, coalesced + L2-hot) + store
    short8 Ahu = *reinterpret_cast<const short8*>(hup + ml * 34 + quad * 8);
    float xr0[4], xr1[4];
    #pragma unroll
    for (int r = 0; r < 4; ++r) {
        int nn = nbase + row + r;
        xr0[r] = x_in[(size_t)nn * 32 + ml];
        xr1[r] = x_in[(size_t)nn * 32 + ml + 16];
    }
    f32x4 e0 = {0.0f, 0.0f, 0.0f, 0.0f};
    f32x4 e1 = {0.0f, 0.0f, 0.0f, 0.0f};
    e0 = __builtin_amdgcn_mfma_f32_16x16x32_bf16(Ahu, Bu2_0, e0, 0, 0, 0);
    e1 = __builtin_amdgcn_mfma_f32_16x16x32_bf16(Ahu, Bu2_1, e1, 0, 0, 0);
    float bu2c0 = bu2[ml], bu2c1 = bu2[ml + 16];
    #pragma unroll
    for (int r = 0; r < 4; ++r) {
        int nn = nbase + row + r;
        float o0 = e0[r] + bu2c0 + xr0[r];
        float o1 = e1[r] + bu2c1 + xr1[r];
        x_out[(size_t)nn * 32 + ml]      = o0;
        x_out[(size_t)nn * 32 + ml + 16] = o1;
        xb_out[(size_t)nn * 32 + ml]      = f2bf(o0);
        xb_out[(size_t)nn * 32 + ml + 16] = f2bf(o1);
    }
}

// ---------------------------------------------------------------- LN + heads, MFMA version
__global__ __launch_bounds__(256) void final_kernel(
    const float* __restrict__ x, const float* __restrict__ u,
    const float* __restrict__ v,
    const float* __restrict__ ln_g, const float* __restrict__ ln_b,
    const short* __restrict__ wtr1, const float* __restrict__ br1,
    const float* __restrict__ Wr2, const float* __restrict__ br2,
    const short* __restrict__ wts1, const float* __restrict__ bs1,
    const float* __restrict__ Ws2, const float* __restrict__ bs2,
    float* __restrict__ out)
{
    int t = threadIdx.x;
    int w = t >> 6;
    int lane = t & 63;
    int quad = lane >> 4;
    int ml = lane & 15;
    int wid = blockIdx.x * 4 + w;
    int nbase = __builtin_amdgcn_readfirstlane(wid * NPW);
    if (nbase >= N) return;

    // lane (quad,ml) holds x[nbase+ml][quad*8 .. quad*8+7]
    const float4* xs = reinterpret_cast<const float4*>(
        x + (size_t)(nbase + ml) * 32 + quad * 8);
    float4 xa = xs[0], xb4 = xs[1];
    float f[8] = {xa.x, xa.y, xa.z, xa.w, xb4.x, xb4.y, xb4.z, xb4.w};

    // LN statistics for node ml: reduce over k (across the 4 quads)
    float s = 0.0f, ss = 0.0f;
    #pragma unroll
    for (int i = 0; i < 8; ++i) { s += f[i]; ss += f[i] * f[i]; }
    s  += __shfl_xor(s, 16, 64);  s  += __shfl_xor(s, 32, 64);
    ss += __shfl_xor(ss, 16, 64); ss += __shfl_xor(ss, 32, 64);
    float mu = s * (1.0f / 32.0f);
    float var = ss * (1.0f / 32.0f) - mu * mu;
    float rs = rsqrtf(var + 1e-5f);

    // LN affine + bf16 A fragment (A[m=ml][k=quad*8+j])
    const float4* gp = reinterpret_cast<const float4*>(ln_g + quad * 8);
    const float4* bp = reinterpret_cast<const float4*>(ln_b + quad * 8);
    float4 g0 = gp[0], g1 = gp[1], bb0 = bp[0], bb1 = bp[1];
    float gg[8] = {g0.x, g0.y, g0.z, g0.w, g1.x, g1.y, g1.z, g1.w};
    float bb[8] = {bb0.x, bb0.y, bb0.z, bb0.w, bb1.x, bb1.y, bb1.z, bb1.w};
    short8 A;
    #pragma unroll
    for (int i = 0; i < 8; ++i)
        A[i] = (short)f2bf((f[i] - mu) * rs * gg[i] + bb[i]);

    // head layer 1: 6 MFMAs per head (output tiles n = ml + 16*h)
    const short8* r1p = reinterpret_cast<const short8*>(wtr1);
    const short8* s1p = reinterpret_cast<const short8*>(wts1);
    const f32x4 Zf = {0.0f, 0.0f, 0.0f, 0.0f};
    f32x4 hr[6], hs[6];
    #pragma unroll
    for (int h = 0; h < 6; ++h) {
        hr[h] = __builtin_amdgcn_mfma_f32_16x16x32_bf16(A, r1p[(ml + 16 * h) * 4 + quad], Zf, 0, 0, 0);
        hs[h] = __builtin_amdgcn_mfma_f32_16x16x32_bf16(A, s1p[(ml + 16 * h) * 4 + quad], Zf, 0, 0, 0);
    }

    // per-lane second-layer weights for features j = ml + 16*h
    float wr2a[6], wr2b[6], ws2v[6], br1v[6], bs1v[6];
    #pragma unroll
    for (int h = 0; h < 6; ++h) {
        int j = ml + 16 * h;
        float2 wr = reinterpret_cast<const float2*>(Wr2)[j];
        wr2a[h] = wr.x; wr2b[h] = wr.y;
        ws2v[h] = Ws2[j];
        br1v[h] = br1[j];
        bs1v[h] = bs1[j];
    }

    // silu + second layer; lane holds D rows m = quad*4+r, col n = ml+16h.
    float o0[4], o1[4], o2[4];
    #pragma unroll
    for (int r = 0; r < 4; ++r) {
        float p0 = 0.0f, p1 = 0.0f, p2 = 0.0f;
        #pragma unroll
        for (int h = 0; h < 6; ++h) {
            float a1 = silu_f(hr[h][r] + br1v[h]);
            float a2 = silu_f(hs[h][r] + bs1v[h]);
            p0 = fmaf(a1, wr2a[h], p0);
            p1 = fmaf(a1, wr2b[h], p1);
            p2 = fmaf(a2, ws2v[h], p2);
        }
        p0 += __shfl_xor(p0, 1, 64); p0 += __shfl_xor(p0, 2, 64);
        p0 += __shfl_xor(p0, 4, 64); p0 += __shfl_xor(p0, 8, 64);
        p1 += __shfl_xor(p1, 1, 64); p1 += __shfl_xor(p1, 2, 64);
        p1 += __shfl_xor(p1, 4, 64); p1 += __shfl_xor(p1, 8, 64);
        p2 += __shfl_xor(p2, 1, 64); p2 += __shfl_xor(p2, 2, 64);
        p2 += __shfl_xor(p2, 4, 64); p2 += __shfl_xor(p2, 8, 64);
        o0[r] = p0; o1[r] = p1; o2[r] = p2;
    }

    if (ml == 0) {
        float b20 = br2[0], b21 = br2[1], b22 = bs2[0];
        #pragma unroll
        for (int r = 0; r < 4; ++r) {
            int n = nbase + quad * 4 + r;
            out[n] = u[n * 4 + 3] + o2[r] + b22;
            out[N + 2 * n]     = o0[r] + b20 + v[n * 8 + 6];
            out[N + 2 * n + 1] = o1[r] + b21 + v[n * 8 + 7];
        }
    }
}

} // anonymous namespace

extern "C" void kernel_launch(void* const* d_in, const int* in_sizes, int n_in,
                              void* d_out, int out_size, void* d_ws, size_t ws_size,
                              hipStream_t stream)
{
    const float* u    = (const float*)d_in[0];
    const float* v    = (const float*)d_in[1];
    const float* bno  = (const float*)d_in[2];
    const float* yf   = (const float*)d_in[4];
    const float* pos  = (const float*)d_in[5];
    const int*   ei   = (const int*)d_in[6];
    const float* Wn1  = (const float*)d_in[7];
    const float* bn1  = (const float*)d_in[8];
    const float* Wn2  = (const float*)d_in[9];
    const float* bn2  = (const float*)d_in[10];
    const float* We1  = (const float*)d_in[11];
    const float* be1  = (const float*)d_in[12];
    const float* We2  = (const float*)d_in[13];
    const float* be2  = (const float*)d_in[14];
    const float* Wu1  = (const float*)d_in[15];
    const float* bu1  = (const float*)d_in[16];
    const float* Wu2  = (const float*)d_in[17];
    const float* bu2  = (const float*)d_in[18];
    const float* ln_g = (const float*)d_in[19];
    const float* ln_b = (const float*)d_in[20];
    const float* Wr1  = (const float*)d_in[21];
    const float* br1  = (const float*)d_in[22];
    const float* Wr2  = (const float*)d_in[23];
    const float* br2  = (const float*)d_in[24];
    const float* Ws1  = (const float*)d_in[25];
    const float* bs1  = (const float*)d_in[26];
    const float* Ws2  = (const float*)d_in[27];
    const float* bs2  = (const float*)d_in[28];
    float* out = (float*)d_out;

    // workspace layout (16B-aligned sections)
    int*   deg      = (int*)d_ws;                            // N
    int*   start    = deg + N;                               // N
    int*   bstart   = start + N;                             // NBKT+1
    int*   csr_col  = bstart + 512;                          // E ints
    unsigned short* rbf = (unsigned short*)(csr_col + E);    // E*16 bf16 (51.2 MB)
    float* x0       = (float*)(rbf + (size_t)E * 16);        // N*32 f32
    float* x1       = x0 + (size_t)N * S;                    // N*32 f32
    unsigned short* xb0 = (unsigned short*)(x1 + (size_t)N * S);   // N*32 bf16
    unsigned short* xb1 = xb0 + (size_t)N * S;               // N*32 bf16
    short* wt1      = (short*)(xb1 + (size_t)N * S);         // 5*32*96
    short* wt2      = wt1 + 5 * 32 * 96;                     // 5*32*32
    short* wtu1     = wt2 + 5 * 32 * 32;                     // 5*32*64
    short* wtu2     = wtu1 + 5 * 32 * 64;                    // 5*32*32
    short* wtr1     = wtu2 + 5 * 32 * 32;                    // 96*32 (head r, [n][k])
    short* wts1     = wtr1 + 96 * 32;                        // 96*32 (head s, [n][k])
    int*   hist     = (int*)(wts1 + 96 * 32);                // NBKT*256
    int*   basem    = hist + NBKT * 256;                     // NBKT*256

    // transient alias (dead before node_embed writes x0 / layer writes x1):
    //   edgebuf: E*16B bucket-ordered {col, dist, row} == x0..xb0 (E*16 == N*32*4*2)
    uint4* edgebuf = (uint4*)x0;

    passA_kernel<<<256, 256, 0, stream>>>(ei, hist);
    p1_kernel<<<1, 512, 0, stream>>>(hist, bstart);
    p2_kernel<<<NBKT, 256, 0, stream>>>(hist, bstart, basem);
    passB_kernel<<<256, 256, 0, stream>>>(ei, pos, basem, edgebuf);
    passC_kernel<<<NBKT, 256, 0, stream>>>(edgebuf, bstart, deg, start, csr_col, rbf);
    prep_wt_kernel<<<60, 256, 0, stream>>>(We1, We2, Wu1, Wu2, Wr1, Ws1,
                                           wt1, wt2, wtu1, wtu2, wtr1, wts1);

    node_embed_kernel<<<NB, 256, 0, stream>>>(u, v, bno, yf, Wn1, bn1, Wn2, bn2,
                                              x0, xb0);

    float* xin = x0;  float* xout = x1;
    unsigned short* xbin = xb0;  unsigned short* xbout = xb1;
    for (int l = 0; l < L; ++l) {
        layer_kernel<<<LB2, 256, 0, stream>>>(
            deg, start, csr_col, rbf, xin, xbin, xout, xbout,
            wt1 + (size_t)l * 32 * 96,  be1 + (size_t)l * 32,
            wt2 + (size_t)l * 32 * 32,  be2 + (size_t)l * 32,
            wtu1 + (size_t)l * 32 * 64, bu1 + (size_t)l * 32,
            wtu2 + (size_t)l * 32 * 32, bu2 + (size_t)l * 32);
        float* tf = xin; xin = xout; xout = tf;
        unsigned short* tb = xbin; xbin = xbout; xbout = tb;
    }

    final_kernel<<<LB2, 256, 0, stream>>>(xin, u, v, ln_g, ln_b,
                                          wtr1, br1, Wr2, br2,
                                          wts1, bs1, Ws2, bs2, out);
}

// Round 10
// 503.101 us; speedup vs baseline: 1.2099x; 1.0043x over previous
//
#include <hip/hip_runtime.h>
#include <cmath>

namespace {

constexpr int N = 100000;
constexpr int E = 1600000;
constexpr int S = 32;           // hidden
constexpr int L = 5;            // layers
constexpr int NB = (N + 255) / 256;   // node-per-thread kernels
constexpr int NPW = 16;               // nodes per wave in layer kernel
constexpr int LB2 = (N + 63) / 64;    // 1563 blocks (4 waves/block, 16 nodes/wave)
constexpr int NBKT = 391;             // CSR buckets: row>>8, 256 rows each
constexpr int EPB  = E / 256;         // 6250 edges per histogram/scatter block
constexpr float PI_F    = 3.14159265358979323846f;
constexpr float SQRT2_F = 1.41421356237309515f;

typedef __attribute__((ext_vector_type(8))) short short8;   // 8 x bf16
typedef __attribute__((ext_vector_type(4))) float f32x4;

// fast silu: v_rcp_f32 instead of IEEE division (saves ~10 VALU instrs/call)
__device__ __forceinline__ float silu_f(float x) {
    return x * __builtin_amdgcn_rcpf(1.0f + __expf(-x));
}

// float -> bf16 bits, round-to-nearest-even
__device__ __forceinline__ unsigned short f2bf(float f) {
    unsigned int u = __float_as_uint(f);
    u = (u + 0x7FFFu + ((u >> 16) & 1u)) >> 16;
    return (unsigned short)u;
}

__device__ __forceinline__ int rl(int v, int i) {
    return __builtin_amdgcn_readlane(v, i);
}

// 32-bit byte-offset gather of a 16B xb fragment: base + col*64 + quad*16
__device__ __forceinline__ short8 ld_xb(const unsigned short* base, int col, int quad) {
    unsigned off = ((unsigned)col << 6) | ((unsigned)quad << 4);
    return *reinterpret_cast<const short8*>(reinterpret_cast<const char*>(base) + off);
}

// 32-bit byte-offset read of an rbf half-row: base + slot*32 + quad*16
__device__ __forceinline__ short8 ld_rbf(const unsigned short* base, int slot, int quad) {
    unsigned off = ((unsigned)slot << 5) | ((unsigned)quad << 4);
    return *reinterpret_cast<const short8*>(reinterpret_cast<const char*>(base) + off);
}

// advance (i,t) to the next tile of this wave's 16-node batch (uniform)
__device__ __forceinline__ void adv(int& i, int& t, int vd) {
    ++t;
    while (i < 16) {
        int dgi = rl(vd, i);
        int nt = (dgi + 15) >> 4;
        if (t < nt) break;
        t = 0; ++i;
    }
}

// CSR slot for (i,t) at lane row ml; clamped into the node's own range
__device__ __forceinline__ int slotOf(int i, int t, int vs, int vd, int ml) {
    if (i >= 16) return 0;
    int s0 = rl(vs, i);
    int dg = rl(vd, i);
    int smax = s0 + ((dg > 0) ? dg : 1) - 1;
    int s = s0 + t * 16 + ml;
    return min(s, smax);
}

// ---------------------------------------------------------------- passA: bucket histogram
__global__ __launch_bounds__(256) void passA_kernel(
    const int* __restrict__ ei, int* __restrict__ hist)
{
    __shared__ int h[NBKT];
    int t = threadIdx.x;
    int blk = blockIdx.x;
    for (int b = t; b < NBKT; b += 256) h[b] = 0;
    __syncthreads();
    int base = blk * EPB;
    for (int i = t; i < EPB; i += 256) {
        int r = ei[base + i];
        atomicAdd(&h[r >> 8], 1);
    }
    __syncthreads();
    for (int b = t; b < NBKT; b += 256) hist[b * 256 + blk] = h[b];
}

// ---------------------------------------------------------------- p1: bucket totals + exclusive prefix
__global__ __launch_bounds__(512) void p1_kernel(
    const int* __restrict__ hist, int* __restrict__ bstart)
{
    __shared__ int tot[NBKT + 1];
    int t = threadIdx.x;
    if (t < NBKT) {
        int s = 0;
        for (int b = 0; b < 256; ++b) s += hist[t * 256 + b];
        tot[t] = s;
    }
    __syncthreads();
    if (t == 0) {
        int a = 0;
        for (int i = 0; i < NBKT; ++i) { int c = tot[i]; tot[i] = a; a += c; }
        tot[NBKT] = a;   // == E
    }
    __syncthreads();
    if (t <= NBKT) bstart[t] = tot[t];
}

// ---------------------------------------------------------------- p2: per-(bin,blk) scatter bases
__global__ __launch_bounds__(256) void p2_kernel(
    const int* __restrict__ hist, const int* __restrict__ bstart,
    int* __restrict__ base)
{
    __shared__ int pre[256];
    int t = threadIdx.x;
    int bin = blockIdx.x;
    int h = hist[bin * 256 + t];
    pre[t] = h;
    __syncthreads();
    #pragma unroll
    for (int off = 1; off < 256; off <<= 1) {
        int v = (t >= off) ? pre[t - off] : 0;
        __syncthreads();
        pre[t] += v;
        __syncthreads();
    }
    base[bin * 256 + t] = bstart[bin] + pre[t] - h;   // exclusive over blocks
}

// ---------------------------------------------------------------- passB: scatter to bucket staging
__global__ __launch_bounds__(256) void passB_kernel(
    const int* __restrict__ ei, const float* __restrict__ pos,
    const int* __restrict__ base, uint4* __restrict__ edgebuf)
{
    __shared__ int cur[NBKT];
    int t = threadIdx.x;
    int blk = blockIdx.x;
    for (int b = t; b < NBKT; b += 256) cur[b] = base[b * 256 + blk];
    __syncthreads();
    int ebase = blk * EPB;
    for (int i = t; i < EPB; i += 256) {
        int e = ebase + i;
        int r = ei[e];
        int c = ei[E + e];
        float2 pr = reinterpret_cast<const float2*>(pos)[r];
        float2 pc = reinterpret_cast<const float2*>(pos)[c];
        float dx = pr.x - pc.x, dy = pr.y - pc.y;
        float d = sqrtf(dx * dx + dy * dy);   // pos-mean cancels
        int slot = atomicAdd(&cur[r >> 8], 1);   // LDS atomic
        edgebuf[slot] = make_uint4((unsigned)c, __float_as_uint(d), (unsigned)r, 0u);
    }
}

// ---------------------------------------------------------------- passC: per-bucket deg/start/rank + fused rbf
__global__ __launch_bounds__(256) void passC_kernel(
    const uint4* __restrict__ edgebuf, const int* __restrict__ bstart,
    int* __restrict__ deg, int* __restrict__ start,
    int* __restrict__ csr_col, unsigned short* __restrict__ rbf_buf)
{
    __shared__ int cnt[256];
    __shared__ int pre[256];
    __shared__ int cur[256];
    int t = threadIdx.x;
    int bkt = blockIdx.x;
    int s0 = bstart[bkt], s1 = bstart[bkt + 1];

    cnt[t] = 0;
    __syncthreads();
    for (int i = s0 + t; i < s1; i += 256) {
        unsigned r = edgebuf[i].z;
        atomicAdd(&cnt[r & 255], 1);
    }
    __syncthreads();
    int c0 = cnt[t];
    pre[t] = c0;
    __syncthreads();
    #pragma unroll
    for (int off = 1; off < 256; off <<= 1) {
        int v = (t >= off) ? pre[t - off] : 0;
        __syncthreads();
        pre[t] += v;
        __syncthreads();
    }
    int row = bkt * 256 + t;
    int st = s0 + pre[t] - c0;   // exclusive
    if (row < N) {
        deg[row] = c0;
        start[row] = st;
    }
    cur[t] = st;
    __syncthreads();

    for (int i = s0 + t; i < s1; i += 256) {
        uint4 e = edgebuf[i];
        int slot = atomicAdd(&cur[e.z & 255], 1);   // LDS atomic
        csr_col[slot] = (int)e.x;
        float d = __uint_as_float(e.y);

        float sn = __sinf(PI_F * d);
        float c1 = __cosf(PI_F * d);
        float inv = SQRT2_F / (d + 1e-8f);
        float tc = 2.0f * c1;
        float sk = sn, skm = 0.0f;
        unsigned int pk[8];
        #pragma unroll
        for (int k = 0; k < 8; ++k) {
            float r0 = sk * inv;
            float s2 = tc * sk - skm; skm = sk; sk = s2;
            float r1 = sk * inv;
            float s3 = tc * sk - skm; skm = sk; sk = s3;
            pk[k] = (unsigned int)f2bf(r0) | ((unsigned int)f2bf(r1) << 16);
        }
        uint4* out = reinterpret_cast<uint4*>(rbf_buf + (size_t)slot * 16);
        out[0] = make_uint4(pk[0], pk[1], pk[2], pk[3]);
        out[1] = make_uint4(pk[4], pk[5], pk[6], pk[7]);
    }
}

// ---------------------------------------------------------------- bf16 weight prep (transposed [n][k])
__global__ __launch_bounds__(256) void prep_wt_kernel(
    const float* __restrict__ We1, const float* __restrict__ We2,
    const float* __restrict__ Wu1, const float* __restrict__ Wu2,
    const float* __restrict__ Wr1, const float* __restrict__ Ws1,
    short* __restrict__ wt1, short* __restrict__ wt2,
    short* __restrict__ wtu1, short* __restrict__ wtu2,
    short* __restrict__ wtr1, short* __restrict__ wts1)
{
    int idx = blockIdx.x * 256 + threadIdx.x;
    if (idx < 5 * 32 * 96) {
        int l = idx / (32 * 96), r = idx % (32 * 96), n = r / 96, k = r % 96;
        float v = (k < 80) ? We1[((size_t)l * 80 + k) * 32 + n] : 0.0f;
        wt1[idx] = (short)f2bf(v);
    }
    if (idx < 5 * 32 * 32) {
        int l = idx / 1024, r = idx % 1024, n = r / 32, k = r % 32;
        wt2[idx]  = (short)f2bf(We2[((size_t)l * 32 + k) * 32 + n]);
        wtu2[idx] = (short)f2bf(Wu2[((size_t)l * 32 + k) * 32 + n]);
    }
    if (idx < 5 * 32 * 64) {
        int l = idx / 2048, r = idx % 2048, n = r / 64, k = r % 64;
        wtu1[idx] = (short)f2bf(Wu1[((size_t)l * 64 + k) * 32 + n]);
    }
    if (idx < 96 * 32) {
        int n = idx / 32, k = idx % 32;   // head weights [n=96][k=32]
        wtr1[idx] = (short)f2bf(Wr1[k * 96 + n]);
        wts1[idx] = (short)f2bf(Ws1[k * 96 + n]);
    }
}

// ---------------------------------------------------------------- node embed v2: 4 threads/node
// f32-exact restructure of the node-embed MLP. Old version: 1 thread/node, 391
// blocks, 14.5% occupancy, serialized uniform s_loads => 55us latency-bound.
// Now: thread (node, p) computes h[p*16..+15] (layer 1), stages h in LDS,
// then o[p*8..+7] (layer 2). 1563 blocks, vector weight loads, coalesced stores.
__global__ __launch_bounds__(256) void node_embed_kernel(
    const float* __restrict__ u, const float* __restrict__ v,
    const float* __restrict__ bnorm, const float* __restrict__ yf,
    const float* __restrict__ Wn1, const float* __restrict__ bn1,
    const float* __restrict__ Wn2, const float* __restrict__ bn2,
    float* __restrict__ x, unsigned short* __restrict__ xb)
{
    __shared__ float hsh[64][68];
    int t = threadIdx.x;
    int nl = t >> 2;          // node within block (0..63)
    int p  = t & 3;           // part (0..3)
    int n  = blockIdx.x * 64 + nl;
    bool valid = (n < N);
    int nc = valid ? n : (N - 1);   // clamp loads for tail block

    // ---- invariant feats (each of the 4 threads computes its node's 10 feats;
    //      redundant x4 but L1-broadcast, negligible)
    float f[10];
    float4 uu = reinterpret_cast<const float4*>(u)[nc];
    f[0] = uu.x; f[1] = uu.y; f[2] = uu.z; f[3] = uu.w;
    float4 v0 = reinterpret_cast<const float4*>(v)[2 * nc];
    float4 v1 = reinterpret_cast<const float4*>(v)[2 * nc + 1];
    f[4] = sqrtf(v0.x * v0.x + v0.y * v0.y);
    f[5] = sqrtf(v0.z * v0.z + v0.w * v0.w);
    f[6] = sqrtf(v1.x * v1.x + v1.y * v1.y);
    f[7] = sqrtf(v1.z * v1.z + v1.w * v1.w);
    float2 bb = reinterpret_cast<const float2*>(bnorm)[nc];
    f[8] = sqrtf(bb.x * bb.x + bb.y * bb.y);
    float2 yy = reinterpret_cast<const float2*>(yf)[nc];
    f[9] = sqrtf(yy.x * yy.x + yy.y * yy.y);

    // ---- layer 1: h[j], j = p*16 + jj
    float h[16];
    {
        const float4* b4 = reinterpret_cast<const float4*>(bn1 + p * 16);
        float4 b0 = b4[0], b1 = b4[1], b2 = b4[2], b3 = b4[3];
        h[0]=b0.x; h[1]=b0.y; h[2]=b0.z; h[3]=b0.w;
        h[4]=b1.x; h[5]=b1.y; h[6]=b1.z; h[7]=b1.w;
        h[8]=b2.x; h[9]=b2.y; h[10]=b2.z; h[11]=b2.w;
        h[12]=b3.x; h[13]=b3.y; h[14]=b3.z; h[15]=b3.w;
    }
    #pragma unroll
    for (int i = 0; i < 10; ++i) {
        float ff = f[i];
        const float4* wr = reinterpret_cast<const float4*>(Wn1 + i * 64 + p * 16);
        float4 w0 = wr[0], w1 = wr[1], w2 = wr[2], w3 = wr[3];
        h[0]  = fmaf(ff, w0.x, h[0]);  h[1]  = fmaf(ff, w0.y, h[1]);
        h[2]  = fmaf(ff, w0.z, h[2]);  h[3]  = fmaf(ff, w0.w, h[3]);
        h[4]  = fmaf(ff, w1.x, h[4]);  h[5]  = fmaf(ff, w1.y, h[5]);
        h[6]  = fmaf(ff, w1.z, h[6]);  h[7]  = fmaf(ff, w1.w, h[7]);
        h[8]  = fmaf(ff, w2.x, h[8]);  h[9]  = fmaf(ff, w2.y, h[9]);
        h[10] = fmaf(ff, w2.z, h[10]); h[11] = fmaf(ff, w2.w, h[11]);
        h[12] = fmaf(ff, w3.x, h[12]); h[13] = fmaf(ff, w3.y, h[13]);
        h[14] = fmaf(ff, w3.z, h[14]); h[15] = fmaf(ff, w3.w, h[15]);
    }
    #pragma unroll
    for (int jj = 0; jj < 16; ++jj) h[jj] = silu_f(h[jj]);

    float4* hrow = reinterpret_cast<float4*>(&hsh[nl][p * 16]);
    hrow[0] = make_float4(h[0], h[1], h[2], h[3]);
    hrow[1] = make_float4(h[4], h[5], h[6], h[7]);
    hrow[2] = make_float4(h[8], h[9], h[10], h[11]);
    hrow[3] = make_float4(h[12], h[13], h[14], h[15]);
    __syncthreads();

    // ---- layer 2: o[k], out col = p*8 + k
    float o[8];
    {
        const float4* b4 = reinterpret_cast<const float4*>(bn2 + p * 8);
        float4 b0 = b4[0], b1 = b4[1];
        o[0]=b0.x; o[1]=b0.y; o[2]=b0.z; o[3]=b0.w;
        o[4]=b1.x; o[5]=b1.y; o[6]=b1.z; o[7]=b1.w;
    }
    #pragma unroll
    for (int i4 = 0; i4 < 16; ++i4) {
        float4 hv = *reinterpret_cast<const float4*>(&hsh[nl][i4 * 4]);
        float hh[4] = {hv.x, hv.y, hv.z, hv.w};
        #pragma unroll
        for (int q = 0; q < 4; ++q) {
            const float4* wr = reinterpret_cast<const float4*>(
                Wn2 + (i4 * 4 + q) * 32 + p * 8);
            float4 wa = wr[0], wb = wr[1];
            float hq = hh[q];
            o[0] = fmaf(hq, wa.x, o[0]); o[1] = fmaf(hq, wa.y, o[1]);
            o[2] = fmaf(hq, wa.z, o[2]); o[3] = fmaf(hq, wa.w, o[3]);
            o[4] = fmaf(hq, wb.x, o[4]); o[5] = fmaf(hq, wb.y, o[5]);
            o[6] = fmaf(hq, wb.z, o[6]); o[7] = fmaf(hq, wb.w, o[7]);
        }
    }

    if (!valid) return;
    float4* xo = reinterpret_cast<float4*>(x + (size_t)n * 32 + p * 8);
    xo[0] = make_float4(o[0], o[1], o[2], o[3]);
    xo[1] = make_float4(o[4], o[5], o[6], o[7]);
    unsigned int* xbu = reinterpret_cast<unsigned int*>(xb) + (size_t)n * 16 + p * 4;
    #pragma unroll
    for (int i = 0; i < 4; ++i)
        xbu[i] = (unsigned int)f2bf(o[2 * i]) | ((unsigned int)f2bf(o[2 * i + 1]) << 16);
}

// ---------------------------------------------------------------- fused layer v4
// v3.2 with a 3-set / 2-tile-deep fragment pipeline (3x unrolled, compile-time
// set indices): each xb/rbf gather now has ~2 full tile-computes to land.
__global__ __launch_bounds__(256, 6) void layer_kernel(
    const int* __restrict__ deg, const int* __restrict__ start,
    const int* __restrict__ csr_col, const unsigned short* __restrict__ rbf_buf,
    const float* __restrict__ x_in, const unsigned short* __restrict__ xb_in,
    float* __restrict__ x_out, unsigned short* __restrict__ xb_out,
    const short* __restrict__ wt1, const float* __restrict__ b1,
    const short* __restrict__ wt2, const float* __restrict__ b2,
    const short* __restrict__ wtu1, const float* __restrict__ bu1,
    const short* __restrict__ wtu2, const float* __restrict__ bu2)
{
    __shared__ unsigned short lsh[4][16 * 34];   // sh  (bf16), stride 34
    __shared__ unsigned short agb[4][16 * 34];   // ag  (bf16)
    __shared__ unsigned short hub[4][16 * 34];   // hu  (bf16)
    __shared__ float lrp[4][16 * 33];            // rowpart b1 + x@W1[0:32,:] (fp32)
    __shared__ float ldg[4][16];
    __shared__ float livd[4][16];

    int t = threadIdx.x;
    int w = t >> 6;
    int lane = t & 63;
    int quad = lane >> 4;
    int ml = lane & 15;
    int wid = blockIdx.x * 4 + w;
    int nbase = __builtin_amdgcn_readfirstlane(wid * NPW);
    if (nbase >= N) return;   // N % 16 == 0, so valid waves own full batches

    // ---- batch metadata: lane ml holds node ml's start/deg
    int vs = start[nbase + ml];
    int vd = deg[nbase + ml];

    // ---- edge-phase B fragments (wt1 [32][96])
    const short8* wp = reinterpret_cast<const short8*>(wt1);
    short8 B00 = wp[(ml     ) * 12 + 0 * 4 + quad];
    short8 B01 = wp[(ml     ) * 12 + 1 * 4 + quad];
    short8 B02 = wp[(ml     ) * 12 + 2 * 4 + quad];
    short8 B10 = wp[(ml + 16) * 12 + 0 * 4 + quad];
    short8 B11 = wp[(ml + 16) * 12 + 1 * 4 + quad];
    short8 B12 = wp[(ml + 16) * 12 + 2 * 4 + quad];

    // node-phase / rowpart x A-fragment (A[m=node ml][k=quad*8+j])
    short8 Ax = ld_xb(xb_in, nbase + ml, quad);

    float b1j0 = b1[ml];
    float b1j1 = b1[ml + 16];

    // ---- zero sh, stash deg floats
    unsigned short* lshp = lsh[w];
    for (int k = lane; k < 16 * 34; k += 64) lshp[k] = 0;
    if (lane < 16) {
        ldg[w][lane] = (float)vd;
        livd[w][lane] = 1.0f / fmaxf((float)vd, 1.0f);
    }

    // ---- hoisted row-node partial: rp[m][j] = b1[j] + x[m] @ W1[0:32, j]
    float* rpp = lrp[w];
    {
        f32x4 rp0 = {b1j0, b1j0, b1j0, b1j0};
        f32x4 rp1 = {b1j1, b1j1, b1j1, b1j1};
        rp0 = __builtin_amdgcn_mfma_f32_16x16x32_bf16(Ax, B00, rp0, 0, 0, 0);
        rp1 = __builtin_amdgcn_mfma_f32_16x16x32_bf16(Ax, B10, rp1, 0, 0, 0);
        int row = quad * 4;
        #pragma unroll
        for (int r = 0; r < 4; ++r) {
            rpp[(row + r) * 33 + ml]      = rp0[r];
            rpp[(row + r) * 33 + ml + 16] = rp1[r];
        }
    }
    __builtin_amdgcn_wave_barrier();

    // ---- edge loop: 5-deep index queue (A..E), 3 fragment sets, 2-deep col queue
    const short8 Z8 = {0, 0, 0, 0, 0, 0, 0, 0};
    int iA = 0, tA = -1; adv(iA, tA, vd);
    int iB = iA, tB = tA; adv(iB, tB, vd);
    int iC = iB, tC = tB; adv(iC, tC, vd);
    int iD = iC, tD = tC; adv(iD, tD, vd);
    int iE = iD, tE = tD; adv(iE, tE, vd);

    int slot0 = slotOf(iA, tA, vs, vd, ml);
    int slot1 = slotOf(iB, tB, vs, vd, ml);
    int slot2 = slotOf(iC, tC, vs, vd, ml);
    int slotQ = slotOf(iD, tD, vs, vd, ml);
    int col0 = csr_col[slot0];
    int col1 = csr_col[slot1];
    int col2 = csr_col[slot2];
    int colQ = csr_col[slotQ];

    short8 F1_0 = ld_xb(xb_in, col0, quad);
    short8 F2_0 = (quad < 2) ? ld_rbf(rbf_buf, slot0, quad) : Z8;
    short8 F1_1 = ld_xb(xb_in, col1, quad);
    short8 F2_1 = (quad < 2) ? ld_rbf(rbf_buf, slot1, quad) : Z8;
    short8 F1_2 = ld_xb(xb_in, col2, quad);
    short8 F2_2 = (quad < 2) ? ld_rbf(rbf_buf, slot2, quad) : Z8;

    float colp0 = 0.0f, colp1 = 0.0f;

    // compute tile at queue head from fragment set (A1,A2)
    auto tile = [&](const short8& A1, const short8& A2) {
        float rpa = rpp[iA * 33 + ml];
        float rpb = rpp[iA * 33 + ml + 16];
        f32x4 acc0 = {rpa, rpa, rpa, rpa};
        f32x4 acc1 = {rpb, rpb, rpb, rpb};
        acc0 = __builtin_amdgcn_mfma_f32_16x16x32_bf16(A1, B01, acc0, 0, 0, 0);
        acc0 = __builtin_amdgcn_mfma_f32_16x16x32_bf16(A2, B02, acc0, 0, 0, 0);
        acc1 = __builtin_amdgcn_mfma_f32_16x16x32_bf16(A1, B11, acc1, 0, 0, 0);
        acc1 = __builtin_amdgcn_mfma_f32_16x16x32_bf16(A2, B12, acc1, 0, 0, 0);

        int dg0 = rl(vd, iA);
        int rowbase = tA * 16 + quad * 4;
        #pragma unroll
        for (int r = 0; r < 4; ++r) {
            bool vld = (rowbase + r) < dg0;
            colp0 += vld ? silu_f(acc0[r]) : 0.0f;
            colp1 += vld ? silu_f(acc1[r]) : 0.0f;
        }
        if (tA == ((dg0 + 15) >> 4) - 1) {   // last tile of node iA (uniform)
            colp0 += __shfl_xor(colp0, 16, 64);
            colp0 += __shfl_xor(colp0, 32, 64);
            colp1 += __shfl_xor(colp1, 16, 64);
            colp1 += __shfl_xor(colp1, 32, 64);
            if (quad == 0) {
                lshp[iA * 34 + ml]      = f2bf(colp0);
                lshp[iA * 34 + ml + 16] = f2bf(colp1);
            }
            colp0 = 0.0f; colp1 = 0.0f;
        }
    };
    auto shiftq = [&]() {
        iA = iB; tA = tB; iB = iC; tB = tC;
        iC = iD; tC = tD; iD = iE; tD = tE;
        adv(iE, tE, vd);
    };

    // STEP k (set s): prefetch col(k+4); compute tile k; refill set s with
    // frags(k+3) via colQ/slotQ (queued at step k-1); shift.
    #define EDGE_STEP(F1s, F2s)                                     \
    {                                                               \
        int slotE_ = slotOf(iE, tE, vs, vd, ml);                    \
        int colE_  = csr_col[slotE_];                               \
        tile(F1s, F2s);                                             \
        F1s = ld_xb(xb_in, colQ, quad);                             \
        F2s = (quad < 2) ? ld_rbf(rbf_buf, slotQ, quad) : Z8;       \
        shiftq();                                                   \
        colQ = colE_; slotQ = slotE_;                               \
    }

    while (iA < 16) {
        EDGE_STEP(F1_0, F2_0);
        if (iA >= 16) break;
        EDGE_STEP(F1_1, F2_1);
        if (iA >= 16) break;
        EDGE_STEP(F1_2, F2_2);
    }
    #undef EDGE_STEP
    __builtin_amdgcn_wave_barrier();

    // ---- node phase: 16-node batch, 8 MFMAs
    const short8* w2p = reinterpret_cast<const short8*>(wt2);
    short8 Bw2_0 = w2p[(ml     ) * 4 + quad];
    short8 Bw2_1 = w2p[(ml + 16) * 4 + quad];
    const short8* u1p = reinterpret_cast<const short8*>(wtu1);
    short8 Bu1_00 = u1p[(ml     ) * 8 + quad];       // k 0..31 (x)
    short8 Bu1_10 = u1p[(ml     ) * 8 + 4 + quad];   // k 32..63 (ag)
    short8 Bu1_01 = u1p[(ml + 16) * 8 + quad];
    short8 Bu1_11 = u1p[(ml + 16) * 8 + 4 + quad];
    const short8* u2p = reinterpret_cast<const short8*>(wtu2);
    short8 Bu2_0 = u2p[(ml     ) * 4 + quad];
    short8 Bu2_1 = u2p[(ml + 16) * 4 + quad];

    // sh @ W2
    short8 Ash = *reinterpret_cast<const short8*>(lshp + ml * 34 + quad * 8);
    f32x4 c0 = {0.0f, 0.0f, 0.0f, 0.0f};
    f32x4 c1 = {0.0f, 0.0f, 0.0f, 0.0f};
    c0 = __builtin_amdgcn_mfma_f32_16x16x32_bf16(Ash, Bw2_0, c0, 0, 0, 0);
    c1 = __builtin_amdgcn_mfma_f32_16x16x32_bf16(Ash, Bw2_1, c1, 0, 0, 0);
    float b2c0 = b2[ml], b2c1 = b2[ml + 16];
    unsigned short* agp = agb[w];
    int row = quad * 4;
    #pragma unroll
    for (int r = 0; r < 4; ++r) {
        float fd = ldg[w][row + r];
        float iv = livd[w][row + r];
        agp[(row + r) * 34 + ml]      = f2bf((c0[r] + fd * b2c0) * iv);
        agp[(row + r) * 34 + ml + 16] = f2bf((c1[r] + fd * b2c1) * iv);
    }
    __builtin_amdgcn_wave_barrier();

    // [x ; ag] @ Wu1
    short8 Aag = *reinterpret_cast<const short8*>(agp + ml * 34 + quad * 8);
    f32x4 d0 = {0.0f, 0.0f, 0.0f, 0.0f};
    f32x4 d1 = {0.0f, 0.0f, 0.0f, 0.0f};
    d0 = __builtin_amdgcn_mfma_f32_16x16x32_bf16(Ax,  Bu1_00, d0, 0, 0, 0);
    d0 = __builtin_amdgcn_mfma_f32_16x16x32_bf16(Aag, Bu1_10, d0, 0, 0, 0);
    d1 = __builtin_amdgcn_mfma_f32_16x16x32_bf16(Ax,  Bu1_01, d1, 0, 0, 0);
    d1 = __builtin_amdgcn_mfma_f32_16x16x32_bf16(Aag, Bu1_11, d1, 0, 0, 0);
    float bu1c0 = bu1[ml], bu1c1 = bu1[ml + 16];
    unsigned short* hup = hub[w];
    #pragma unroll
    for (int r = 0; r < 4; ++r) {
        hup[(row + r) * 34 + ml]      = f2bf(silu_f(d0[r] + bu1c0));
        hup[(row + r) * 34 + ml + 16] = f2bf(silu_f(d1[r] + bu1c1));
    }
    __builtin_amdgcn_wave_barrier();

    // hu @ Wu2 ; residual (x_in re-read, coalesced + L2-hot) + store
    short8 Ahu = *reinterpret_cast<const short8*>(hup + ml * 34 + quad * 8);
    float xr0[4], xr1[4];
    #pragma unroll
    for (int r = 0; r < 4; ++r) {
        int nn = nbase + row + r;
        xr0[r] = x_in[(size_t)nn * 32 + ml];
        xr1[r] = x_in[(size_t)nn * 32 + ml + 16];
    }
    f32x4 e0 = {0.0f, 0.0f, 0.0f, 0.0f};
    f32x4 e1 = {0.0f, 0.0f, 0.0f, 0.0f};
    e0 = __builtin_amdgcn_mfma_f32_16x16x32_bf16(Ahu, Bu2_0, e0, 0, 0, 0);
    e1 = __builtin_amdgcn_mfma_f32_16x16x32_bf16(Ahu, Bu2_1, e1, 0, 0, 0);
    float bu2c0 = bu2[ml], bu2c1 = bu2[ml + 16];
    #pragma unroll
    for (int r = 0; r < 4; ++r) {
        int nn = nbase + row + r;
        float o0 = e0[r] + bu2c0 + xr0[r];
        float o1 = e1[r] + bu2c1 + xr1[r];
        x_out[(size_t)nn * 32 + ml]      = o0;
        x_out[(size_t)nn * 32 + ml + 16] = o1;
        xb_out[(size_t)nn * 32 + ml]      = f2bf(o0);
        xb_out[(size_t)nn * 32 + ml + 16] = f2bf(o1);
    }
}

// ---------------------------------------------------------------- LN + heads, MFMA version
__global__ __launch_bounds__(256) void final_kernel(
    const float* __restrict__ x, const float* __restrict__ u,
    const float* __restrict__ v,
    const float* __restrict__ ln_g, const float* __restrict__ ln_b,
    const short* __restrict__ wtr1, const float* __restrict__ br1,
    const float* __restrict__ Wr2, const float* __restrict__ br2,
    const short* __restrict__ wts1, const float* __restrict__ bs1,
    const float* __restrict__ Ws2, const float* __restrict__ bs2,
    float* __restrict__ out)
{
    int t = threadIdx.x;
    int w = t >> 6;
    int lane = t & 63;
    int quad = lane >> 4;
    int ml = lane & 15;
    int wid = blockIdx.x * 4 + w;
    int nbase = __builtin_amdgcn_readfirstlane(wid * NPW);
    if (nbase >= N) return;

    // lane (quad,ml) holds x[nbase+ml][quad*8 .. quad*8+7]
    const float4* xs = reinterpret_cast<const float4*>(
        x + (size_t)(nbase + ml) * 32 + quad * 8);
    float4 xa = xs[0], xb4 = xs[1];
    float f[8] = {xa.x, xa.y, xa.z, xa.w, xb4.x, xb4.y, xb4.z, xb4.w};

    // LN statistics for node ml: reduce over k (across the 4 quads)
    float s = 0.0f, ss = 0.0f;
    #pragma unroll
    for (int i = 0; i < 8; ++i) { s += f[i]; ss += f[i] * f[i]; }
    s  += __shfl_xor(s, 16, 64);  s  += __shfl_xor(s, 32, 64);
    ss += __shfl_xor(ss, 16, 64); ss += __shfl_xor(ss, 32, 64);
    float mu = s * (1.0f / 32.0f);
    float var = ss * (1.0f / 32.0f) - mu * mu;
    float rs = rsqrtf(var + 1e-5f);

    // LN affine + bf16 A fragment (A[m=ml][k=quad*8+j])
    const float4* gp = reinterpret_cast<const float4*>(ln_g + quad * 8);
    const float4* bp = reinterpret_cast<const float4*>(ln_b + quad * 8);
    float4 g0 = gp[0], g1 = gp[1], bb0 = bp[0], bb1 = bp[1];
    float gg[8] = {g0.x, g0.y, g0.z, g0.w, g1.x, g1.y, g1.z, g1.w};
    float bb[8] = {bb0.x, bb0.y, bb0.z, bb0.w, bb1.x, bb1.y, bb1.z, bb1.w};
    short8 A;
    #pragma unroll
    for (int i = 0; i < 8; ++i)
        A[i] = (short)f2bf((f[i] - mu) * rs * gg[i] + bb[i]);

    // head layer 1: 6 MFMAs per head (output tiles n = ml + 16*h)
    const short8* r1p = reinterpret_cast<const short8*>(wtr1);
    const short8* s1p = reinterpret_cast<const short8*>(wts1);
    const f32x4 Zf = {0.0f, 0.0f, 0.0f, 0.0f};
    f32x4 hr[6], hs[6];
    #pragma unroll
    for (int h = 0; h < 6; ++h) {
        hr[h] = __builtin_amdgcn_mfma_f32_16x16x32_bf16(A, r1p[(ml + 16 * h) * 4 + quad], Zf, 0, 0, 0);
        hs[h] = __builtin_amdgcn_mfma_f32_16x16x32_bf16(A, s1p[(ml + 16 * h) * 4 + quad], Zf, 0, 0, 0);
    }

    // per-lane second-layer weights for features j = ml + 16*h
    float wr2a[6], wr2b[6], ws2v[6], br1v[6], bs1v[6];
    #pragma unroll
    for (int h = 0; h < 6; ++h) {
        int j = ml + 16 * h;
        float2 wr = reinterpret_cast<const float2*>(Wr2)[j];
        wr2a[h] = wr.x; wr2b[h] = wr.y;
        ws2v[h] = Ws2[j];
        br1v[h] = br1[j];
        bs1v[h] = bs1[j];
    }

    // silu + second layer; lane holds D rows m = quad*4+r, col n = ml+16h.
    float o0[4], o1[4], o2[4];
    #pragma unroll
    for (int r = 0; r < 4; ++r) {
        float p0 = 0.0f, p1 = 0.0f, p2 = 0.0f;
        #pragma unroll
        for (int h = 0; h < 6; ++h) {
            float a1 = silu_f(hr[h][r] + br1v[h]);
            float a2 = silu_f(hs[h][r] + bs1v[h]);
            p0 = fmaf(a1, wr2a[h], p0);
            p1 = fmaf(a1, wr2b[h], p1);
            p2 = fmaf(a2, ws2v[h], p2);
        }
        p0 += __shfl_xor(p0, 1, 64); p0 += __shfl_xor(p0, 2, 64);
        p0 += __shfl_xor(p0, 4, 64); p0 += __shfl_xor(p0, 8, 64);
        p1 += __shfl_xor(p1, 1, 64); p1 += __shfl_xor(p1, 2, 64);
        p1 += __shfl_xor(p1, 4, 64); p1 += __shfl_xor(p1, 8, 64);
        p2 += __shfl_xor(p2, 1, 64); p2 += __shfl_xor(p2, 2, 64);
        p2 += __shfl_xor(p2, 4, 64); p2 += __shfl_xor(p2, 8, 64);
        o0[r] = p0; o1[r] = p1; o2[r] = p2;
    }

    if (ml == 0) {
        float b20 = br2[0], b21 = br2[1], b22 = bs2[0];
        #pragma unroll
        for (int r = 0; r < 4; ++r) {
            int n = nbase + quad * 4 + r;
            out[n] = u[n * 4 + 3] + o2[r] + b22;
            out[N + 2 * n]     = o0[r] + b20 + v[n * 8 + 6];
            out[N + 2 * n + 1] = o1[r] + b21 + v[n * 8 + 7];
        }
    }
}

} // anonymous namespace

extern "C" void kernel_launch(void* const* d_in, const int* in_sizes, int n_in,
                              void* d_out, int out_size, void* d_ws, size_t ws_size,
                              hipStream_t stream)
{
    const float* u    = (const float*)d_in[0];
    const float* v    = (const float*)d_in[1];
    const float* bno  = (const float*)d_in[2];
    const float* yf   = (const float*)d_in[4];
    const float* pos  = (const float*)d_in[5];
    const int*   ei   = (const int*)d_in[6];
    const float* Wn1  = (const float*)d_in[7];
    const float* bn1  = (const float*)d_in[8];
    const float* Wn2  = (const float*)d_in[9];
    const float* bn2  = (const float*)d_in[10];
    const float* We1  = (const float*)d_in[11];
    const float* be1  = (const float*)d_in[12];
    const float* We2  = (const float*)d_in[13];
    const float* be2  = (const float*)d_in[14];
    const float* Wu1  = (const float*)d_in[15];
    const float* bu1  = (const float*)d_in[16];
    const float* Wu2  = (const float*)d_in[17];
    const float* bu2  = (const float*)d_in[18];
    const float* ln_g = (const float*)d_in[19];
    const float* ln_b = (const float*)d_in[20];
    const float* Wr1  = (const float*)d_in[21];
    const float* br1  = (const float*)d_in[22];
    const float* Wr2  = (const float*)d_in[23];
    const float* br2  = (const float*)d_in[24];
    const float* Ws1  = (const float*)d_in[25];
    const float* bs1  = (const float*)d_in[26];
    const float* Ws2  = (const float*)d_in[27];
    const float* bs2  = (const float*)d_in[28];
    float* out = (float*)d_out;

    // workspace layout (16B-aligned sections)
    int*   deg      = (int*)d_ws;                            // N
    int*   start    = deg + N;                               // N
    int*   bstart   = start + N;                             // NBKT+1
    int*   csr_col  = bstart + 512;                          // E ints
    unsigned short* rbf = (unsigned short*)(csr_col + E);    // E*16 bf16 (51.2 MB)
    float* x0       = (float*)(rbf + (size_t)E * 16);        // N*32 f32
    float* x1       = x0 + (size_t)N * S;                    // N*32 f32
    unsigned short* xb0 = (unsigned short*)(x1 + (size_t)N * S);   // N*32 bf16
    unsigned short* xb1 = xb0 + (size_t)N * S;               // N*32 bf16
    short* wt1      = (short*)(xb1 + (size_t)N * S);         // 5*32*96
    short* wt2      = wt1 + 5 * 32 * 96;                     // 5*32*32
    short* wtu1     = wt2 + 5 * 32 * 32;                     // 5*32*64
    short* wtu2     = wtu1 + 5 * 32 * 64;                    // 5*32*32
    short* wtr1     = wtu2 + 5 * 32 * 32;                    // 96*32 (head r, [n][k])
    short* wts1     = wtr1 + 96 * 32;                        // 96*32 (head s, [n][k])
    int*   hist     = (int*)(wts1 + 96 * 32);                // NBKT*256
    int*   basem    = hist + NBKT * 256;                     // NBKT*256

    // transient alias (dead before node_embed writes x0 / layer writes x1):
    //   edgebuf: E*16B bucket-ordered {col, dist, row} == x0..xb0 (E*16 == N*32*4*2)
    uint4* edgebuf = (uint4*)x0;

    passA_kernel<<<256, 256, 0, stream>>>(ei, hist);
    p1_kernel<<<1, 512, 0, stream>>>(hist, bstart);
    p2_kernel<<<NBKT, 256, 0, stream>>>(hist, bstart, basem);
    passB_kernel<<<256, 256, 0, stream>>>(ei, pos, basem, edgebuf);
    passC_kernel<<<NBKT, 256, 0, stream>>>(edgebuf, bstart, deg, start, csr_col, rbf);
    prep_wt_kernel<<<60, 256, 0, stream>>>(We1, We2, Wu1, Wu2, Wr1, Ws1,
                                           wt1, wt2, wtu1, wtu2, wtr1, wts1);

    node_embed_kernel<<<LB2, 256, 0, stream>>>(u, v, bno, yf, Wn1, bn1, Wn2, bn2,
                                               x0, xb0);

    float* xin = x0;  float* xout = x1;
    unsigned short* xbin = xb0;  unsigned short* xbout = xb1;
    for (int l = 0; l < L; ++l) {
        layer_kernel<<<LB2, 256, 0, stream>>>(
            deg, start, csr_col, rbf, xin, xbin, xout, xbout,
            wt1 + (size_t)l * 32 * 96,  be1 + (size_t)l * 32,
            wt2 + (size_t)l * 32 * 32,  be2 + (size_t)l * 32,
            wtu1 + (size_t)l * 32 * 64, bu1 + (size_t)l * 32,
            wtu2 + (size_t)l * 32 * 32, bu2 + (size_t)l * 32);
        float* tf = xin; xin = xout; xout = tf;
        unsigned short* tb = xbin; xbin = xbout; xbout = tb;
    }

    final_kernel<<<LB2, 256, 0, stream>>>(xin, u, v, ln_g, ln_b,
                                          wtr1, br1, Wr2, br2,
                                          wts1, bs1, Ws2, bs2, out);
}

// Round 11
// 496.743 us; speedup vs baseline: 1.2254x; 1.0128x over previous
//
#include <hip/hip_runtime.h>
#include <cmath>

namespace {

constexpr int N = 100000;
constexpr int E = 1600000;
constexpr int S = 32;           // hidden
constexpr int L = 5;            // layers
constexpr int NB = (N + 255) / 256;   // node-per-thread kernels
constexpr int NPW = 16;               // nodes per wave in layer kernel
constexpr int LB2 = (N + 63) / 64;    // 1563 blocks (4 waves/block, 16 nodes/wave)
constexpr int NBKT = 391;             // CSR buckets: row>>8, 256 rows each
constexpr int EPB  = E / 256;         // 6250 edges per histogram/scatter block
constexpr float PI_F    = 3.14159265358979323846f;
constexpr float SQRT2_F = 1.41421356237309515f;

typedef __attribute__((ext_vector_type(8))) short short8;   // 8 x bf16
typedef __attribute__((ext_vector_type(4))) float f32x4;

// fast silu: v_rcp_f32 instead of IEEE division (saves ~10 VALU instrs/call)
__device__ __forceinline__ float silu_f(float x) {
    return x * __builtin_amdgcn_rcpf(1.0f + __expf(-x));
}

// float -> bf16 bits, round-to-nearest-even
__device__ __forceinline__ unsigned short f2bf(float f) {
    unsigned int u = __float_as_uint(f);
    u = (u + 0x7FFFu + ((u >> 16) & 1u)) >> 16;
    return (unsigned short)u;
}

__device__ __forceinline__ int rl(int v, int i) {
    return __builtin_amdgcn_readlane(v, i);
}

// 32-bit byte-offset gather of a 16B xb fragment: base + col*64 + quad*16
__device__ __forceinline__ short8 ld_xb(const unsigned short* base, int col, int quad) {
    unsigned off = ((unsigned)col << 6) | ((unsigned)quad << 4);
    return *reinterpret_cast<const short8*>(reinterpret_cast<const char*>(base) + off);
}

// 32-bit byte-offset read of an rbf half-row: base + slot*32 + quad*16
__device__ __forceinline__ short8 ld_rbf(const unsigned short* base, int slot, int quad) {
    unsigned off = ((unsigned)slot << 5) | ((unsigned)quad << 4);
    return *reinterpret_cast<const short8*>(reinterpret_cast<const char*>(base) + off);
}

// advance (i,t) to the next tile of this wave's 16-node batch (uniform)
__device__ __forceinline__ void adv(int& i, int& t, int vd) {
    ++t;
    while (i < 16) {
        int dgi = rl(vd, i);
        int nt = (dgi + 15) >> 4;
        if (t < nt) break;
        t = 0; ++i;
    }
}

// CSR slot for (i,t) at lane row ml; clamped into the node's own range
__device__ __forceinline__ int slotOf(int i, int t, int vs, int vd, int ml) {
    if (i >= 16) return 0;
    int s0 = rl(vs, i);
    int dg = rl(vd, i);
    int smax = s0 + ((dg > 0) ? dg : 1) - 1;
    int s = s0 + t * 16 + ml;
    return min(s, smax);
}

// ---------------------------------------------------------------- passA: bucket histogram
// 256 blocks x 1024 threads (was 256: 1 wave/SIMD, latency-starved).
__global__ __launch_bounds__(1024) void passA_kernel(
    const int* __restrict__ ei, int* __restrict__ hist)
{
    __shared__ int h[NBKT];
    int t = threadIdx.x;
    int blk = blockIdx.x;
    for (int b = t; b < NBKT; b += 1024) h[b] = 0;
    __syncthreads();
    int base = blk * EPB;
    for (int i = t; i < EPB; i += 1024) {
        int r = ei[base + i];
        atomicAdd(&h[r >> 8], 1);
    }
    __syncthreads();
    for (int b = t; b < NBKT; b += 1024) hist[b * 256 + blk] = h[b];
}

// ---------------------------------------------------------------- p1: bucket totals + exclusive prefix
__global__ __launch_bounds__(512) void p1_kernel(
    const int* __restrict__ hist, int* __restrict__ bstart)
{
    __shared__ int tot[NBKT + 1];
    int t = threadIdx.x;
    if (t < NBKT) {
        int s = 0;
        for (int b = 0; b < 256; ++b) s += hist[t * 256 + b];
        tot[t] = s;
    }
    __syncthreads();
    if (t == 0) {
        int a = 0;
        for (int i = 0; i < NBKT; ++i) { int c = tot[i]; tot[i] = a; a += c; }
        tot[NBKT] = a;   // == E
    }
    __syncthreads();
    if (t <= NBKT) bstart[t] = tot[t];
}

// ---------------------------------------------------------------- p2: per-(bin,blk) scatter bases
__global__ __launch_bounds__(256) void p2_kernel(
    const int* __restrict__ hist, const int* __restrict__ bstart,
    int* __restrict__ base)
{
    __shared__ int pre[256];
    int t = threadIdx.x;
    int bin = blockIdx.x;
    int h = hist[bin * 256 + t];
    pre[t] = h;
    __syncthreads();
    #pragma unroll
    for (int off = 1; off < 256; off <<= 1) {
        int v = (t >= off) ? pre[t - off] : 0;
        __syncthreads();
        pre[t] += v;
        __syncthreads();
    }
    base[bin * 256 + t] = bstart[bin] + pre[t] - h;   // exclusive over blocks
}

// ---------------------------------------------------------------- passB: scatter to bucket staging
// 256 blocks x 1024 threads (16 waves/block) -> 4x the resident waves of the old
// 256-thread version; LDS cursor table stays per-block (no global atomics).
__global__ __launch_bounds__(1024) void passB_kernel(
    const int* __restrict__ ei, const float* __restrict__ pos,
    const int* __restrict__ base, uint4* __restrict__ edgebuf)
{
    __shared__ int cur[NBKT];
    int t = threadIdx.x;
    int blk = blockIdx.x;
    for (int b = t; b < NBKT; b += 1024) cur[b] = base[b * 256 + blk];
    __syncthreads();
    int ebase = blk * EPB;
    for (int i = t; i < EPB; i += 1024) {
        int e = ebase + i;
        int r = ei[e];
        int c = ei[E + e];
        float2 pr = reinterpret_cast<const float2*>(pos)[r];
        float2 pc = reinterpret_cast<const float2*>(pos)[c];
        float dx = pr.x - pc.x, dy = pr.y - pc.y;
        float d = sqrtf(dx * dx + dy * dy);   // pos-mean cancels
        int slot = atomicAdd(&cur[r >> 8], 1);   // LDS atomic
        edgebuf[slot] = make_uint4((unsigned)c, __float_as_uint(d), (unsigned)r, 0u);
    }
}

// ---------------------------------------------------------------- passC: per-bucket deg/start/rank + fused rbf
// 391 blocks x 1024 threads (was 256: only ~6 waves/CU for the heaviest
// prep kernel). Scan section guarded to t<256; barriers stay uniform.
__global__ __launch_bounds__(1024) void passC_kernel(
    const uint4* __restrict__ edgebuf, const int* __restrict__ bstart,
    int* __restrict__ deg, int* __restrict__ start,
    int* __restrict__ csr_col, unsigned short* __restrict__ rbf_buf)
{
    __shared__ int cnt[256];
    __shared__ int pre[256];
    __shared__ int cur[256];
    int t = threadIdx.x;
    int bkt = blockIdx.x;
    int s0 = bstart[bkt], s1 = bstart[bkt + 1];

    if (t < 256) cnt[t] = 0;
    __syncthreads();
    for (int i = s0 + t; i < s1; i += 1024) {
        unsigned r = edgebuf[i].z;
        atomicAdd(&cnt[r & 255], 1);
    }
    __syncthreads();
    int c0 = 0;
    if (t < 256) {
        c0 = cnt[t];
        pre[t] = c0;
    }
    __syncthreads();
    #pragma unroll
    for (int off = 1; off < 256; off <<= 1) {
        int v = 0;
        if (t < 256) v = (t >= off) ? pre[t - off] : 0;
        __syncthreads();
        if (t < 256) pre[t] += v;
        __syncthreads();
    }
    if (t < 256) {
        int row = bkt * 256 + t;
        int st = s0 + pre[t] - c0;   // exclusive
        if (row < N) {
            deg[row] = c0;
            start[row] = st;
        }
        cur[t] = st;
    }
    __syncthreads();

    for (int i = s0 + t; i < s1; i += 1024) {
        uint4 e = edgebuf[i];
        int slot = atomicAdd(&cur[e.z & 255], 1);   // LDS atomic
        csr_col[slot] = (int)e.x;
        float d = __uint_as_float(e.y);

        float sn = __sinf(PI_F * d);
        float c1 = __cosf(PI_F * d);
        float inv = SQRT2_F / (d + 1e-8f);
        float tc = 2.0f * c1;
        float sk = sn, skm = 0.0f;
        unsigned int pk[8];
        #pragma unroll
        for (int k = 0; k < 8; ++k) {
            float r0 = sk * inv;
            float s2 = tc * sk - skm; skm = sk; sk = s2;
            float r1 = sk * inv;
            float s3 = tc * sk - skm; skm = sk; sk = s3;
            pk[k] = (unsigned int)f2bf(r0) | ((unsigned int)f2bf(r1) << 16);
        }
        uint4* out = reinterpret_cast<uint4*>(rbf_buf + (size_t)slot * 16);
        out[0] = make_uint4(pk[0], pk[1], pk[2], pk[3]);
        out[1] = make_uint4(pk[4], pk[5], pk[6], pk[7]);
    }
}

// ---------------------------------------------------------------- bf16 weight prep (transposed [n][k])
__global__ __launch_bounds__(256) void prep_wt_kernel(
    const float* __restrict__ We1, const float* __restrict__ We2,
    const float* __restrict__ Wu1, const float* __restrict__ Wu2,
    const float* __restrict__ Wr1, const float* __restrict__ Ws1,
    short* __restrict__ wt1, short* __restrict__ wt2,
    short* __restrict__ wtu1, short* __restrict__ wtu2,
    short* __restrict__ wtr1, short* __restrict__ wts1)
{
    int idx = blockIdx.x * 256 + threadIdx.x;
    if (idx < 5 * 32 * 96) {
        int l = idx / (32 * 96), r = idx % (32 * 96), n = r / 96, k = r % 96;
        float v = (k < 80) ? We1[((size_t)l * 80 + k) * 32 + n] : 0.0f;
        wt1[idx] = (short)f2bf(v);
    }
    if (idx < 5 * 32 * 32) {
        int l = idx / 1024, r = idx % 1024, n = r / 32, k = r % 32;
        wt2[idx]  = (short)f2bf(We2[((size_t)l * 32 + k) * 32 + n]);
        wtu2[idx] = (short)f2bf(Wu2[((size_t)l * 32 + k) * 32 + n]);
    }
    if (idx < 5 * 32 * 64) {
        int l = idx / 2048, r = idx % 2048, n = r / 64, k = r % 64;
        wtu1[idx] = (short)f2bf(Wu1[((size_t)l * 64 + k) * 32 + n]);
    }
    if (idx < 96 * 32) {
        int n = idx / 32, k = idx % 32;   // head weights [n=96][k=32]
        wtr1[idx] = (short)f2bf(Wr1[k * 96 + n]);
        wts1[idx] = (short)f2bf(Ws1[k * 96 + n]);
    }
}

// ---------------------------------------------------------------- node embed v2: 4 threads/node
__global__ __launch_bounds__(256) void node_embed_kernel(
    const float* __restrict__ u, const float* __restrict__ v,
    const float* __restrict__ bnorm, const float* __restrict__ yf,
    const float* __restrict__ Wn1, const float* __restrict__ bn1,
    const float* __restrict__ Wn2, const float* __restrict__ bn2,
    float* __restrict__ x, unsigned short* __restrict__ xb)
{
    __shared__ float hsh[64][68];
    int t = threadIdx.x;
    int nl = t >> 2;          // node within block (0..63)
    int p  = t & 3;           // part (0..3)
    int n  = blockIdx.x * 64 + nl;
    bool valid = (n < N);
    int nc = valid ? n : (N - 1);   // clamp loads for tail block

    float f[10];
    float4 uu = reinterpret_cast<const float4*>(u)[nc];
    f[0] = uu.x; f[1] = uu.y; f[2] = uu.z; f[3] = uu.w;
    float4 v0 = reinterpret_cast<const float4*>(v)[2 * nc];
    float4 v1 = reinterpret_cast<const float4*>(v)[2 * nc + 1];
    f[4] = sqrtf(v0.x * v0.x + v0.y * v0.y);
    f[5] = sqrtf(v0.z * v0.z + v0.w * v0.w);
    f[6] = sqrtf(v1.x * v1.x + v1.y * v1.y);
    f[7] = sqrtf(v1.z * v1.z + v1.w * v1.w);
    float2 bb = reinterpret_cast<const float2*>(bnorm)[nc];
    f[8] = sqrtf(bb.x * bb.x + bb.y * bb.y);
    float2 yy = reinterpret_cast<const float2*>(yf)[nc];
    f[9] = sqrtf(yy.x * yy.x + yy.y * yy.y);

    float h[16];
    {
        const float4* b4 = reinterpret_cast<const float4*>(bn1 + p * 16);
        float4 b0 = b4[0], b1 = b4[1], b2 = b4[2], b3 = b4[3];
        h[0]=b0.x; h[1]=b0.y; h[2]=b0.z; h[3]=b0.w;
        h[4]=b1.x; h[5]=b1.y; h[6]=b1.z; h[7]=b1.w;
        h[8]=b2.x; h[9]=b2.y; h[10]=b2.z; h[11]=b2.w;
        h[12]=b3.x; h[13]=b3.y; h[14]=b3.z; h[15]=b3.w;
    }
    #pragma unroll
    for (int i = 0; i < 10; ++i) {
        float ff = f[i];
        const float4* wr = reinterpret_cast<const float4*>(Wn1 + i * 64 + p * 16);
        float4 w0 = wr[0], w1 = wr[1], w2 = wr[2], w3 = wr[3];
        h[0]  = fmaf(ff, w0.x, h[0]);  h[1]  = fmaf(ff, w0.y, h[1]);
        h[2]  = fmaf(ff, w0.z, h[2]);  h[3]  = fmaf(ff, w0.w, h[3]);
        h[4]  = fmaf(ff, w1.x, h[4]);  h[5]  = fmaf(ff, w1.y, h[5]);
        h[6]  = fmaf(ff, w1.z, h[6]);  h[7]  = fmaf(ff, w1.w, h[7]);
        h[8]  = fmaf(ff, w2.x, h[8]);  h[9]  = fmaf(ff, w2.y, h[9]);
        h[10] = fmaf(ff, w2.z, h[10]); h[11] = fmaf(ff, w2.w, h[11]);
        h[12] = fmaf(ff, w3.x, h[12]); h[13] = fmaf(ff, w3.y, h[13]);
        h[14] = fmaf(ff, w3.z, h[14]); h[15] = fmaf(ff, w3.w, h[15]);
    }
    #pragma unroll
    for (int jj = 0; jj < 16; ++jj) h[jj] = silu_f(h[jj]);

    float4* hrow = reinterpret_cast<float4*>(&hsh[nl][p * 16]);
    hrow[0] = make_float4(h[0], h[1], h[2], h[3]);
    hrow[1] = make_float4(h[4], h[5], h[6], h[7]);
    hrow[2] = make_float4(h[8], h[9], h[10], h[11]);
    hrow[3] = make_float4(h[12], h[13], h[14], h[15]);
    __syncthreads();

    float o[8];
    {
        const float4* b4 = reinterpret_cast<const float4*>(bn2 + p * 8);
        float4 b0 = b4[0], b1 = b4[1];
        o[0]=b0.x; o[1]=b0.y; o[2]=b0.z; o[3]=b0.w;
        o[4]=b1.x; o[5]=b1.y; o[6]=b1.z; o[7]=b1.w;
    }
    #pragma unroll
    for (int i4 = 0; i4 < 16; ++i4) {
        float4 hv = *reinterpret_cast<const float4*>(&hsh[nl][i4 * 4]);
        float hh[4] = {hv.x, hv.y, hv.z, hv.w};
        #pragma unroll
        for (int q = 0; q < 4; ++q) {
            const float4* wr = reinterpret_cast<const float4*>(
                Wn2 + (i4 * 4 + q) * 32 + p * 8);
            float4 wa = wr[0], wb = wr[1];
            float hq = hh[q];
            o[0] = fmaf(hq, wa.x, o[0]); o[1] = fmaf(hq, wa.y, o[1]);
            o[2] = fmaf(hq, wa.z, o[2]); o[3] = fmaf(hq, wa.w, o[3]);
            o[4] = fmaf(hq, wb.x, o[4]); o[5] = fmaf(hq, wb.y, o[5]);
            o[6] = fmaf(hq, wb.z, o[6]); o[7] = fmaf(hq, wb.w, o[7]);
        }
    }

    if (!valid) return;
    float4* xo = reinterpret_cast<float4*>(x + (size_t)n * 32 + p * 8);
    xo[0] = make_float4(o[0], o[1], o[2], o[3]);
    xo[1] = make_float4(o[4], o[5], o[6], o[7]);
    unsigned int* xbu = reinterpret_cast<unsigned int*>(xb) + (size_t)n * 16 + p * 4;
    #pragma unroll
    for (int i = 0; i < 4; ++i)
        xbu[i] = (unsigned int)f2bf(o[2 * i]) | ((unsigned int)f2bf(o[2 * i + 1]) << 16);
}

// ---------------------------------------------------------------- fused layer v4
__global__ __launch_bounds__(256, 6) void layer_kernel(
    const int* __restrict__ deg, const int* __restrict__ start,
    const int* __restrict__ csr_col, const unsigned short* __restrict__ rbf_buf,
    const float* __restrict__ x_in, const unsigned short* __restrict__ xb_in,
    float* __restrict__ x_out, unsigned short* __restrict__ xb_out,
    const short* __restrict__ wt1, const float* __restrict__ b1,
    const short* __restrict__ wt2, const float* __restrict__ b2,
    const short* __restrict__ wtu1, const float* __restrict__ bu1,
    const short* __restrict__ wtu2, const float* __restrict__ bu2)
{
    __shared__ unsigned short lsh[4][16 * 34];   // sh  (bf16), stride 34
    __shared__ unsigned short agb[4][16 * 34];   // ag  (bf16)
    __shared__ unsigned short hub[4][16 * 34];   // hu  (bf16)
    __shared__ float lrp[4][16 * 33];            // rowpart b1 + x@W1[0:32,:] (fp32)
    __shared__ float ldg[4][16];
    __shared__ float livd[4][16];

    int t = threadIdx.x;
    int w = t >> 6;
    int lane = t & 63;
    int quad = lane >> 4;
    int ml = lane & 15;
    int wid = blockIdx.x * 4 + w;
    int nbase = __builtin_amdgcn_readfirstlane(wid * NPW);
    if (nbase >= N) return;   // N % 16 == 0, so valid waves own full batches

    // ---- batch metadata: lane ml holds node ml's start/deg
    int vs = start[nbase + ml];
    int vd = deg[nbase + ml];

    // ---- edge-phase B fragments (wt1 [32][96])
    const short8* wp = reinterpret_cast<const short8*>(wt1);
    short8 B00 = wp[(ml     ) * 12 + 0 * 4 + quad];
    short8 B01 = wp[(ml     ) * 12 + 1 * 4 + quad];
    short8 B02 = wp[(ml     ) * 12 + 2 * 4 + quad];
    short8 B10 = wp[(ml + 16) * 12 + 0 * 4 + quad];
    short8 B11 = wp[(ml + 16) * 12 + 1 * 4 + quad];
    short8 B12 = wp[(ml + 16) * 12 + 2 * 4 + quad];

    // node-phase / rowpart x A-fragment (A[m=node ml][k=quad*8+j])
    short8 Ax = ld_xb(xb_in, nbase + ml, quad);

    float b1j0 = b1[ml];
    float b1j1 = b1[ml + 16];

    // ---- zero sh, stash deg floats
    unsigned short* lshp = lsh[w];
    for (int k = lane; k < 16 * 34; k += 64) lshp[k] = 0;
    if (lane < 16) {
        ldg[w][lane] = (float)vd;
        livd[w][lane] = 1.0f / fmaxf((float)vd, 1.0f);
    }

    // ---- hoisted row-node partial: rp[m][j] = b1[j] + x[m] @ W1[0:32, j]
    float* rpp = lrp[w];
    {
        f32x4 rp0 = {b1j0, b1j0, b1j0, b1j0};
        f32x4 rp1 = {b1j1, b1j1, b1j1, b1j1};
        rp0 = __builtin_amdgcn_mfma_f32_16x16x32_bf16(Ax, B00, rp0, 0, 0, 0);
        rp1 = __builtin_amdgcn_mfma_f32_16x16x32_bf16(Ax, B10, rp1, 0, 0, 0);
        int row = quad * 4;
        #pragma unroll
        for (int r = 0; r < 4; ++r) {
            rpp[(row + r) * 33 + ml]      = rp0[r];
            rpp[(row + r) * 33 + ml + 16] = rp1[r];
        }
    }
    __builtin_amdgcn_wave_barrier();

    // ---- edge loop: 5-deep index queue (A..E), 3 fragment sets, 2-deep col queue
    const short8 Z8 = {0, 0, 0, 0, 0, 0, 0, 0};
    int iA = 0, tA = -1; adv(iA, tA, vd);
    int iB = iA, tB = tA; adv(iB, tB, vd);
    int iC = iB, tC = tB; adv(iC, tC, vd);
    int iD = iC, tD = tC; adv(iD, tD, vd);
    int iE = iD, tE = tD; adv(iE, tE, vd);

    int slot0 = slotOf(iA, tA, vs, vd, ml);
    int slot1 = slotOf(iB, tB, vs, vd, ml);
    int slot2 = slotOf(iC, tC, vs, vd, ml);
    int slotQ = slotOf(iD, tD, vs, vd, ml);
    int col0 = csr_col[slot0];
    int col1 = csr_col[slot1];
    int col2 = csr_col[slot2];
    int colQ = csr_col[slotQ];

    short8 F1_0 = ld_xb(xb_in, col0, quad);
    short8 F2_0 = (quad < 2) ? ld_rbf(rbf_buf, slot0, quad) : Z8;
    short8 F1_1 = ld_xb(xb_in, col1, quad);
    short8 F2_1 = (quad < 2) ? ld_rbf(rbf_buf, slot1, quad) : Z8;
    short8 F1_2 = ld_xb(xb_in, col2, quad);
    short8 F2_2 = (quad < 2) ? ld_rbf(rbf_buf, slot2, quad) : Z8;

    float colp0 = 0.0f, colp1 = 0.0f;

    // compute tile at queue head from fragment set (A1,A2)
    auto tile = [&](const short8& A1, const short8& A2) {
        float rpa = rpp[iA * 33 + ml];
        float rpb = rpp[iA * 33 + ml + 16];
        f32x4 acc0 = {rpa, rpa, rpa, rpa};
        f32x4 acc1 = {rpb, rpb, rpb, rpb};
        acc0 = __builtin_amdgcn_mfma_f32_16x16x32_bf16(A1, B01, acc0, 0, 0, 0);
        acc0 = __builtin_amdgcn_mfma_f32_16x16x32_bf16(A2, B02, acc0, 0, 0, 0);
        acc1 = __builtin_amdgcn_mfma_f32_16x16x32_bf16(A1, B11, acc1, 0, 0, 0);
        acc1 = __builtin_amdgcn_mfma_f32_16x16x32_bf16(A2, B12, acc1, 0, 0, 0);

        int dg0 = rl(vd, iA);
        int rowbase = tA * 16 + quad * 4;
        #pragma unroll
        for (int r = 0; r < 4; ++r) {
            bool vld = (rowbase + r) < dg0;
            colp0 += vld ? silu_f(acc0[r]) : 0.0f;
            colp1 += vld ? silu_f(acc1[r]) : 0.0f;
        }
        if (tA == ((dg0 + 15) >> 4) - 1) {   // last tile of node iA (uniform)
            colp0 += __shfl_xor(colp0, 16, 64);
            colp0 += __shfl_xor(colp0, 32, 64);
            colp1 += __shfl_xor(colp1, 16, 64);
            colp1 += __shfl_xor(colp1, 32, 64);
            if (quad == 0) {
                lshp[iA * 34 + ml]      = f2bf(colp0);
                lshp[iA * 34 + ml + 16] = f2bf(colp1);
            }
            colp0 = 0.0f; colp1 = 0.0f;
        }
    };
    auto shiftq = [&]() {
        iA = iB; tA = tB; iB = iC; tB = tC;
        iC = iD; tC = tD; iD = iE; tD = tE;
        adv(iE, tE, vd);
    };

    // STEP k (set s): prefetch col(k+4); compute tile k; refill set s with
    // frags(k+3) via colQ/slotQ (queued at step k-1); shift.
    #define EDGE_STEP(F1s, F2s)                                     \
    {                                                               \
        int slotE_ = slotOf(iE, tE, vs, vd, ml);                    \
        int colE_  = csr_col[slotE_];                               \
        tile(F1s, F2s);                                             \
        F1s = ld_xb(xb_in, colQ, quad);                             \
        F2s = (quad < 2) ? ld_rbf(rbf_buf, slotQ, quad) : Z8;       \
        shiftq();                                                   \
        colQ = colE_; slotQ = slotE_;                               \
    }

    while (iA < 16) {
        EDGE_STEP(F1_0, F2_0);
        if (iA >= 16) break;
        EDGE_STEP(F1_1, F2_1);
        if (iA >= 16) break;
        EDGE_STEP(F1_2, F2_2);
    }
    #undef EDGE_STEP
    __builtin_amdgcn_wave_barrier();

    // ---- node phase: 16-node batch, 8 MFMAs
    const short8* w2p = reinterpret_cast<const short8*>(wt2);
    short8 Bw2_0 = w2p[(ml     ) * 4 + quad];
    short8 Bw2_1 = w2p[(ml + 16) * 4 + quad];
    const short8* u1p = reinterpret_cast<const short8*>(wtu1);
    short8 Bu1_00 = u1p[(ml     ) * 8 + quad];       // k 0..31 (x)
    short8 Bu1_10 = u1p[(ml     ) * 8 + 4 + quad];   // k 32..63 (ag)
    short8 Bu1_01 = u1p[(ml + 16) * 8 + quad];
    short8 Bu1_11 = u1p[(ml + 16) * 8 + 4 + quad];
    const short8* u2p = reinterpret_cast<const short8*>(wtu2);
    short8 Bu2_0 = u2p[(ml     ) * 4 + quad];
    short8 Bu2_1 = u2p[(ml + 16) * 4 + quad];

    // sh @ W2
    short8 Ash = *reinterpret_cast<const short8*>(lshp + ml * 34 + quad * 8);
    f32x4 c0 = {0.0f, 0.0f, 0.0f, 0.0f};
    f32x4 c1 = {0.0f, 0.0f, 0.0f, 0.0f};
    c0 = __builtin_amdgcn_mfma_f32_16x16x32_bf16(Ash, Bw2_0, c0, 0, 0, 0);
    c1 = __builtin_amdgcn_mfma_f32_16x16x32_bf16(Ash, Bw2_1, c1, 0, 0, 0);
    float b2c0 = b2[ml], b2c1 = b2[ml + 16];
    unsigned short* agp = agb[w];
    int row = quad * 4;
    #pragma unroll
    for (int r = 0; r < 4; ++r) {
        float fd = ldg[w][row + r];
        float iv = livd[w][row + r];
        agp[(row + r) * 34 + ml]      = f2bf((c0[r] + fd * b2c0) * iv);
        agp[(row + r) * 34 + ml + 16] = f2bf((c1[r] + fd * b2c1) * iv);
    }
    __builtin_amdgcn_wave_barrier();

    // [x ; ag] @ Wu1
    short8 Aag = *reinterpret_cast<const short8*>(agp + ml * 34 + quad * 8);
    f32x4 d0 = {0.0f, 0.0f, 0.0f, 0.0f};
    f32x4 d1 = {0.0f, 0.0f, 0.0f, 0.0f};
    d0 = __builtin_amdgcn_mfma_f32_16x16x32_bf16(Ax,  Bu1_00, d0, 0, 0, 0);
    d0 = __builtin_amdgcn_mfma_f32_16x16x32_bf16(Aag, Bu1_10, d0, 0, 0, 0);
    d1 = __builtin_amdgcn_mfma_f32_16x16x32_bf16(Ax,  Bu1_01, d1, 0, 0, 0);
    d1 = __builtin_amdgcn_mfma_f32_16x16x32_bf16(Aag, Bu1_11, d1, 0, 0, 0);
    float bu1c0 = bu1[ml], bu1c1 = bu1[ml + 16];
    unsigned short* hup = hub[w];
    #pragma unroll
    for (int r = 0; r < 4; ++r) {
        hup[(row + r) * 34 + ml]      = f2bf(silu_f(d0[r] + bu1c0));
        hup[(row + r) * 34 + ml + 16] = f2bf(silu_f(d1[r] + bu1c1));
    }
    __builtin_amdgcn_wave_barrier();

    // hu @ Wu2 ; residual (x_in re-read, coalesced + L2-hot) + store
    short8 Ahu = *reinterpret_cast<const short8*>(hup + ml * 34 + quad * 8);
    float xr0[4], xr1[4];
    #pragma unroll
    for (int r = 0; r < 4; ++r) {
        int nn = nbase + row + r;
        xr0[r] = x_in[(size_t)nn * 32 + ml];
        xr1[r] = x_in[(size_t)nn * 32 + ml + 16];
    }
    f32x4 e0 = {0.0f, 0.0f, 0.0f, 0.0f};
    f32x4 e1 = {0.0f, 0.0f, 0.0f, 0.0f};
    e0 = __builtin_amdgcn_mfma_f32_16x16x32_bf16(Ahu, Bu2_0, e0, 0, 0, 0);
    e1 = __builtin_amdgcn_mfma_f32_16x16x32_bf16(Ahu, Bu2_1, e1, 0, 0, 0);
    float bu2c0 = bu2[ml], bu2c1 = bu2[ml + 16];
    #pragma unroll
    for (int r = 0; r < 4; ++r) {
        int nn = nbase + row + r;
        float o0 = e0[r] + bu2c0 + xr0[r];
        float o1 = e1[r] + bu2c1 + xr1[r];
        x_out[(size_t)nn * 32 + ml]      = o0;
        x_out[(size_t)nn * 32 + ml + 16] = o1;
        xb_out[(size_t)nn * 32 + ml]      = f2bf(o0);
        xb_out[(size_t)nn * 32 + ml + 16] = f2bf(o1);
    }
}

// ---------------------------------------------------------------- LN + heads, MFMA version
__global__ __launch_bounds__(256) void final_kernel(
    const float* __restrict__ x, const float* __restrict__ u,
    const float* __restrict__ v,
    const float* __restrict__ ln_g, const float* __restrict__ ln_b,
    const short* __restrict__ wtr1, const float* __restrict__ br1,
    const float* __restrict__ Wr2, const float* __restrict__ br2,
    const short* __restrict__ wts1, const float* __restrict__ bs1,
    const float* __restrict__ Ws2, const float* __restrict__ bs2,
    float* __restrict__ out)
{
    int t = threadIdx.x;
    int w = t >> 6;
    int lane = t & 63;
    int quad = lane >> 4;
    int ml = lane & 15;
    int wid = blockIdx.x * 4 + w;
    int nbase = __builtin_amdgcn_readfirstlane(wid * NPW);
    if (nbase >= N) return;

    // lane (quad,ml) holds x[nbase+ml][quad*8 .. quad*8+7]
    const float4* xs = reinterpret_cast<const float4*>(
        x + (size_t)(nbase + ml) * 32 + quad * 8);
    float4 xa = xs[0], xb4 = xs[1];
    float f[8] = {xa.x, xa.y, xa.z, xa.w, xb4.x, xb4.y, xb4.z, xb4.w};

    // LN statistics for node ml: reduce over k (across the 4 quads)
    float s = 0.0f, ss = 0.0f;
    #pragma unroll
    for (int i = 0; i < 8; ++i) { s += f[i]; ss += f[i] * f[i]; }
    s  += __shfl_xor(s, 16, 64);  s  += __shfl_xor(s, 32, 64);
    ss += __shfl_xor(ss, 16, 64); ss += __shfl_xor(ss, 32, 64);
    float mu = s * (1.0f / 32.0f);
    float var = ss * (1.0f / 32.0f) - mu * mu;
    float rs = rsqrtf(var + 1e-5f);

    // LN affine + bf16 A fragment (A[m=ml][k=quad*8+j])
    const float4* gp = reinterpret_cast<const float4*>(ln_g + quad * 8);
    const float4* bp = reinterpret_cast<const float4*>(ln_b + quad * 8);
    float4 g0 = gp[0], g1 = gp[1], bb0 = bp[0], bb1 = bp[1];
    float gg[8] = {g0.x, g0.y, g0.z, g0.w, g1.x, g1.y, g1.z, g1.w};
    float bb[8] = {bb0.x, bb0.y, bb0.z, bb0.w, bb1.x, bb1.y, bb1.z, bb1.w};
    short8 A;
    #pragma unroll
    for (int i = 0; i < 8; ++i)
        A[i] = (short)f2bf((f[i] - mu) * rs * gg[i] + bb[i]);

    // head layer 1: 6 MFMAs per head (output tiles n = ml + 16*h)
    const short8* r1p = reinterpret_cast<const short8*>(wtr1);
    const short8* s1p = reinterpret_cast<const short8*>(wts1);
    const f32x4 Zf = {0.0f, 0.0f, 0.0f, 0.0f};
    f32x4 hr[6], hs[6];
    #pragma unroll
    for (int h = 0; h < 6; ++h) {
        hr[h] = __builtin_amdgcn_mfma_f32_16x16x32_bf16(A, r1p[(ml + 16 * h) * 4 + quad], Zf, 0, 0, 0);
        hs[h] = __builtin_amdgcn_mfma_f32_16x16x32_bf16(A, s1p[(ml + 16 * h) * 4 + quad], Zf, 0, 0, 0);
    }

    // per-lane second-layer weights for features j = ml + 16*h
    float wr2a[6], wr2b[6], ws2v[6], br1v[6], bs1v[6];
    #pragma unroll
    for (int h = 0; h < 6; ++h) {
        int j = ml + 16 * h;
        float2 wr = reinterpret_cast<const float2*>(Wr2)[j];
        wr2a[h] = wr.x; wr2b[h] = wr.y;
        ws2v[h] = Ws2[j];
        br1v[h] = br1[j];
        bs1v[h] = bs1[j];
    }

    // silu + second layer; lane holds D rows m = quad*4+r, col n = ml+16h.
    float o0[4], o1[4], o2[4];
    #pragma unroll
    for (int r = 0; r < 4; ++r) {
        float p0 = 0.0f, p1 = 0.0f, p2 = 0.0f;
        #pragma unroll
        for (int h = 0; h < 6; ++h) {
            float a1 = silu_f(hr[h][r] + br1v[h]);
            float a2 = silu_f(hs[h][r] + bs1v[h]);
            p0 = fmaf(a1, wr2a[h], p0);
            p1 = fmaf(a1, wr2b[h], p1);
            p2 = fmaf(a2, ws2v[h], p2);
        }
        p0 += __shfl_xor(p0, 1, 64); p0 += __shfl_xor(p0, 2, 64);
        p0 += __shfl_xor(p0, 4, 64); p0 += __shfl_xor(p0, 8, 64);
        p1 += __shfl_xor(p1, 1, 64); p1 += __shfl_xor(p1, 2, 64);
        p1 += __shfl_xor(p1, 4, 64); p1 += __shfl_xor(p1, 8, 64);
        p2 += __shfl_xor(p2, 1, 64); p2 += __shfl_xor(p2, 2, 64);
        p2 += __shfl_xor(p2, 4, 64); p2 += __shfl_xor(p2, 8, 64);
        o0[r] = p0; o1[r] = p1; o2[r] = p2;
    }

    if (ml == 0) {
        float b20 = br2[0], b21 = br2[1], b22 = bs2[0];
        #pragma unroll
        for (int r = 0; r < 4; ++r) {
            int n = nbase + quad * 4 + r;
            out[n] = u[n * 4 + 3] + o2[r] + b22;
            out[N + 2 * n]     = o0[r] + b20 + v[n * 8 + 6];
            out[N + 2 * n + 1] = o1[r] + b21 + v[n * 8 + 7];
        }
    }
}

} // anonymous namespace

extern "C" void kernel_launch(void* const* d_in, const int* in_sizes, int n_in,
                              void* d_out, int out_size, void* d_ws, size_t ws_size,
                              hipStream_t stream)
{
    const float* u    = (const float*)d_in[0];
    const float* v    = (const float*)d_in[1];
    const float* bno  = (const float*)d_in[2];
    const float* yf   = (const float*)d_in[4];
    const float* pos  = (const float*)d_in[5];
    const int*   ei   = (const int*)d_in[6];
    const float* Wn1  = (const float*)d_in[7];
    const float* bn1  = (const float*)d_in[8];
    const float* Wn2  = (const float*)d_in[9];
    const float* bn2  = (const float*)d_in[10];
    const float* We1  = (const float*)d_in[11];
    const float* be1  = (const float*)d_in[12];
    const float* We2  = (const float*)d_in[13];
    const float* be2  = (const float*)d_in[14];
    const float* Wu1  = (const float*)d_in[15];
    const float* bu1  = (const float*)d_in[16];
    const float* Wu2  = (const float*)d_in[17];
    const float* bu2  = (const float*)d_in[18];
    const float* ln_g = (const float*)d_in[19];
    const float* ln_b = (const float*)d_in[20];
    const float* Wr1  = (const float*)d_in[21];
    const float* br1  = (const float*)d_in[22];
    const float* Wr2  = (const float*)d_in[23];
    const float* br2  = (const float*)d_in[24];
    const float* Ws1  = (const float*)d_in[25];
    const float* bs1  = (const float*)d_in[26];
    const float* Ws2  = (const float*)d_in[27];
    const float* bs2  = (const float*)d_in[28];
    float* out = (float*)d_out;

    // workspace layout (16B-aligned sections)
    int*   deg      = (int*)d_ws;                            // N
    int*   start    = deg + N;                               // N
    int*   bstart   = start + N;                             // NBKT+1
    int*   csr_col  = bstart + 512;                          // E ints
    unsigned short* rbf = (unsigned short*)(csr_col + E);    // E*16 bf16 (51.2 MB)
    float* x0       = (float*)(rbf + (size_t)E * 16);        // N*32 f32
    float* x1       = x0 + (size_t)N * S;                    // N*32 f32
    unsigned short* xb0 = (unsigned short*)(x1 + (size_t)N * S);   // N*32 bf16
    unsigned short* xb1 = xb0 + (size_t)N * S;               // N*32 bf16
    short* wt1      = (short*)(xb1 + (size_t)N * S);         // 5*32*96
    short* wt2      = wt1 + 5 * 32 * 96;                     // 5*32*32
    short* wtu1     = wt2 + 5 * 32 * 32;                     // 5*32*64
    short* wtu2     = wtu1 + 5 * 32 * 64;                    // 5*32*32
    short* wtr1     = wtu2 + 5 * 32 * 32;                    // 96*32 (head r, [n][k])
    short* wts1     = wtr1 + 96 * 32;                        // 96*32 (head s, [n][k])
    int*   hist     = (int*)(wts1 + 96 * 32);                // NBKT*256
    int*   basem    = hist + NBKT * 256;                     // NBKT*256

    // transient alias (dead before node_embed writes x0 / layer writes x1):
    //   edgebuf: E*16B bucket-ordered {col, dist, row} == x0..xb0 (E*16 == N*32*4*2)
    uint4* edgebuf = (uint4*)x0;

    passA_kernel<<<256, 1024, 0, stream>>>(ei, hist);
    p1_kernel<<<1, 512, 0, stream>>>(hist, bstart);
    p2_kernel<<<NBKT, 256, 0, stream>>>(hist, bstart, basem);
    passB_kernel<<<256, 1024, 0, stream>>>(ei, pos, basem, edgebuf);
    passC_kernel<<<NBKT, 1024, 0, stream>>>(edgebuf, bstart, deg, start, csr_col, rbf);
    prep_wt_kernel<<<60, 256, 0, stream>>>(We1, We2, Wu1, Wu2, Wr1, Ws1,
                                           wt1, wt2, wtu1, wtu2, wtr1, wts1);

    node_embed_kernel<<<LB2, 256, 0, stream>>>(u, v, bno, yf, Wn1, bn1, Wn2, bn2,
                                               x0, xb0);

    float* xin = x0;  float* xout = x1;
    unsigned short* xbin = xb0;  unsigned short* xbout = xb1;
    for (int l = 0; l < L; ++l) {
        layer_kernel<<<LB2, 256, 0, stream>>>(
            deg, start, csr_col, rbf, xin, xbin, xout, xbout,
            wt1 + (size_t)l * 32 * 96,  be1 + (size_t)l * 32,
            wt2 + (size_t)l * 32 * 32,  be2 + (size_t)l * 32,
            wtu1 + (size_t)l * 32 * 64, bu1 + (size_t)l * 32,
            wtu2 + (size_t)l * 32 * 32, bu2 + (size_t)l * 32);
        float* tf = xin; xin = xout; xout = tf;
        unsigned short* tb = xbin; xbin = xbout; xbout = tb;
    }

    final_kernel<<<LB2, 256, 0, stream>>>(xin, u, v, ln_g, ln_b,
                                          wtr1, br1, Wr2, br2,
                                          wts1, bs1, Ws2, bs2, out);
}

// Round 12
// 472.518 us; speedup vs baseline: 1.2882x; 1.0513x over previous
//
#include <hip/hip_runtime.h>
#include <cmath>

namespace {

constexpr int N = 100000;
constexpr int E = 1600000;
constexpr int S = 32;           // hidden
constexpr int L = 5;            // layers
constexpr int NPW = 16;               // nodes per wave in layer kernel
constexpr int LB2 = (N + 63) / 64;    // 1563 blocks (4 waves/block, 16 nodes/wave)
constexpr int NBKT = 391;             // CSR buckets: row>>8, 256 rows each
constexpr int EPB  = E / 256;         // 6250 edges per histogram/scatter block
constexpr float PI_F    = 3.14159265358979323846f;
constexpr float SQRT2_F = 1.41421356237309515f;

typedef __attribute__((ext_vector_type(8))) short short8;   // 8 x bf16
typedef __attribute__((ext_vector_type(4))) float f32x4;

// fast silu: v_rcp_f32 instead of IEEE division (saves ~10 VALU instrs/call)
__device__ __forceinline__ float silu_f(float x) {
    return x * __builtin_amdgcn_rcpf(1.0f + __expf(-x));
}

// float -> bf16 bits, round-to-nearest-even
__device__ __forceinline__ unsigned short f2bf(float f) {
    unsigned int u = __float_as_uint(f);
    u = (u + 0x7FFFu + ((u >> 16) & 1u)) >> 16;
    return (unsigned short)u;
}

__device__ __forceinline__ int rl(int v, int i) {
    return __builtin_amdgcn_readlane(v, i);
}

// 32-bit byte-offset gather of a 16B xb fragment: base + col*64 + quad*16
__device__ __forceinline__ short8 ld_xb(const unsigned short* base, int col, int quad) {
    unsigned off = ((unsigned)col << 6) | ((unsigned)quad << 4);
    return *reinterpret_cast<const short8*>(reinterpret_cast<const char*>(base) + off);
}

// 32-bit byte-offset read of an rbf half-row: base + slot*32 + quad*16
__device__ __forceinline__ short8 ld_rbf(const unsigned short* base, int slot, int quad) {
    unsigned off = ((unsigned)slot << 5) | ((unsigned)quad << 4);
    return *reinterpret_cast<const short8*>(reinterpret_cast<const char*>(base) + off);
}

// advance (i,t) to the next tile of this wave's 16-node batch (uniform)
__device__ __forceinline__ void adv(int& i, int& t, int vd) {
    ++t;
    while (i < 16) {
        int dgi = rl(vd, i);
        int nt = (dgi + 15) >> 4;
        if (t < nt) break;
        t = 0; ++i;
    }
}

// CSR slot for (i,t) at lane row ml; clamped into the node's own range
__device__ __forceinline__ int slotOf(int i, int t, int vs, int vd, int ml) {
    if (i >= 16) return 0;
    int s0 = rl(vs, i);
    int dg = rl(vd, i);
    int smax = s0 + ((dg > 0) ? dg : 1) - 1;
    int s = s0 + t * 16 + ml;
    return min(s, smax);
}

// ---------------------------------------------------------------- passA: bucket histogram
__global__ __launch_bounds__(1024) void passA_kernel(
    const int* __restrict__ ei, int* __restrict__ hist)
{
    __shared__ int h[NBKT];
    int t = threadIdx.x;
    int blk = blockIdx.x;
    for (int b = t; b < NBKT; b += 1024) h[b] = 0;
    __syncthreads();
    int base = blk * EPB;
    for (int i = t; i < EPB; i += 1024) {
        int r = ei[base + i];
        atomicAdd(&h[r >> 8], 1);
    }
    __syncthreads();
    for (int b = t; b < NBKT; b += 1024) hist[b * 256 + blk] = h[b];
}

// ---------------------------------------------------------------- p1: bucket totals + exclusive prefix
__global__ __launch_bounds__(512) void p1_kernel(
    const int* __restrict__ hist, int* __restrict__ bstart)
{
    __shared__ int tot[NBKT + 1];
    int t = threadIdx.x;
    if (t < NBKT) {
        int s = 0;
        for (int b = 0; b < 256; ++b) s += hist[t * 256 + b];
        tot[t] = s;
    }
    __syncthreads();
    if (t == 0) {
        int a = 0;
        for (int i = 0; i < NBKT; ++i) { int c = tot[i]; tot[i] = a; a += c; }
        tot[NBKT] = a;   // == E
    }
    __syncthreads();
    if (t <= NBKT) bstart[t] = tot[t];
}

// ---------------------------------------------------------------- p2: per-(bin,blk) scatter bases
__global__ __launch_bounds__(256) void p2_kernel(
    const int* __restrict__ hist, const int* __restrict__ bstart,
    int* __restrict__ base)
{
    __shared__ int pre[256];
    int t = threadIdx.x;
    int bin = blockIdx.x;
    int h = hist[bin * 256 + t];
    pre[t] = h;
    __syncthreads();
    #pragma unroll
    for (int off = 1; off < 256; off <<= 1) {
        int v = (t >= off) ? pre[t - off] : 0;
        __syncthreads();
        pre[t] += v;
        __syncthreads();
    }
    base[bin * 256 + t] = bstart[bin] + pre[t] - h;   // exclusive over blocks
}

// ---------------------------------------------------------------- passB: scatter to bucket staging
__global__ __launch_bounds__(1024) void passB_kernel(
    const int* __restrict__ ei, const float* __restrict__ pos,
    const int* __restrict__ base, uint4* __restrict__ edgebuf)
{
    __shared__ int cur[NBKT];
    int t = threadIdx.x;
    int blk = blockIdx.x;
    for (int b = t; b < NBKT; b += 1024) cur[b] = base[b * 256 + blk];
    __syncthreads();
    int ebase = blk * EPB;
    for (int i = t; i < EPB; i += 1024) {
        int e = ebase + i;
        int r = ei[e];
        int c = ei[E + e];
        float2 pr = reinterpret_cast<const float2*>(pos)[r];
        float2 pc = reinterpret_cast<const float2*>(pos)[c];
        float dx = pr.x - pc.x, dy = pr.y - pc.y;
        float d = sqrtf(dx * dx + dy * dy);   // pos-mean cancels
        int slot = atomicAdd(&cur[r >> 8], 1);   // LDS atomic
        edgebuf[slot] = make_uint4((unsigned)c, __float_as_uint(d), (unsigned)r, 0u);
    }
}

// ---------------------------------------------------------------- passC: per-bucket deg/start/rank + fused rbf
__global__ __launch_bounds__(1024) void passC_kernel(
    const uint4* __restrict__ edgebuf, const int* __restrict__ bstart,
    int* __restrict__ deg, int* __restrict__ start,
    int* __restrict__ csr_col, unsigned short* __restrict__ rbf_buf)
{
    __shared__ int cnt[256];
    __shared__ int pre[256];
    __shared__ int cur[256];
    int t = threadIdx.x;
    int bkt = blockIdx.x;
    int s0 = bstart[bkt], s1 = bstart[bkt + 1];

    if (t < 256) cnt[t] = 0;
    __syncthreads();
    for (int i = s0 + t; i < s1; i += 1024) {
        unsigned r = edgebuf[i].z;
        atomicAdd(&cnt[r & 255], 1);
    }
    __syncthreads();
    int c0 = 0;
    if (t < 256) {
        c0 = cnt[t];
        pre[t] = c0;
    }
    __syncthreads();
    #pragma unroll
    for (int off = 1; off < 256; off <<= 1) {
        int v = 0;
        if (t < 256) v = (t >= off) ? pre[t - off] : 0;
        __syncthreads();
        if (t < 256) pre[t] += v;
        __syncthreads();
    }
    if (t < 256) {
        int row = bkt * 256 + t;
        int st = s0 + pre[t] - c0;   // exclusive
        if (row < N) {
            deg[row] = c0;
            start[row] = st;
        }
        cur[t] = st;
    }
    __syncthreads();

    for (int i = s0 + t; i < s1; i += 1024) {
        uint4 e = edgebuf[i];
        int slot = atomicAdd(&cur[e.z & 255], 1);   // LDS atomic
        csr_col[slot] = (int)e.x;
        float d = __uint_as_float(e.y);

        float sn = __sinf(PI_F * d);
        float c1 = __cosf(PI_F * d);
        float inv = SQRT2_F / (d + 1e-8f);
        float tc = 2.0f * c1;
        float sk = sn, skm = 0.0f;
        unsigned int pk[8];
        #pragma unroll
        for (int k = 0; k < 8; ++k) {
            float r0 = sk * inv;
            float s2 = tc * sk - skm; skm = sk; sk = s2;
            float r1 = sk * inv;
            float s3 = tc * sk - skm; skm = sk; sk = s3;
            pk[k] = (unsigned int)f2bf(r0) | ((unsigned int)f2bf(r1) << 16);
        }
        uint4* out = reinterpret_cast<uint4*>(rbf_buf + (size_t)slot * 16);
        out[0] = make_uint4(pk[0], pk[1], pk[2], pk[3]);
        out[1] = make_uint4(pk[4], pk[5], pk[6], pk[7]);
    }
}

// ---------------------------------------------------------------- bf16 weight prep (transposed [n][k])
__global__ __launch_bounds__(256) void prep_wt_kernel(
    const float* __restrict__ We1, const float* __restrict__ We2,
    const float* __restrict__ Wu1, const float* __restrict__ Wu2,
    const float* __restrict__ Wr1, const float* __restrict__ Ws1,
    const float* __restrict__ Wn2,
    short* __restrict__ wt1, short* __restrict__ wt2,
    short* __restrict__ wtu1, short* __restrict__ wtu2,
    short* __restrict__ wtr1, short* __restrict__ wts1,
    short* __restrict__ wtn2)
{
    int idx = blockIdx.x * 256 + threadIdx.x;
    if (idx < 5 * 32 * 96) {
        int l = idx / (32 * 96), r = idx % (32 * 96), n = r / 96, k = r % 96;
        float v = (k < 80) ? We1[((size_t)l * 80 + k) * 32 + n] : 0.0f;
        wt1[idx] = (short)f2bf(v);
    }
    if (idx < 5 * 32 * 32) {
        int l = idx / 1024, r = idx % 1024, n = r / 32, k = r % 32;
        wt2[idx]  = (short)f2bf(We2[((size_t)l * 32 + k) * 32 + n]);
        wtu2[idx] = (short)f2bf(Wu2[((size_t)l * 32 + k) * 32 + n]);
    }
    if (idx < 5 * 32 * 64) {
        int l = idx / 2048, r = idx % 2048, n = r / 64, k = r % 64;
        wtu1[idx] = (short)f2bf(Wu1[((size_t)l * 64 + k) * 32 + n]);
    }
    if (idx < 96 * 32) {
        int n = idx / 32, k = idx % 32;   // head weights [n=96][k=32]
        wtr1[idx] = (short)f2bf(Wr1[k * 96 + n]);
        wts1[idx] = (short)f2bf(Ws1[k * 96 + n]);
    }
    if (idx < 32 * 64) {
        int n = idx / 64, k = idx % 64;   // embed layer-2 [n=32][k=64]
        wtn2[idx] = (short)f2bf(Wn2[k * 32 + n]);
    }
}

// ---------------------------------------------------------------- node embed v3: MFMA layer-2
// Structural clone of final_kernel's proven 16-nodes-per-wave pattern (~12us).
// Layer 1 ([N,10]@[10,64]) stays exact f32, distributed: lane (quad,ml) computes
// h[quad*16..+15] for node ml. h -> bf16 LDS row (stride-68, wave-local).
// Layer 2 ([16,64]@[64,32], formerly 2048 scalar FMA/node) = 4 MFMAs, bias-seeded.
__global__ __launch_bounds__(256) void node_embed_kernel(
    const float* __restrict__ u, const float* __restrict__ v,
    const float* __restrict__ bnorm, const float* __restrict__ yf,
    const float* __restrict__ Wn1, const float* __restrict__ bn1,
    const short* __restrict__ wtn2, const float* __restrict__ bn2,
    float* __restrict__ x, unsigned short* __restrict__ xb)
{
    __shared__ unsigned short hb[4][16 * 68];
    int t = threadIdx.x;
    int w = t >> 6;
    int lane = t & 63;
    int quad = lane >> 4;
    int ml = lane & 15;
    int wid = blockIdx.x * 4 + w;
    int nbase = __builtin_amdgcn_readfirstlane(wid * NPW);
    if (nbase >= N) return;   // N % 16 == 0: valid waves own full 16-node batches

    int n = nbase + ml;   // this lane's node for feats + layer 1

    // ---- invariant feats (exact f32)
    float f[10];
    float4 uu = reinterpret_cast<const float4*>(u)[n];
    f[0] = uu.x; f[1] = uu.y; f[2] = uu.z; f[3] = uu.w;
    float4 v0 = reinterpret_cast<const float4*>(v)[2 * n];
    float4 v1 = reinterpret_cast<const float4*>(v)[2 * n + 1];
    f[4] = sqrtf(v0.x * v0.x + v0.y * v0.y);
    f[5] = sqrtf(v0.z * v0.z + v0.w * v0.w);
    f[6] = sqrtf(v1.x * v1.x + v1.y * v1.y);
    f[7] = sqrtf(v1.z * v1.z + v1.w * v1.w);
    float2 bb = reinterpret_cast<const float2*>(bnorm)[n];
    f[8] = sqrtf(bb.x * bb.x + bb.y * bb.y);
    float2 yy = reinterpret_cast<const float2*>(yf)[n];
    f[9] = sqrtf(yy.x * yy.x + yy.y * yy.y);

    // ---- layer 1 (f32): h[j], j = quad*16 + jj
    float h[16];
    {
        const float4* b4 = reinterpret_cast<const float4*>(bn1 + quad * 16);
        float4 b0 = b4[0], b1 = b4[1], b2 = b4[2], b3 = b4[3];
        h[0]=b0.x; h[1]=b0.y; h[2]=b0.z; h[3]=b0.w;
        h[4]=b1.x; h[5]=b1.y; h[6]=b1.z; h[7]=b1.w;
        h[8]=b2.x; h[9]=b2.y; h[10]=b2.z; h[11]=b2.w;
        h[12]=b3.x; h[13]=b3.y; h[14]=b3.z; h[15]=b3.w;
    }
    #pragma unroll
    for (int i = 0; i < 10; ++i) {
        float ff = f[i];
        const float4* wr = reinterpret_cast<const float4*>(Wn1 + i * 64 + quad * 16);
        float4 w0 = wr[0], w1 = wr[1], w2 = wr[2], w3 = wr[3];
        h[0]  = fmaf(ff, w0.x, h[0]);  h[1]  = fmaf(ff, w0.y, h[1]);
        h[2]  = fmaf(ff, w0.z, h[2]);  h[3]  = fmaf(ff, w0.w, h[3]);
        h[4]  = fmaf(ff, w1.x, h[4]);  h[5]  = fmaf(ff, w1.y, h[5]);
        h[6]  = fmaf(ff, w1.z, h[6]);  h[7]  = fmaf(ff, w1.w, h[7]);
        h[8]  = fmaf(ff, w2.x, h[8]);  h[9]  = fmaf(ff, w2.y, h[9]);
        h[10] = fmaf(ff, w2.z, h[10]); h[11] = fmaf(ff, w2.w, h[11]);
        h[12] = fmaf(ff, w3.x, h[12]); h[13] = fmaf(ff, w3.y, h[13]);
        h[14] = fmaf(ff, w3.z, h[14]); h[15] = fmaf(ff, w3.w, h[15]);
    }
    #pragma unroll
    for (int jj = 0; jj < 16; ++jj) h[jj] = silu_f(h[jj]);

    // ---- pack bf16 h into wave-local LDS: row = node ml, cols quad*16..+15
    unsigned short* hp = hb[w];
    {
        unsigned int* dst = reinterpret_cast<unsigned int*>(hp + ml * 68 + quad * 16);
        #pragma unroll
        for (int i = 0; i < 8; ++i)
            dst[i] = (unsigned int)f2bf(h[2 * i]) | ((unsigned int)f2bf(h[2 * i + 1]) << 16);
    }
    __builtin_amdgcn_wave_barrier();

    // ---- layer 2: 4 MFMAs (A[m=node ml][k], B=[n=32][k=64])
    short8 Ak0 = *reinterpret_cast<const short8*>(hp + ml * 68 + quad * 8);
    short8 Ak1 = *reinterpret_cast<const short8*>(hp + ml * 68 + 32 + quad * 8);
    const short8* n2p = reinterpret_cast<const short8*>(wtn2);
    short8 B00 = n2p[(ml     ) * 8 + quad];       // n=ml,    k 0..31
    short8 B01 = n2p[(ml     ) * 8 + 4 + quad];   // n=ml,    k 32..63
    short8 B10 = n2p[(ml + 16) * 8 + quad];
    short8 B11 = n2p[(ml + 16) * 8 + 4 + quad];
    float bz0 = bn2[ml], bz1 = bn2[ml + 16];
    f32x4 a0 = {bz0, bz0, bz0, bz0};
    f32x4 a1 = {bz1, bz1, bz1, bz1};
    a0 = __builtin_amdgcn_mfma_f32_16x16x32_bf16(Ak0, B00, a0, 0, 0, 0);
    a0 = __builtin_amdgcn_mfma_f32_16x16x32_bf16(Ak1, B01, a0, 0, 0, 0);
    a1 = __builtin_amdgcn_mfma_f32_16x16x32_bf16(Ak0, B10, a1, 0, 0, 0);
    a1 = __builtin_amdgcn_mfma_f32_16x16x32_bf16(Ak1, B11, a1, 0, 0, 0);

    int row = quad * 4;
    #pragma unroll
    for (int r = 0; r < 4; ++r) {
        int nn = nbase + row + r;
        float o0 = a0[r];
        float o1 = a1[r];
        x[(size_t)nn * 32 + ml]      = o0;
        x[(size_t)nn * 32 + ml + 16] = o1;
        xb[(size_t)nn * 32 + ml]      = f2bf(o0);
        xb[(size_t)nn * 32 + ml + 16] = f2bf(o1);
    }
}

// ---------------------------------------------------------------- fused layer v4
__global__ __launch_bounds__(256, 6) void layer_kernel(
    const int* __restrict__ deg, const int* __restrict__ start,
    const int* __restrict__ csr_col, const unsigned short* __restrict__ rbf_buf,
    const float* __restrict__ x_in, const unsigned short* __restrict__ xb_in,
    float* __restrict__ x_out, unsigned short* __restrict__ xb_out,
    const short* __restrict__ wt1, const float* __restrict__ b1,
    const short* __restrict__ wt2, const float* __restrict__ b2,
    const short* __restrict__ wtu1, const float* __restrict__ bu1,
    const short* __restrict__ wtu2, const float* __restrict__ bu2)
{
    __shared__ unsigned short lsh[4][16 * 34];   // sh  (bf16), stride 34
    __shared__ unsigned short agb[4][16 * 34];   // ag  (bf16)
    __shared__ unsigned short hub[4][16 * 34];   // hu  (bf16)
    __shared__ float lrp[4][16 * 33];            // rowpart b1 + x@W1[0:32,:] (fp32)
    __shared__ float ldg[4][16];
    __shared__ float livd[4][16];

    int t = threadIdx.x;
    int w = t >> 6;
    int lane = t & 63;
    int quad = lane >> 4;
    int ml = lane & 15;
    int wid = blockIdx.x * 4 + w;
    int nbase = __builtin_amdgcn_readfirstlane(wid * NPW);
    if (nbase >= N) return;   // N % 16 == 0, so valid waves own full batches

    // ---- batch metadata: lane ml holds node ml's start/deg
    int vs = start[nbase + ml];
    int vd = deg[nbase + ml];

    // ---- edge-phase B fragments (wt1 [32][96])
    const short8* wp = reinterpret_cast<const short8*>(wt1);
    short8 B00 = wp[(ml     ) * 12 + 0 * 4 + quad];
    short8 B01 = wp[(ml     ) * 12 + 1 * 4 + quad];
    short8 B02 = wp[(ml     ) * 12 + 2 * 4 + quad];
    short8 B10 = wp[(ml + 16) * 12 + 0 * 4 + quad];
    short8 B11 = wp[(ml + 16) * 12 + 1 * 4 + quad];
    short8 B12 = wp[(ml + 16) * 12 + 2 * 4 + quad];

    // node-phase / rowpart x A-fragment (A[m=node ml][k=quad*8+j])
    short8 Ax = ld_xb(xb_in, nbase + ml, quad);

    float b1j0 = b1[ml];
    float b1j1 = b1[ml + 16];

    // ---- zero sh, stash deg floats
    unsigned short* lshp = lsh[w];
    for (int k = lane; k < 16 * 34; k += 64) lshp[k] = 0;
    if (lane < 16) {
        ldg[w][lane] = (float)vd;
        livd[w][lane] = 1.0f / fmaxf((float)vd, 1.0f);
    }

    // ---- hoisted row-node partial: rp[m][j] = b1[j] + x[m] @ W1[0:32, j]
    float* rpp = lrp[w];
    {
        f32x4 rp0 = {b1j0, b1j0, b1j0, b1j0};
        f32x4 rp1 = {b1j1, b1j1, b1j1, b1j1};
        rp0 = __builtin_amdgcn_mfma_f32_16x16x32_bf16(Ax, B00, rp0, 0, 0, 0);
        rp1 = __builtin_amdgcn_mfma_f32_16x16x32_bf16(Ax, B10, rp1, 0, 0, 0);
        int row = quad * 4;
        #pragma unroll
        for (int r = 0; r < 4; ++r) {
            rpp[(row + r) * 33 + ml]      = rp0[r];
            rpp[(row + r) * 33 + ml + 16] = rp1[r];
        }
    }
    __builtin_amdgcn_wave_barrier();

    // ---- edge loop: 5-deep index queue (A..E), 3 fragment sets, 2-deep col queue
    const short8 Z8 = {0, 0, 0, 0, 0, 0, 0, 0};
    int iA = 0, tA = -1; adv(iA, tA, vd);
    int iB = iA, tB = tA; adv(iB, tB, vd);
    int iC = iB, tC = tB; adv(iC, tC, vd);
    int iD = iC, tD = tC; adv(iD, tD, vd);
    int iE = iD, tE = tD; adv(iE, tE, vd);

    int slot0 = slotOf(iA, tA, vs, vd, ml);
    int slot1 = slotOf(iB, tB, vs, vd, ml);
    int slot2 = slotOf(iC, tC, vs, vd, ml);
    int slotQ = slotOf(iD, tD, vs, vd, ml);
    int col0 = csr_col[slot0];
    int col1 = csr_col[slot1];
    int col2 = csr_col[slot2];
    int colQ = csr_col[slotQ];

    short8 F1_0 = ld_xb(xb_in, col0, quad);
    short8 F2_0 = (quad < 2) ? ld_rbf(rbf_buf, slot0, quad) : Z8;
    short8 F1_1 = ld_xb(xb_in, col1, quad);
    short8 F2_1 = (quad < 2) ? ld_rbf(rbf_buf, slot1, quad) : Z8;
    short8 F1_2 = ld_xb(xb_in, col2, quad);
    short8 F2_2 = (quad < 2) ? ld_rbf(rbf_buf, slot2, quad) : Z8;

    float colp0 = 0.0f, colp1 = 0.0f;

    // compute tile at queue head from fragment set (A1,A2)
    auto tile = [&](const short8& A1, const short8& A2) {
        float rpa = rpp[iA * 33 + ml];
        float rpb = rpp[iA * 33 + ml + 16];
        f32x4 acc0 = {rpa, rpa, rpa, rpa};
        f32x4 acc1 = {rpb, rpb, rpb, rpb};
        acc0 = __builtin_amdgcn_mfma_f32_16x16x32_bf16(A1, B01, acc0, 0, 0, 0);
        acc0 = __builtin_amdgcn_mfma_f32_16x16x32_bf16(A2, B02, acc0, 0, 0, 0);
        acc1 = __builtin_amdgcn_mfma_f32_16x16x32_bf16(A1, B11, acc1, 0, 0, 0);
        acc1 = __builtin_amdgcn_mfma_f32_16x16x32_bf16(A2, B12, acc1, 0, 0, 0);

        int dg0 = rl(vd, iA);
        int rowbase = tA * 16 + quad * 4;
        #pragma unroll
        for (int r = 0; r < 4; ++r) {
            bool vld = (rowbase + r) < dg0;
            colp0 += vld ? silu_f(acc0[r]) : 0.0f;
            colp1 += vld ? silu_f(acc1[r]) : 0.0f;
        }
        if (tA == ((dg0 + 15) >> 4) - 1) {   // last tile of node iA (uniform)
            colp0 += __shfl_xor(colp0, 16, 64);
            colp0 += __shfl_xor(colp0, 32, 64);
            colp1 += __shfl_xor(colp1, 16, 64);
            colp1 += __shfl_xor(colp1, 32, 64);
            if (quad == 0) {
                lshp[iA * 34 + ml]      = f2bf(colp0);
                lshp[iA * 34 + ml + 16] = f2bf(colp1);
            }
            colp0 = 0.0f; colp1 = 0.0f;
        }
    };
    auto shiftq = [&]() {
        iA = iB; tA = tB; iB = iC; tB = tC;
        iC = iD; tC = tD; iD = iE; tD = tE;
        adv(iE, tE, vd);
    };

    // STEP k (set s): prefetch col(k+4); compute tile k; refill set s with
    // frags(k+3) via colQ/slotQ (queued at step k-1); shift.
    #define EDGE_STEP(F1s, F2s)                                     \
    {                                                               \
        int slotE_ = slotOf(iE, tE, vs, vd, ml);                    \
        int colE_  = csr_col[slotE_];                               \
        tile(F1s, F2s);                                             \
        F1s = ld_xb(xb_in, colQ, quad);                             \
        F2s = (quad < 2) ? ld_rbf(rbf_buf, slotQ, quad) : Z8;       \
        shiftq();                                                   \
        colQ = colE_; slotQ = slotE_;                               \
    }

    while (iA < 16) {
        EDGE_STEP(F1_0, F2_0);
        if (iA >= 16) break;
        EDGE_STEP(F1_1, F2_1);
        if (iA >= 16) break;
        EDGE_STEP(F1_2, F2_2);
    }
    #undef EDGE_STEP
    __builtin_amdgcn_wave_barrier();

    // ---- node phase: 16-node batch, 8 MFMAs
    const short8* w2p = reinterpret_cast<const short8*>(wt2);
    short8 Bw2_0 = w2p[(ml     ) * 4 + quad];
    short8 Bw2_1 = w2p[(ml + 16) * 4 + quad];
    const short8* u1p = reinterpret_cast<const short8*>(wtu1);
    short8 Bu1_00 = u1p[(ml     ) * 8 + quad];       // k 0..31 (x)
    short8 Bu1_10 = u1p[(ml     ) * 8 + 4 + quad];   // k 32..63 (ag)
    short8 Bu1_01 = u1p[(ml + 16) * 8 + quad];
    short8 Bu1_11 = u1p[(ml + 16) * 8 + 4 + quad];
    const short8* u2p = reinterpret_cast<const short8*>(wtu2);
    short8 Bu2_0 = u2p[(ml     ) * 4 + quad];
    short8 Bu2_1 = u2p[(ml + 16) * 4 + quad];

    // sh @ W2
    short8 Ash = *reinterpret_cast<const short8*>(lshp + ml * 34 + quad * 8);
    f32x4 c0 = {0.0f, 0.0f, 0.0f, 0.0f};
    f32x4 c1 = {0.0f, 0.0f, 0.0f, 0.0f};
    c0 = __builtin_amdgcn_mfma_f32_16x16x32_bf16(Ash, Bw2_0, c0, 0, 0, 0);
    c1 = __builtin_amdgcn_mfma_f32_16x16x32_bf16(Ash, Bw2_1, c1, 0, 0, 0);
    float b2c0 = b2[ml], b2c1 = b2[ml + 16];
    unsigned short* agp = agb[w];
    int row = quad * 4;
    #pragma unroll
    for (int r = 0; r < 4; ++r) {
        float fd = ldg[w][row + r];
        float iv = livd[w][row + r];
        agp[(row + r) * 34 + ml]      = f2bf((c0[r] + fd * b2c0) * iv);
        agp[(row + r) * 34 + ml + 16] = f2bf((c1[r] + fd * b2c1) * iv);
    }
    __builtin_amdgcn_wave_barrier();

    // [x ; ag] @ Wu1
    short8 Aag = *reinterpret_cast<const short8*>(agp + ml * 34 + quad * 8);
    f32x4 d0 = {0.0f, 0.0f, 0.0f, 0.0f};
    f32x4 d1 = {0.0f, 0.0f, 0.0f, 0.0f};
    d0 = __builtin_amdgcn_mfma_f32_16x16x32_bf16(Ax,  Bu1_00, d0, 0, 0, 0);
    d0 = __builtin_amdgcn_mfma_f32_16x16x32_bf16(Aag, Bu1_10, d0, 0, 0, 0);
    d1 = __builtin_amdgcn_mfma_f32_16x16x32_bf16(Ax,  Bu1_01, d1, 0, 0, 0);
    d1 = __builtin_amdgcn_mfma_f32_16x16x32_bf16(Aag, Bu1_11, d1, 0, 0, 0);
    float bu1c0 = bu1[ml], bu1c1 = bu1[ml + 16];
    unsigned short* hup = hub[w];
    #pragma unroll
    for (int r = 0; r < 4; ++r) {
        hup[(row + r) * 34 + ml]      = f2bf(silu_f(d0[r] + bu1c0));
        hup[(row + r) * 34 + ml + 16] = f2bf(silu_f(d1[r] + bu1c1));
    }
    __builtin_amdgcn_wave_barrier();

    // hu @ Wu2 ; residual (x_in re-read, coalesced + L2-hot) + store
    short8 Ahu = *reinterpret_cast<const short8*>(hup + ml * 34 + quad * 8);
    float xr0[4], xr1[4];
    #pragma unroll
    for (int r = 0; r < 4; ++r) {
        int nn = nbase + row + r;
        xr0[r] = x_in[(size_t)nn * 32 + ml];
        xr1[r] = x_in[(size_t)nn * 32 + ml + 16];
    }
    f32x4 e0 = {0.0f, 0.0f, 0.0f, 0.0f};
    f32x4 e1 = {0.0f, 0.0f, 0.0f, 0.0f};
    e0 = __builtin_amdgcn_mfma_f32_16x16x32_bf16(Ahu, Bu2_0, e0, 0, 0, 0);
    e1 = __builtin_amdgcn_mfma_f32_16x16x32_bf16(Ahu, Bu2_1, e1, 0, 0, 0);
    float bu2c0 = bu2[ml], bu2c1 = bu2[ml + 16];
    #pragma unroll
    for (int r = 0; r < 4; ++r) {
        int nn = nbase + row + r;
        float o0 = e0[r] + bu2c0 + xr0[r];
        float o1 = e1[r] + bu2c1 + xr1[r];
        x_out[(size_t)nn * 32 + ml]      = o0;
        x_out[(size_t)nn * 32 + ml + 16] = o1;
        xb_out[(size_t)nn * 32 + ml]      = f2bf(o0);
        xb_out[(size_t)nn * 32 + ml + 16] = f2bf(o1);
    }
}

// ---------------------------------------------------------------- LN + heads, MFMA version
__global__ __launch_bounds__(256) void final_kernel(
    const float* __restrict__ x, const float* __restrict__ u,
    const float* __restrict__ v,
    const float* __restrict__ ln_g, const float* __restrict__ ln_b,
    const short* __restrict__ wtr1, const float* __restrict__ br1,
    const float* __restrict__ Wr2, const float* __restrict__ br2,
    const short* __restrict__ wts1, const float* __restrict__ bs1,
    const float* __restrict__ Ws2, const float* __restrict__ bs2,
    float* __restrict__ out)
{
    int t = threadIdx.x;
    int w = t >> 6;
    int lane = t & 63;
    int quad = lane >> 4;
    int ml = lane & 15;
    int wid = blockIdx.x * 4 + w;
    int nbase = __builtin_amdgcn_readfirstlane(wid * NPW);
    if (nbase >= N) return;

    // lane (quad,ml) holds x[nbase+ml][quad*8 .. quad*8+7]
    const float4* xs = reinterpret_cast<const float4*>(
        x + (size_t)(nbase + ml) * 32 + quad * 8);
    float4 xa = xs[0], xb4 = xs[1];
    float f[8] = {xa.x, xa.y, xa.z, xa.w, xb4.x, xb4.y, xb4.z, xb4.w};

    // LN statistics for node ml: reduce over k (across the 4 quads)
    float s = 0.0f, ss = 0.0f;
    #pragma unroll
    for (int i = 0; i < 8; ++i) { s += f[i]; ss += f[i] * f[i]; }
    s  += __shfl_xor(s, 16, 64);  s  += __shfl_xor(s, 32, 64);
    ss += __shfl_xor(ss, 16, 64); ss += __shfl_xor(ss, 32, 64);
    float mu = s * (1.0f / 32.0f);
    float var = ss * (1.0f / 32.0f) - mu * mu;
    float rs = rsqrtf(var + 1e-5f);

    // LN affine + bf16 A fragment (A[m=ml][k=quad*8+j])
    const float4* gp = reinterpret_cast<const float4*>(ln_g + quad * 8);
    const float4* bp = reinterpret_cast<const float4*>(ln_b + quad * 8);
    float4 g0 = gp[0], g1 = gp[1], bb0 = bp[0], bb1 = bp[1];
    float gg[8] = {g0.x, g0.y, g0.z, g0.w, g1.x, g1.y, g1.z, g1.w};
    float bb[8] = {bb0.x, bb0.y, bb0.z, bb0.w, bb1.x, bb1.y, bb1.z, bb1.w};
    short8 A;
    #pragma unroll
    for (int i = 0; i < 8; ++i)
        A[i] = (short)f2bf((f[i] - mu) * rs * gg[i] + bb[i]);

    // head layer 1: 6 MFMAs per head (output tiles n = ml + 16*h)
    const short8* r1p = reinterpret_cast<const short8*>(wtr1);
    const short8* s1p = reinterpret_cast<const short8*>(wts1);
    const f32x4 Zf = {0.0f, 0.0f, 0.0f, 0.0f};
    f32x4 hr[6], hs[6];
    #pragma unroll
    for (int h = 0; h < 6; ++h) {
        hr[h] = __builtin_amdgcn_mfma_f32_16x16x32_bf16(A, r1p[(ml + 16 * h) * 4 + quad], Zf, 0, 0, 0);
        hs[h] = __builtin_amdgcn_mfma_f32_16x16x32_bf16(A, s1p[(ml + 16 * h) * 4 + quad], Zf, 0, 0, 0);
    }

    // per-lane second-layer weights for features j = ml + 16*h
    float wr2a[6], wr2b[6], ws2v[6], br1v[6], bs1v[6];
    #pragma unroll
    for (int h = 0; h < 6; ++h) {
        int j = ml + 16 * h;
        float2 wr = reinterpret_cast<const float2*>(Wr2)[j];
        wr2a[h] = wr.x; wr2b[h] = wr.y;
        ws2v[h] = Ws2[j];
        br1v[h] = br1[j];
        bs1v[h] = bs1[j];
    }

    // silu + second layer; lane holds D rows m = quad*4+r, col n = ml+16h.
    float o0[4], o1[4], o2[4];
    #pragma unroll
    for (int r = 0; r < 4; ++r) {
        float p0 = 0.0f, p1 = 0.0f, p2 = 0.0f;
        #pragma unroll
        for (int h = 0; h < 6; ++h) {
            float a1 = silu_f(hr[h][r] + br1v[h]);
            float a2 = silu_f(hs[h][r] + bs1v[h]);
            p0 = fmaf(a1, wr2a[h], p0);
            p1 = fmaf(a1, wr2b[h], p1);
            p2 = fmaf(a2, ws2v[h], p2);
        }
        p0 += __shfl_xor(p0, 1, 64); p0 += __shfl_xor(p0, 2, 64);
        p0 += __shfl_xor(p0, 4, 64); p0 += __shfl_xor(p0, 8, 64);
        p1 += __shfl_xor(p1, 1, 64); p1 += __shfl_xor(p1, 2, 64);
        p1 += __shfl_xor(p1, 4, 64); p1 += __shfl_xor(p1, 8, 64);
        p2 += __shfl_xor(p2, 1, 64); p2 += __shfl_xor(p2, 2, 64);
        p2 += __shfl_xor(p2, 4, 64); p2 += __shfl_xor(p2, 8, 64);
        o0[r] = p0; o1[r] = p1; o2[r] = p2;
    }

    if (ml == 0) {
        float b20 = br2[0], b21 = br2[1], b22 = bs2[0];
        #pragma unroll
        for (int r = 0; r < 4; ++r) {
            int n = nbase + quad * 4 + r;
            out[n] = u[n * 4 + 3] + o2[r] + b22;
            out[N + 2 * n]     = o0[r] + b20 + v[n * 8 + 6];
            out[N + 2 * n + 1] = o1[r] + b21 + v[n * 8 + 7];
        }
    }
}

} // anonymous namespace

extern "C" void kernel_launch(void* const* d_in, const int* in_sizes, int n_in,
                              void* d_out, int out_size, void* d_ws, size_t ws_size,
                              hipStream_t stream)
{
    const float* u    = (const float*)d_in[0];
    const float* v    = (const float*)d_in[1];
    const float* bno  = (const float*)d_in[2];
    const float* yf   = (const float*)d_in[4];
    const float* pos  = (const float*)d_in[5];
    const int*   ei   = (const int*)d_in[6];
    const float* Wn1  = (const float*)d_in[7];
    const float* bn1  = (const float*)d_in[8];
    const float* Wn2  = (const float*)d_in[9];
    const float* bn2  = (const float*)d_in[10];
    const float* We1  = (const float*)d_in[11];
    const float* be1  = (const float*)d_in[12];
    const float* We2  = (const float*)d_in[13];
    const float* be2  = (const float*)d_in[14];
    const float* Wu1  = (const float*)d_in[15];
    const float* bu1  = (const float*)d_in[16];
    const float* Wu2  = (const float*)d_in[17];
    const float* bu2  = (const float*)d_in[18];
    const float* ln_g = (const float*)d_in[19];
    const float* ln_b = (const float*)d_in[20];
    const float* Wr1  = (const float*)d_in[21];
    const float* br1  = (const float*)d_in[22];
    const float* Wr2  = (const float*)d_in[23];
    const float* br2  = (const float*)d_in[24];
    const float* Ws1  = (const float*)d_in[25];
    const float* bs1  = (const float*)d_in[26];
    const float* Ws2  = (const float*)d_in[27];
    const float* bs2  = (const float*)d_in[28];
    float* out = (float*)d_out;

    // workspace layout (16B-aligned sections)
    int*   deg      = (int*)d_ws;                            // N
    int*   start    = deg + N;                               // N
    int*   bstart   = start + N;                             // NBKT+1
    int*   csr_col  = bstart + 512;                          // E ints
    unsigned short* rbf = (unsigned short*)(csr_col + E);    // E*16 bf16 (51.2 MB)
    float* x0       = (float*)(rbf + (size_t)E * 16);        // N*32 f32
    float* x1       = x0 + (size_t)N * S;                    // N*32 f32
    unsigned short* xb0 = (unsigned short*)(x1 + (size_t)N * S);   // N*32 bf16
    unsigned short* xb1 = xb0 + (size_t)N * S;               // N*32 bf16
    short* wt1      = (short*)(xb1 + (size_t)N * S);         // 5*32*96
    short* wt2      = wt1 + 5 * 32 * 96;                     // 5*32*32
    short* wtu1     = wt2 + 5 * 32 * 32;                     // 5*32*64
    short* wtu2     = wtu1 + 5 * 32 * 64;                    // 5*32*32
    short* wtr1     = wtu2 + 5 * 32 * 32;                    // 96*32 (head r, [n][k])
    short* wts1     = wtr1 + 96 * 32;                        // 96*32 (head s, [n][k])
    short* wtn2     = wts1 + 96 * 32;                        // 32*64 (embed l2, [n][k])
    int*   hist     = (int*)(wtn2 + 32 * 64);                // NBKT*256
    int*   basem    = hist + NBKT * 256;                     // NBKT*256

    // transient alias (dead before node_embed writes x0 / layer writes x1):
    //   edgebuf: E*16B bucket-ordered {col, dist, row} == x0..xb0 (E*16 == N*32*4*2)
    uint4* edgebuf = (uint4*)x0;

    passA_kernel<<<256, 1024, 0, stream>>>(ei, hist);
    p1_kernel<<<1, 512, 0, stream>>>(hist, bstart);
    p2_kernel<<<NBKT, 256, 0, stream>>>(hist, bstart, basem);
    passB_kernel<<<256, 1024, 0, stream>>>(ei, pos, basem, edgebuf);
    passC_kernel<<<NBKT, 1024, 0, stream>>>(edgebuf, bstart, deg, start, csr_col, rbf);
    prep_wt_kernel<<<60, 256, 0, stream>>>(We1, We2, Wu1, Wu2, Wr1, Ws1, Wn2,
                                           wt1, wt2, wtu1, wtu2, wtr1, wts1, wtn2);

    node_embed_kernel<<<LB2, 256, 0, stream>>>(u, v, bno, yf, Wn1, bn1, wtn2, bn2,
                                               x0, xb0);

    float* xin = x0;  float* xout = x1;
    unsigned short* xbin = xb0;  unsigned short* xbout = xb1;
    for (int l = 0; l < L; ++l) {
        layer_kernel<<<LB2, 256, 0, stream>>>(
            deg, start, csr_col, rbf, xin, xbin, xout, xbout,
            wt1 + (size_t)l * 32 * 96,  be1 + (size_t)l * 32,
            wt2 + (size_t)l * 32 * 32,  be2 + (size_t)l * 32,
            wtu1 + (size_t)l * 32 * 64, bu1 + (size_t)l * 32,
            wtu2 + (size_t)l * 32 * 32, bu2 + (size_t)l * 32);
        float* tf = xin; xin = xout; xout = tf;
        unsigned short* tb = xbin; xbin = xbout; xbout = tb;
    }

    final_kernel<<<LB2, 256, 0, stream>>>(xin, u, v, ln_g, ln_b,
                                          wtr1, br1, Wr2, br2,
                                          wts1, bs1, Ws2, bs2, out);
}